// Round 4
// baseline (599.908 us; speedup 1.0000x reference)
//
#include <hip/hip_runtime.h>

#define T 2048
#define HID 4096
#define NH 32
#define NKV 8
#define HD 128
#define QKV_OUT ((NH + 2*NKV) * HD)   // 6144
#define SCALING 0.08838834764831843f  // 128^-0.5
#define QS2 0.12751744954f            // SCALING * log2(e): QK^T in log2 domain
#define DEFER_THR 10.0f               // defer-max threshold (log2 domain, P<=2^10)
#define ROPE_C 0.20762050593046014f   // log2(10000)/64

typedef __attribute__((ext_vector_type(8))) short bfrag;   // 8 bf16
typedef __attribute__((ext_vector_type(4))) float ffrag;   // 4 f32 acc
typedef __attribute__((ext_vector_type(4))) int  ifrag;    // 16 i8 / 4 i32 acc
typedef __attribute__((ext_vector_type(16))) char c16;

__device__ __forceinline__ short f2bf(float f) {
  unsigned u = __builtin_bit_cast(unsigned, f);
  u += 0x7fffu + ((u >> 16) & 1u);   // RNE
  return (short)(u >> 16);
}

// bf16x2 split: x ~= hi + lo, residual ~2^-17 * |x|
__device__ __forceinline__ void split2(float x, short& hi, short& lo) {
  unsigned u = __builtin_bit_cast(unsigned, x);
  unsigned uh = u + (0x7fffu + ((u >> 16) & 1u));
  hi = (short)(uh >> 16);
  float fh = __builtin_bit_cast(float, uh & 0xffff0000u);
  float r = x - fh;
  unsigned ur = __builtin_bit_cast(unsigned, r);
  ur += 0x7fffu + ((ur >> 16) & 1u);
  lo = (short)(ur >> 16);
}

// async global->LDS, 16 B per lane
__device__ __forceinline__ void gload_lds16(const void* g, void* l) {
  __builtin_amdgcn_global_load_lds(
      (const __attribute__((address_space(1))) unsigned int*)g,
      (__attribute__((address_space(3))) unsigned int*)l, 16, 0, 0);
}

// ---------------- fused a_sum + int8 pack of activations ----------------
__global__ __launch_bounds__(256)
void asum_conv(const int* __restrict__ qact, float* __restrict__ a_sum,
               char* __restrict__ a_i8) {
  __shared__ int red[256];
  const int t = blockIdx.x, tid = threadIdx.x;
  const int* row = qact + (size_t)t * HID + tid * 16;
  int s = 0;
  c16 o;
#pragma unroll
  for (int i = 0; i < 4; i++) {
    int4 v = *(const int4*)(row + i * 4);
    s += v.x + v.y + v.z + v.w;
    o[i*4+0] = (char)v.x; o[i*4+1] = (char)v.y;
    o[i*4+2] = (char)v.z; o[i*4+3] = (char)v.w;
  }
  *(c16*)(a_i8 + (size_t)t * HID + tid * 16) = o;
  red[tid] = s; __syncthreads();
  for (int off = 128; off > 0; off >>= 1) {
    if (tid < off) red[tid] += red[tid + off];
    __syncthreads();
  }
  if (tid == 0) a_sum[t] = (float)red[0];
}

// ---------------- int32 -> int8 pack (weights) ----------------
__global__ __launch_bounds__(256)
void conv_i2c(const int* __restrict__ src, char* __restrict__ dst, int n16) {
  int idx = blockIdx.x * 256 + threadIdx.x;
  if (idx >= n16) return;
  const int4* s4 = (const int4*)src + (size_t)idx * 4;
  c16 o;
#pragma unroll
  for (int j = 0; j < 4; j++) {
    int4 v = s4[j];
    o[j*4+0] = (char)v.x; o[j*4+1] = (char)v.y;
    o[j*4+2] = (char)v.z; o[j*4+3] = (char)v.w;
  }
  *(c16*)(dst + (size_t)idx * 16) = o;
}

// ---------------- W4A8 GEMM, exact i8 MFMA (pre-packed weights only) ------
__global__ __launch_bounds__(256)
void gemm_i8(const char* __restrict__ A, const char* __restrict__ W,
             const float* __restrict__ s_a, const float* __restrict__ asum,
             const float* __restrict__ s_w, const float* __restrict__ z_w,
             float* __restrict__ C, int M, int N, int K) {
  __shared__ __align__(16) char As[128 * 64];
  __shared__ __align__(16) char Bs[128 * 64];
  const int tid = threadIdx.x;
  const int lane = tid & 63;
  const int quad = lane >> 4, l15 = lane & 15;
  const int wave = tid >> 6;
  const int wm = (wave >> 1) * 64, wn = (wave & 1) * 64;
  const int bm = blockIdx.y * 128, bn = blockIdx.x * 128;
  const int sr = tid >> 2, sc = (tid & 3) * 16;

  ifrag acc[4][4];
#pragma unroll
  for (int mi = 0; mi < 4; mi++)
#pragma unroll
    for (int ni = 0; ni < 4; ni++)
      acc[mi][ni] = (ifrag){0, 0, 0, 0};

  for (int k0 = 0; k0 < K; k0 += 64) {
#pragma unroll
    for (int it = 0; it < 2; it++) {
      gload_lds16(A + (size_t)(bm + it * 64 + sr) * K + k0 + sc,
                  &As[it * 4096 + wave * 1024]);
      gload_lds16(W + (size_t)(bn + it * 64 + sr) * K + k0 + sc,
                  &Bs[it * 4096 + wave * 1024]);
    }
    __syncthreads();

    ifrag af[4], bfv[4];
#pragma unroll
    for (int mi = 0; mi < 4; mi++)
      af[mi] = *(const ifrag*)&As[(wm + mi * 16 + l15) * 64 + quad * 16];
#pragma unroll
    for (int ni = 0; ni < 4; ni++)
      bfv[ni] = *(const ifrag*)&Bs[(wn + ni * 16 + l15) * 64 + quad * 16];
#pragma unroll
    for (int mi = 0; mi < 4; mi++)
#pragma unroll
      for (int ni = 0; ni < 4; ni++)
        acc[mi][ni] = __builtin_amdgcn_mfma_i32_16x16x64_i8(
            af[mi], bfv[ni], acc[mi][ni], 0, 0, 0);
    __syncthreads();
  }

#pragma unroll
  for (int mi = 0; mi < 4; mi++) {
    int row0 = bm + wm + mi * 16 + quad * 4;
#pragma unroll
    for (int r = 0; r < 4; r++) {
      int row = row0 + r;
      float sa = s_a[row], av = asum[row];
#pragma unroll
      for (int ni = 0; ni < 4; ni++) {
        int col = bn + wn + ni * 16 + l15;
        C[(size_t)row * N + col] = (sa * s_w[col]) * ((float)acc[mi][ni][r] - z_w[col] * av);
      }
    }
  }
}

// ---- split/rope: y<NKV: K rope->hi/lo + V->bf16 transposed; else Q rope in-place
__global__ __launch_bounds__(256)
void split_kv(float* __restrict__ qkv, const int* __restrict__ positions,
              short* __restrict__ Kh, short* __restrict__ Kl,
              short* __restrict__ Vth) {
  __shared__ __align__(16) short Vh_lds[128 * 72];
  const int y = blockIdx.y;
  const int t0 = blockIdx.x * 64;
  const int tid = threadIdx.x;

  if (y >= NKV) {                      // ---- Q: rope in place ----
    const int h = y - NKV;
#pragma unroll
    for (int it = 0; it < 4; it++) {
      int c = tid + 256 * it;
      int key = c >> 4, dc = c & 15;
      float* qr = qkv + (size_t)(t0 + key) * QKV_OUT + (size_t)h * HD;
      float4 a = *(const float4*)(qr + dc * 4);
      float4 b = *(const float4*)(qr + dc * 4 + 64);
      float av[4] = {a.x, a.y, a.z, a.w};
      float bv[4] = {b.x, b.y, b.z, b.w};
      float pos = (float)positions[t0 + key];
#pragma unroll
      for (int jj = 0; jj < 4; jj++) {
        float fr = pos * exp2f(-ROPE_C * (float)(dc * 4 + jj));
        float sn, cs; sincosf(fr, &sn, &cs);
        float x1 = av[jj], x2 = bv[jj];
        av[jj] = x1 * cs - x2 * sn;
        bv[jj] = x2 * cs + x1 * sn;
      }
      *(float4*)(qr + dc * 4)      = make_float4(av[0], av[1], av[2], av[3]);
      *(float4*)(qr + dc * 4 + 64) = make_float4(bv[0], bv[1], bv[2], bv[3]);
    }
    return;
  }

  const int kvh = y;
  // K: rope + hi/lo split
#pragma unroll
  for (int it = 0; it < 4; it++) {
    int c = tid + 256 * it;
    int key = c >> 4, dc = c & 15;
    const float* kr = qkv + (size_t)(t0 + key) * QKV_OUT
                      + (size_t)NH * HD + (size_t)kvh * HD;
    float4 a = *(const float4*)(kr + dc * 4);
    float4 b = *(const float4*)(kr + dc * 4 + 64);
    float av[4] = {a.x, a.y, a.z, a.w};
    float bv[4] = {b.x, b.y, b.z, b.w};
    float pos = (float)positions[t0 + key];
    short4 ha, la, hb, lb;
    short hh, ll;
#pragma unroll
    for (int jj = 0; jj < 4; jj++) {
      float fr = pos * exp2f(-ROPE_C * (float)(dc * 4 + jj));
      float sn, cs; sincosf(fr, &sn, &cs);
      float x1 = av[jj], x2 = bv[jj];
      float r1 = x1 * cs - x2 * sn;
      float r2 = x2 * cs + x1 * sn;
      split2(r1, hh, ll); ((short*)&ha)[jj] = hh; ((short*)&la)[jj] = ll;
      split2(r2, hh, ll); ((short*)&hb)[jj] = hh; ((short*)&lb)[jj] = ll;
    }
    size_t o1 = (size_t)kvh * T * HD + (size_t)(t0 + key) * HD + dc * 4;
    *(short4*)(Kh + o1) = ha;      *(short4*)(Kl + o1) = la;
    *(short4*)(Kh + o1 + 64) = hb; *(short4*)(Kl + o1 + 64) = lb;
  }
  // V -> bf16 transposed
#pragma unroll
  for (int i = 0; i < 8; i++) {
    int c = tid + 256 * i;
    int key = c >> 5, dc = c & 31;
    float4 f = *(const float4*)(qkv + (size_t)(t0 + key) * QKV_OUT
                                + (size_t)(NH + NKV) * HD + (size_t)kvh * HD + dc * 4);
    Vh_lds[(dc*4+0)*72 + key] = f2bf(f.x);
    Vh_lds[(dc*4+1)*72 + key] = f2bf(f.y);
    Vh_lds[(dc*4+2)*72 + key] = f2bf(f.z);
    Vh_lds[(dc*4+3)*72 + key] = f2bf(f.w);
  }
  __syncthreads();
#pragma unroll
  for (int i = 0; i < 2; i++) {
    int c = tid + 256 * i;
    int row = c >> 2, cc = c & 3;
    size_t o = (size_t)kvh * HD * T + (size_t)row * T + t0 + cc * 8;
    *(bfrag*)(Vth + o) = *(const bfrag*)&Vh_lds[row * 72 + cc * 8];
  }
#pragma unroll
  for (int i = 0; i < 2; i++) {
    int c = tid + 256 * i;
    int row = c >> 2, cc = c & 3;
    size_t o = (size_t)kvh * HD * T + (size_t)row * T + t0 + 32 + cc * 8;
    *(bfrag*)(Vth + o) = *(const bfrag*)&Vh_lds[row * 72 + 32 + cc * 8];
  }
}

// ---------------- MFMA flash attention ------------------------------------
// R2 post-mortem: occupancy stuck at 2 blocks/CU because TOTAL regs/wave
// (124 arch + ~44 acc ~ 168) exceeds the 3-waves/SIMD budget on the unified
// gfx950 RF (R1 proved 128-total -> 4 blocks/CU resident). This version:
//  - ql[4] (16 VGPR) moved to per-wave LDS (Qlo, 16KB) -> ~152 total regs,
//    target 3 waves/SIMD. LDS 48KB -> 3 blocks/CU (consistent).
//  - per-qtile blocks (grid 256 x NKV, qt descending = longest first) so the
//    3-blocks/CU residency has no generation tail; split-K halves kept.
//  - exp2-domain softmax (QS2 folded into Q prescale) + defer-max THR=10:
//    rescale of o[8] skipped unless row max grows > 10 (log2).
__global__ __launch_bounds__(256)
void attn_kernel(const float* __restrict__ qkv,
                 const short* __restrict__ Kh, const short* __restrict__ Kl,
                 const short* __restrict__ Vth,
                 float* __restrict__ Opart, float* __restrict__ Mp,
                 float* __restrict__ Lp, float* __restrict__ attn) {
  __shared__ __align__(16) short Ksh[32 * 136];   // +4 banks/row: 2-way, free
  __shared__ __align__(16) short Ksl[32 * 136];
  __shared__ __align__(16) short Vsh[128 * 40];   // +20 banks/row: 2-way, free
  __shared__ __align__(16) short Psh[4 * 16 * 40];
  __shared__ __align__(16) short Qlo[4 * 4 * 512];  // [wave][kc][lane*8]

  const int kvh = blockIdx.y;
  const int qt  = 127 - (int)(blockIdx.x >> 1);  // longest blocks first
  const int half = blockIdx.x & 1;               // split-K half
  const int tid = threadIdx.x;
  const int lane = tid & 63;
  const int wv = tid >> 6;
  const int l15 = lane & 15, quad = lane >> 4;
  const int h = kvh * 4 + wv;
  short* Pw = Psh + wv * 16 * 40;

  const short* KhB = Kh + (size_t)kvh * T * HD;
  const short* KlB = Kl + (size_t)kvh * T * HD;
  const short* VhB = Vth + (size_t)kvh * HD * T;

  const int kr = tid >> 4, kc8 = (tid & 15) * 8;   // K staging: rows kr, kr+16
  const int vd = tid >> 2, vc8 = (tid & 3) * 8;    // V staging: dims vd, vd+64

  bfrag rkh0, rkh1, rkl0, rkl1, rv0, rv1;
  auto preload = [&](int k0) {
    rkh0 = *(const bfrag*)(KhB + (size_t)(k0 + kr) * HD + kc8);
    rkh1 = *(const bfrag*)(KhB + (size_t)(k0 + kr + 16) * HD + kc8);
    rkl0 = *(const bfrag*)(KlB + (size_t)(k0 + kr) * HD + kc8);
    rkl1 = *(const bfrag*)(KlB + (size_t)(k0 + kr + 16) * HD + kc8);
    rv0  = *(const bfrag*)(VhB + (size_t)vd * T + k0 + vc8);
    rv1  = *(const bfrag*)(VhB + (size_t)(vd + 64) * T + k0 + vc8);
  };
  preload(half * 32);

  bfrag ones;
#pragma unroll
  for (int j = 0; j < 8; j++) ones[j] = (short)0x3f80;

  const int q0 = qt * 16;
  const int nk = (q0 >> 5) + 1;              // keys 0..q0+15

  // Q fragments (roped fp32), prescaled by QS2, bf16x2 split; lo part -> LDS
  bfrag qh[4];
  const float* qrow = qkv + (size_t)(q0 + l15) * QKV_OUT + (size_t)h * HD;
#pragma unroll
  for (int kc = 0; kc < 4; kc++) {
    float4 f0 = *(const float4*)(qrow + kc * 32 + quad * 8);
    float4 f1 = *(const float4*)(qrow + kc * 32 + quad * 8 + 4);
    float fv[8] = {f0.x, f0.y, f0.z, f0.w, f1.x, f1.y, f1.z, f1.w};
    bfrag qhv, qlv;
#pragma unroll
    for (int j = 0; j < 8; j++) {
      short hi, lo; split2(fv[j] * QS2, hi, lo);
      qhv[j] = hi; qlv[j] = lo;
    }
    qh[kc] = qhv;
    *(bfrag*)&Qlo[(wv * 4 + kc) * 512 + lane * 8] = qlv;
  }

  ffrag o[8], ol;
  ol = (ffrag){0.f, 0.f, 0.f, 0.f};
#pragma unroll
  for (int n = 0; n < 8; n++) o[n] = (ffrag){0.f, 0.f, 0.f, 0.f};
  float m_i[4] = {-1e30f, -1e30f, -1e30f, -1e30f};

  for (int kt = half; kt < nk; kt += 2) {    // interleaved split-K half
    const int k0 = kt << 5;
    __syncthreads();                         // prev LDS consumed
    *(bfrag*)&Ksh[kr * 136 + kc8] = rkh0;
    *(bfrag*)&Ksh[(kr + 16) * 136 + kc8] = rkh1;
    *(bfrag*)&Ksl[kr * 136 + kc8] = rkl0;
    *(bfrag*)&Ksl[(kr + 16) * 136 + kc8] = rkl1;
    *(bfrag*)&Vsh[vd * 40 + vc8] = rv0;
    *(bfrag*)&Vsh[(vd + 64) * 40 + vc8] = rv1;
    if (kt + 2 < nk) preload(k0 + 64);       // hidden behind compute
    __syncthreads();

    // ---- S = Q K^T (exact via hi/lo split; log2-domain prescaled) ----
    ffrag s[2];
    s[0] = (ffrag){0.f,0.f,0.f,0.f}; s[1] = (ffrag){0.f,0.f,0.f,0.f};
#pragma unroll
    for (int kc = 0; kc < 4; kc++) {
      bfrag qlv = *(const bfrag*)&Qlo[(wv * 4 + kc) * 512 + lane * 8];
#pragma unroll
      for (int n = 0; n < 2; n++) {
        bfrag bh = *(const bfrag*)&Ksh[(n*16 + l15) * 136 + kc*32 + quad*8];
        bfrag bl = *(const bfrag*)&Ksl[(n*16 + l15) * 136 + kc*32 + quad*8];
        s[n] = __builtin_amdgcn_mfma_f32_16x16x32_bf16(qh[kc], bh, s[n], 0,0,0);
        s[n] = __builtin_amdgcn_mfma_f32_16x16x32_bf16(qh[kc], bl, s[n], 0,0,0);
        s[n] = __builtin_amdgcn_mfma_f32_16x16x32_bf16(qlv,    bh, s[n], 0,0,0);
      }
    }
    // ---- online softmax (log2 domain, defer-max) ----
    const bool lastkt = (kt == nk - 1);
    float sv[2][4];
#pragma unroll
    for (int n = 0; n < 2; n++)
#pragma unroll
      for (int r = 0; r < 4; r++) {
        float v = s[n][r];
        if (lastkt) {
          int key = k0 + n * 16 + l15;
          int row = q0 + quad * 4 + r;
          if (key > row) v = -1e30f;
        }
        sv[n][r] = v;
      }
    float mt[4];
    bool trig = false;
#pragma unroll
    for (int r = 0; r < 4; r++) {
      float m2 = fmaxf(sv[0][r], sv[1][r]);
      m2 = fmaxf(m2, __shfl_xor(m2, 1));
      m2 = fmaxf(m2, __shfl_xor(m2, 2));
      m2 = fmaxf(m2, __shfl_xor(m2, 4));
      m2 = fmaxf(m2, __shfl_xor(m2, 8));
      mt[r] = m2;
      trig = trig || (m2 > m_i[r] + DEFER_THR);
    }
    if (__any(trig)) {                       // rare after the first tile
#pragma unroll
      for (int r = 0; r < 4; r++) {
        float mn = fmaxf(m_i[r], mt[r]);
        float a = exp2f(m_i[r] - mn);
        m_i[r] = mn;
        ol[r] *= a;
#pragma unroll
        for (int n = 0; n < 8; n++) o[n][r] *= a;
      }
    }
#pragma unroll
    for (int n = 0; n < 2; n++)
#pragma unroll
      for (int r = 0; r < 4; r++) {
        float p = exp2f(sv[n][r] - m_i[r]);   // bounded by 2^DEFER_THR
        Pw[(quad*4 + r) * 40 + n*16 + l15] = f2bf(p);
      }
    // ---- PV; l via ones-MFMA (same wave wrote Pw, no barrier) ----
    bfrag ph = *(const bfrag*)&Pw[l15 * 40 + quad * 8];
    ol = __builtin_amdgcn_mfma_f32_16x16x32_bf16(ph, ones, ol, 0,0,0);
#pragma unroll
    for (int n = 0; n < 8; n++) {
      bfrag vh = *(const bfrag*)&Vsh[(n*16 + l15) * 40 + quad * 8];
      o[n] = __builtin_amdgcn_mfma_f32_16x16x32_bf16(ph, vh, o[n], 0,0,0);
    }
  }

  // ---- write unnormalized partial (o, m, l) for this half ----
  float* dst = half ? attn : Opart;
#pragma unroll
  for (int n = 0; n < 8; n++)
#pragma unroll
    for (int r = 0; r < 4; r++) {
      int row = q0 + quad * 4 + r;
      dst[(size_t)row * HID + (size_t)h * HD + n * 16 + l15] = o[n][r];
    }
  if (l15 == 0) {
#pragma unroll
    for (int r = 0; r < 4; r++) {
      int row = q0 + quad * 4 + r;
      size_t ix = (size_t)half * NH * T + (size_t)h * T + row;
      Mp[ix] = m_i[r];
      Lp[ix] = ol[r];
    }
  }
}

// ---- split-K combine (log2-domain m): out = (o0*2^(m0-m)+o1*2^(m1-m))/l ----
__global__ __launch_bounds__(256)
void attn_combine(const float* __restrict__ Opart, const float* __restrict__ Mp,
                  const float* __restrict__ Lp, float* attn) {
  const int row = blockIdx.x, tid = threadIdx.x;
  const int h = tid >> 3;                      // 16 floats/thread, within one head
  const float m0 = Mp[(size_t)h * T + row];
  const float m1 = Mp[(size_t)NH * T + (size_t)h * T + row];
  const float l0 = Lp[(size_t)h * T + row];
  const float l1 = Lp[(size_t)NH * T + (size_t)h * T + row];
  const float m = fmaxf(m0, m1);
  float s0 = exp2f(m0 - m), s1 = exp2f(m1 - m);
  const float inv = 1.f / (l0 * s0 + l1 * s1);
  s0 *= inv; s1 *= inv;
  const size_t base = (size_t)row * HID + (size_t)tid * 16;
  float4* dst = (float4*)(attn + base);
  const float4* p0 = (const float4*)(Opart + base);
#pragma unroll
  for (int i = 0; i < 4; i++) {
    float4 a = p0[i];
    float4 b = dst[i];
    dst[i] = make_float4(a.x * s0 + b.x * s1, a.y * s0 + b.y * s1,
                         a.z * s0 + b.z * s1, a.w * s0 + b.w * s1);
  }
}

// ---------------- dynamic quant with sum (i8 out) ----------------
__global__ __launch_bounds__(256)
void quant_kernel(const float* __restrict__ x, char* __restrict__ q2,
                  float* __restrict__ s2, float* __restrict__ sum2) {
  __shared__ float red[256];
  const int t = blockIdx.x, tid = threadIdx.x;
  const float* row = x + (size_t)t * HID;
  float4 v[4];
  float m = 0.f;
#pragma unroll
  for (int i = 0; i < 4; i++) {
    v[i] = *(const float4*)(row + tid * 16 + i * 4);
    m = fmaxf(m, fmaxf(fmaxf(fabsf(v[i].x), fabsf(v[i].y)),
                       fmaxf(fabsf(v[i].z), fabsf(v[i].w))));
  }
  red[tid] = m; __syncthreads();
  for (int off = 128; off > 0; off >>= 1) {
    if (tid < off) red[tid] = fmaxf(red[tid], red[tid + off]);
    __syncthreads();
  }
  float s = fmaxf(red[0], 1e-8f) / 127.f;
  __syncthreads();
  float ssum = 0.f;
  c16 o;
#pragma unroll
  for (int i = 0; i < 4; i++) {
    float q;
    q = fminf(127.f, fmaxf(-127.f, rintf(v[i].x / s))); ssum += q; o[i*4+0] = (char)(int)q;
    q = fminf(127.f, fmaxf(-127.f, rintf(v[i].y / s))); ssum += q; o[i*4+1] = (char)(int)q;
    q = fminf(127.f, fmaxf(-127.f, rintf(v[i].z / s))); ssum += q; o[i*4+2] = (char)(int)q;
    q = fminf(127.f, fmaxf(-127.f, rintf(v[i].w / s))); ssum += q; o[i*4+3] = (char)(int)q;
  }
  *(c16*)(q2 + (size_t)t * HID + tid * 16) = o;
  red[tid] = ssum; __syncthreads();
  for (int off = 128; off > 0; off >>= 1) {
    if (tid < off) red[tid] += red[tid + off];
    __syncthreads();
  }
  if (tid == 0) { s2[t] = s; sum2[t] = red[0]; }
}

// ---------------- launch ----------------
// Workspace layout (~110.4 MB, <= 117.5 MB proven):
//   act8+w8 are allocated ADJACENT; their 33,554,432 B exactly hold Opart
//   (T*NH*HD fp32 split-K half-0 partial), dead by the time conv_i2c(w_o) /
//   quant_kernel reuse those regions.
extern "C" void kernel_launch(void* const* d_in, const int* in_sizes, int n_in,
                              void* d_out, int out_size, void* d_ws, size_t ws_size,
                              hipStream_t stream) {
  const int*   positions   = (const int*)d_in[0];
  const int*   q_act       = (const int*)d_in[1];
  const float* act_scale   = (const float*)d_in[2];
  const int*   w_qkv_q     = (const int*)d_in[3];
  const float* w_qkv_scale = (const float*)d_in[4];
  const float* w_qkv_zero  = (const float*)d_in[5];
  const int*   w_o_q       = (const int*)d_in[6];
  const float* w_o_scale   = (const float*)d_in[7];
  const float* w_o_zero    = (const float*)d_in[8];
  float* out = (float*)d_out;

  size_t off = 0;
  auto alloc = [&](size_t bytes) -> void* {
    void* p = (char*)d_ws + off;
    off += (bytes + 255) & ~(size_t)255;
    return p;
  };
  float* qkv   = (float*)alloc((size_t)T * QKV_OUT * 4);         // 50.3 MB
  char*  act8  = (char*)alloc((size_t)T * HID);                  //  8.4 MB (a_i8 / q2 / Opart lo)
  char*  w8    = (char*)alloc((size_t)QKV_OUT * HID);            // 25.2 MB (wqkv / wo / Opart hi)
  short* Kh    = (short*)alloc((size_t)NKV * T * HD * 2);        //  8.4 MB
  short* Kl    = (short*)alloc((size_t)NKV * T * HD * 2);        //  8.4 MB
  short* Vth   = (short*)alloc((size_t)NKV * T * HD * 2);        //  8.4 MB
  float* a_sum = (float*)alloc(T * 4);
  float* s2    = (float*)alloc(T * 4);
  float* sum2  = (float*)alloc(T * 4);
  float* Mp    = (float*)alloc((size_t)2 * NH * T * 4);          //  0.5 MB
  float* Lp    = (float*)alloc((size_t)2 * NH * T * 4);          //  0.5 MB
  float* Opart = (float*)act8;   // spans act8+w8 = exactly T*NH*HD*4 bytes
  (void)ws_size;

  asum_conv<<<T, 256, 0, stream>>>(q_act, a_sum, act8);
  conv_i2c<<<(QKV_OUT * HID / 16 + 255) / 256, 256, 0, stream>>>(
      w_qkv_q, w8, QKV_OUT * HID / 16);
  gemm_i8<<<dim3(QKV_OUT / 128, T / 128), 256, 0, stream>>>(
      act8, w8, act_scale, a_sum, w_qkv_scale, w_qkv_zero, qkv, T, QKV_OUT, HID);
  split_kv<<<dim3(T / 64, NKV + NH), 256, 0, stream>>>(qkv, positions, Kh, Kl, Vth);
  attn_kernel<<<dim3(256, NKV), 256, 0, stream>>>(
      qkv, Kh, Kl, Vth, Opart, Mp, Lp, out);
  attn_combine<<<T, 256, 0, stream>>>(Opart, Mp, Lp, out);
  conv_i2c<<<(HID * HID / 16 + 255) / 256, 256, 0, stream>>>(
      w_o_q, w8, HID * HID / 16);                 // Opart dead; reuse w8
  quant_kernel<<<T, 256, 0, stream>>>(out, act8, s2, sum2);   // reuse act8
  gemm_i8<<<dim3(HID / 128, T / 128), 256, 0, stream>>>(
      act8, w8, s2, sum2, w_o_scale, w_o_zero, out, T, HID, HID);
}

// Round 5
// 575.280 us; speedup vs baseline: 1.0428x; 1.0428x over previous
//
#include <hip/hip_runtime.h>

#define T 2048
#define HID 4096
#define NH 32
#define NKV 8
#define HD 128
#define QKV_OUT ((NH + 2*NKV) * HD)   // 6144
#define SCALING 0.08838834764831843f  // 128^-0.5
#define QS2 0.12751744954f            // SCALING * log2(e): QK^T in log2 domain
#define DEFER_THR 10.0f               // defer-max threshold (log2 domain, P<=2^10)
#define ROPE_C 0.20762050593046014f   // log2(10000)/64

typedef __attribute__((ext_vector_type(8))) short bfrag;   // 8 bf16
typedef __attribute__((ext_vector_type(4))) float ffrag;   // 4 f32 acc
typedef __attribute__((ext_vector_type(4))) int  ifrag;    // 16 i8 / 4 i32 acc
typedef __attribute__((ext_vector_type(16))) char c16;

__device__ __forceinline__ short f2bf(float f) {
  unsigned u = __builtin_bit_cast(unsigned, f);
  u += 0x7fffu + ((u >> 16) & 1u);   // RNE
  return (short)(u >> 16);
}

// bf16x2 split: x ~= hi + lo, residual ~2^-17 * |x|
__device__ __forceinline__ void split2(float x, short& hi, short& lo) {
  unsigned u = __builtin_bit_cast(unsigned, x);
  unsigned uh = u + (0x7fffu + ((u >> 16) & 1u));
  hi = (short)(uh >> 16);
  float fh = __builtin_bit_cast(float, uh & 0xffff0000u);
  float r = x - fh;
  unsigned ur = __builtin_bit_cast(unsigned, r);
  ur += 0x7fffu + ((ur >> 16) & 1u);
  lo = (short)(ur >> 16);
}

// async global->LDS, 16 B per lane (LDS dest = wave-uniform base + lane*16)
__device__ __forceinline__ void gload_lds16(const void* g, void* l) {
  __builtin_amdgcn_global_load_lds(
      (const __attribute__((address_space(1))) unsigned int*)g,
      (__attribute__((address_space(3))) unsigned int*)l, 16, 0, 0);
}

// ---------------- fused a_sum + int8 pack of activations ----------------
__global__ __launch_bounds__(256)
void asum_conv(const int* __restrict__ qact, float* __restrict__ a_sum,
               char* __restrict__ a_i8) {
  __shared__ int red[256];
  const int t = blockIdx.x, tid = threadIdx.x;
  const int* row = qact + (size_t)t * HID + tid * 16;
  int s = 0;
  c16 o;
#pragma unroll
  for (int i = 0; i < 4; i++) {
    int4 v = *(const int4*)(row + i * 4);
    s += v.x + v.y + v.z + v.w;
    o[i*4+0] = (char)v.x; o[i*4+1] = (char)v.y;
    o[i*4+2] = (char)v.z; o[i*4+3] = (char)v.w;
  }
  *(c16*)(a_i8 + (size_t)t * HID + tid * 16) = o;
  red[tid] = s; __syncthreads();
  for (int off = 128; off > 0; off >>= 1) {
    if (tid < off) red[tid] += red[tid + off];
    __syncthreads();
  }
  if (tid == 0) a_sum[t] = (float)red[0];
}

// ---------------- int32 -> int8 pack (weights) ----------------
__global__ __launch_bounds__(256)
void conv_i2c(const int* __restrict__ src, char* __restrict__ dst, int n16) {
  int idx = blockIdx.x * 256 + threadIdx.x;
  if (idx >= n16) return;
  const int4* s4 = (const int4*)src + (size_t)idx * 4;
  c16 o;
#pragma unroll
  for (int j = 0; j < 4; j++) {
    int4 v = s4[j];
    o[j*4+0] = (char)v.x; o[j*4+1] = (char)v.y;
    o[j*4+2] = (char)v.z; o[j*4+3] = (char)v.w;
  }
  *(c16*)(dst + (size_t)idx * 16) = o;
}

// ---------------- W4A8 GEMM, exact i8 MFMA (pre-packed weights only) ------
__global__ __launch_bounds__(256)
void gemm_i8(const char* __restrict__ A, const char* __restrict__ W,
             const float* __restrict__ s_a, const float* __restrict__ asum,
             const float* __restrict__ s_w, const float* __restrict__ z_w,
             float* __restrict__ C, int M, int N, int K) {
  __shared__ __align__(16) char As[128 * 64];
  __shared__ __align__(16) char Bs[128 * 64];
  const int tid = threadIdx.x;
  const int lane = tid & 63;
  const int quad = lane >> 4, l15 = lane & 15;
  const int wave = tid >> 6;
  const int wm = (wave >> 1) * 64, wn = (wave & 1) * 64;
  const int bm = blockIdx.y * 128, bn = blockIdx.x * 128;
  const int sr = tid >> 2, sc = (tid & 3) * 16;

  ifrag acc[4][4];
#pragma unroll
  for (int mi = 0; mi < 4; mi++)
#pragma unroll
    for (int ni = 0; ni < 4; ni++)
      acc[mi][ni] = (ifrag){0, 0, 0, 0};

  for (int k0 = 0; k0 < K; k0 += 64) {
#pragma unroll
    for (int it = 0; it < 2; it++) {
      gload_lds16(A + (size_t)(bm + it * 64 + sr) * K + k0 + sc,
                  &As[it * 4096 + wave * 1024]);
      gload_lds16(W + (size_t)(bn + it * 64 + sr) * K + k0 + sc,
                  &Bs[it * 4096 + wave * 1024]);
    }
    __syncthreads();

    ifrag af[4], bfv[4];
#pragma unroll
    for (int mi = 0; mi < 4; mi++)
      af[mi] = *(const ifrag*)&As[(wm + mi * 16 + l15) * 64 + quad * 16];
#pragma unroll
    for (int ni = 0; ni < 4; ni++)
      bfv[ni] = *(const ifrag*)&Bs[(wn + ni * 16 + l15) * 64 + quad * 16];
#pragma unroll
    for (int mi = 0; mi < 4; mi++)
#pragma unroll
      for (int ni = 0; ni < 4; ni++)
        acc[mi][ni] = __builtin_amdgcn_mfma_i32_16x16x64_i8(
            af[mi], bfv[ni], acc[mi][ni], 0, 0, 0);
    __syncthreads();
  }

#pragma unroll
  for (int mi = 0; mi < 4; mi++) {
    int row0 = bm + wm + mi * 16 + quad * 4;
#pragma unroll
    for (int r = 0; r < 4; r++) {
      int row = row0 + r;
      float sa = s_a[row], av = asum[row];
#pragma unroll
      for (int ni = 0; ni < 4; ni++) {
        int col = bn + wn + ni * 16 + l15;
        C[(size_t)row * N + col] = (sa * s_w[col]) * ((float)acc[mi][ni][r] - z_w[col] * av);
      }
    }
  }
}

// ---- split/rope. K and V are written PRE-SWIZZLED (guide rule 21) so the
// attn kernel can stage them with linear global_load_lds and read with the
// matching XOR:
//   K row t: logical 16B-slot s (0..15) stored at u = (s&8)|((s^t)&7)
//   V dim d: logical 16B key-slot q (0..3) stored at q^((d>>1)&3)
__global__ __launch_bounds__(256)
void split_kv(float* __restrict__ qkv, const int* __restrict__ positions,
              short* __restrict__ Kh, short* __restrict__ Kl,
              short* __restrict__ Vth) {
  __shared__ __align__(16) short Vh_lds[128 * 72];
  const int y = blockIdx.y;
  const int t0 = blockIdx.x * 64;
  const int tid = threadIdx.x;

  if (y >= NKV) {                      // ---- Q: rope in place ----
    const int h = y - NKV;
#pragma unroll
    for (int it = 0; it < 4; it++) {
      int c = tid + 256 * it;
      int key = c >> 4, dc = c & 15;
      float* qr = qkv + (size_t)(t0 + key) * QKV_OUT + (size_t)h * HD;
      float4 a = *(const float4*)(qr + dc * 4);
      float4 b = *(const float4*)(qr + dc * 4 + 64);
      float av[4] = {a.x, a.y, a.z, a.w};
      float bv[4] = {b.x, b.y, b.z, b.w};
      float pos = (float)positions[t0 + key];
#pragma unroll
      for (int jj = 0; jj < 4; jj++) {
        float fr = pos * exp2f(-ROPE_C * (float)(dc * 4 + jj));
        float sn, cs; sincosf(fr, &sn, &cs);
        float x1 = av[jj], x2 = bv[jj];
        av[jj] = x1 * cs - x2 * sn;
        bv[jj] = x2 * cs + x1 * sn;
      }
      *(float4*)(qr + dc * 4)      = make_float4(av[0], av[1], av[2], av[3]);
      *(float4*)(qr + dc * 4 + 64) = make_float4(bv[0], bv[1], bv[2], bv[3]);
    }
    return;
  }

  const int kvh = y;
  // K: rope + hi/lo split, swizzled slot placement
#pragma unroll
  for (int it = 0; it < 4; it++) {
    int c = tid + 256 * it;
    int key = c >> 4, dc = c & 15;
    const int t = t0 + key;
    const float* kr = qkv + (size_t)t * QKV_OUT
                      + (size_t)NH * HD + (size_t)kvh * HD;
    float4 a = *(const float4*)(kr + dc * 4);
    float4 b = *(const float4*)(kr + dc * 4 + 64);
    float av[4] = {a.x, a.y, a.z, a.w};
    float bv[4] = {b.x, b.y, b.z, b.w};
    float pos = (float)positions[t];
    short4 ha, la, hb, lb;
    short hh, ll;
#pragma unroll
    for (int jj = 0; jj < 4; jj++) {
      float fr = pos * exp2f(-ROPE_C * (float)(dc * 4 + jj));
      float sn, cs; sincosf(fr, &sn, &cs);
      float x1 = av[jj], x2 = bv[jj];
      float r1 = x1 * cs - x2 * sn;
      float r2 = x2 * cs + x1 * sn;
      split2(r1, hh, ll); ((short*)&ha)[jj] = hh; ((short*)&la)[jj] = ll;
      split2(r2, hh, ll); ((short*)&hb)[jj] = hh; ((short*)&lb)[jj] = ll;
    }
    // logical slots: first write s=dc>>1 (half dc&1), second s=8+(dc>>1)
    const int uu = ((dc >> 1) ^ t) & 7;
    const int h4 = (dc & 1) * 4;
    size_t base = (size_t)kvh * T * HD + (size_t)t * HD;
    *(short4*)(Kh + base + uu * 8 + h4) = ha;
    *(short4*)(Kl + base + uu * 8 + h4) = la;
    *(short4*)(Kh + base + (8 + uu) * 8 + h4) = hb;
    *(short4*)(Kl + base + (8 + uu) * 8 + h4) = lb;
  }
  // V -> bf16 transposed, swizzled key-slot placement within 32-key tiles
#pragma unroll
  for (int i = 0; i < 8; i++) {
    int c = tid + 256 * i;
    int key = c >> 5, dc = c & 31;
    float4 f = *(const float4*)(qkv + (size_t)(t0 + key) * QKV_OUT
                                + (size_t)(NH + NKV) * HD + (size_t)kvh * HD + dc * 4);
    Vh_lds[(dc*4+0)*72 + key] = f2bf(f.x);
    Vh_lds[(dc*4+1)*72 + key] = f2bf(f.y);
    Vh_lds[(dc*4+2)*72 + key] = f2bf(f.z);
    Vh_lds[(dc*4+3)*72 + key] = f2bf(f.w);
  }
  __syncthreads();
#pragma unroll
  for (int i = 0; i < 2; i++) {
    int c = tid + 256 * i;
    int row = c >> 2, cc = c & 3;
    int sd = (row >> 1) & 3;
    size_t o = (size_t)kvh * HD * T + (size_t)row * T + t0 + ((cc ^ sd)) * 8;
    *(bfrag*)(Vth + o) = *(const bfrag*)&Vh_lds[row * 72 + cc * 8];
  }
#pragma unroll
  for (int i = 0; i < 2; i++) {
    int c = tid + 256 * i;
    int row = c >> 2, cc = c & 3;
    int sd = (row >> 1) & 3;
    size_t o = (size_t)kvh * HD * T + (size_t)row * T + t0 + 32 + ((cc ^ sd)) * 8;
    *(bfrag*)(Vth + o) = *(const bfrag*)&Vh_lds[row * 72 + 32 + cc * 8];
  }
}

// ---------------- MFMA flash attention ------------------------------------
// R4 post-mortem: unified-RF occupancy bands at total(arch+acc) regs
// {64,128,256}. R2=168, R4=140 -> both >128 -> 2 waves/SIMD. This version
// removes the 24-VGPR K/V register prefetch entirely: staging is 6x
// global_load_lds (zero VGPRs) into LINEAR swizzled-LDS tiles (sources
// pre-swizzled by split_kv; reads XOR the same pattern -> 2-way = free).
// ql back in regs (no Qlo LDS, no extra ds_reads in QK^T path).
// Target: total <= 128 -> 4 waves/SIMD; LDS 30KB -> >=4 blocks/CU.
// Loop is single-buffer 2-barrier (m97 pattern): cross-wave overlap at
// 4 blocks/CU replaces the lost in-block prefetch (m114 mechanism).
__global__ __launch_bounds__(256)
void attn_kernel(const float* __restrict__ qkv,
                 const short* __restrict__ Kh, const short* __restrict__ Kl,
                 const short* __restrict__ Vth,
                 float* __restrict__ Opart, float* __restrict__ Mp,
                 float* __restrict__ Lp, float* __restrict__ attn) {
  __shared__ __align__(16) short Ksh[32 * 128];   // 8KB, swizzled (see split_kv)
  __shared__ __align__(16) short Ksl[32 * 128];   // 8KB
  __shared__ __align__(16) short Vsh[128 * 32];   // 8KB, swizzled
  __shared__ __align__(16) short Psh[4 * 16 * 40];// 5KB, per-wave, padded

  const int kvh = blockIdx.y;
  const int qt  = 127 - (int)(blockIdx.x >> 1);  // longest blocks first
  const int half = blockIdx.x & 1;               // split-K half
  const int tid = threadIdx.x;
  const int lane = tid & 63;
  const int wv = tid >> 6;
  const int l15 = lane & 15, quad = lane >> 4;
  const int h = kvh * 4 + wv;
  short* Pw = Psh + wv * 16 * 40;

  const short* KhB = Kh + (size_t)kvh * T * HD;
  const short* KlB = Kl + (size_t)kvh * T * HD;
  const short* VhB = Vth + (size_t)kvh * HD * T;

  // staging source offsets (shorts), loop-invariant; dest is linear lane*16
  const int offK0 = (tid >> 4) * 128 + (tid & 15) * 8;          // rows 0..15
  const int offK1 = offK0 + 16 * 128;                           // rows 16..31
  const int offV0 = (tid >> 2) * T + (tid & 3) * 8;             // dims 0..63
  const int offV1 = offV0 + 64 * T;                             // dims 64..127
  const int wv1k = wv * 1024;                                   // byte chunk

  // read-side swizzle constants (lane-invariant per kc)
  const int sdv = (l15 >> 1) & 3;                 // V: q' = quad ^ sdv
  const int vq8 = (quad ^ sdv) * 8;
  int uuk[4];                                     // K: u = (s&8)|((s^l15)&7)
#pragma unroll
  for (int kc = 0; kc < 4; kc++) {
    int s = 4 * kc + quad;
    uuk[kc] = ((s & 8) | ((s ^ l15) & 7)) * 8;
  }

  bfrag ones;
#pragma unroll
  for (int j = 0; j < 8; j++) ones[j] = (short)0x3f80;

  const int q0 = qt * 16;
  const int nk = (q0 >> 5) + 1;              // keys 0..q0+15

  // Q fragments (roped fp32), prescaled by QS2, bf16x2 split, in regs
  bfrag qh[4], ql[4];
  const float* qrow = qkv + (size_t)(q0 + l15) * QKV_OUT + (size_t)h * HD;
#pragma unroll
  for (int kc = 0; kc < 4; kc++) {
    float4 f0 = *(const float4*)(qrow + kc * 32 + quad * 8);
    float4 f1 = *(const float4*)(qrow + kc * 32 + quad * 8 + 4);
    float fv[8] = {f0.x, f0.y, f0.z, f0.w, f1.x, f1.y, f1.z, f1.w};
#pragma unroll
    for (int j = 0; j < 8; j++) {
      short hi, lo; split2(fv[j] * QS2, hi, lo);
      qh[kc][j] = hi; ql[kc][j] = lo;
    }
  }

  ffrag o[8], ol;
  ol = (ffrag){0.f, 0.f, 0.f, 0.f};
#pragma unroll
  for (int n = 0; n < 8; n++) o[n] = (ffrag){0.f, 0.f, 0.f, 0.f};
  float m_i[4] = {-1e30f, -1e30f, -1e30f, -1e30f};

  for (int kt = half; kt < nk; kt += 2) {    // interleaved split-K half
    const int k0 = kt << 5;
    __syncthreads();                         // prev LDS fully consumed
    {
      const short* khs = KhB + (size_t)k0 * HD;
      const short* kls = KlB + (size_t)k0 * HD;
      const short* vs  = VhB + k0;
      gload_lds16(khs + offK0, (char*)Ksh + wv1k);
      gload_lds16(khs + offK1, (char*)Ksh + 4096 + wv1k);
      gload_lds16(kls + offK0, (char*)Ksl + wv1k);
      gload_lds16(kls + offK1, (char*)Ksl + 4096 + wv1k);
      gload_lds16(vs + offV0, (char*)Vsh + wv1k);
      gload_lds16(vs + offV1, (char*)Vsh + 4096 + wv1k);
    }
    __syncthreads();                         // loads landed + visible

    // ---- S = Q K^T (exact via hi/lo split; log2-domain prescaled) ----
    ffrag s[2];
    s[0] = (ffrag){0.f,0.f,0.f,0.f}; s[1] = (ffrag){0.f,0.f,0.f,0.f};
#pragma unroll
    for (int kc = 0; kc < 4; kc++) {
#pragma unroll
      for (int n = 0; n < 2; n++) {
        const int rb = (n * 16 + l15) * 128 + uuk[kc];
        bfrag bh = *(const bfrag*)&Ksh[rb];
        bfrag bl = *(const bfrag*)&Ksl[rb];
        s[n] = __builtin_amdgcn_mfma_f32_16x16x32_bf16(qh[kc], bh, s[n], 0,0,0);
        s[n] = __builtin_amdgcn_mfma_f32_16x16x32_bf16(qh[kc], bl, s[n], 0,0,0);
        s[n] = __builtin_amdgcn_mfma_f32_16x16x32_bf16(ql[kc], bh, s[n], 0,0,0);
      }
    }
    // ---- online softmax (log2 domain, defer-max) ----
    const bool lastkt = (kt == nk - 1);
    float sv[2][4];
#pragma unroll
    for (int n = 0; n < 2; n++)
#pragma unroll
      for (int r = 0; r < 4; r++) {
        float v = s[n][r];
        if (lastkt) {
          int key = k0 + n * 16 + l15;
          int row = q0 + quad * 4 + r;
          if (key > row) v = -1e30f;
        }
        sv[n][r] = v;
      }
    float mt[4];
    bool trig = false;
#pragma unroll
    for (int r = 0; r < 4; r++) {
      float m2 = fmaxf(sv[0][r], sv[1][r]);
      m2 = fmaxf(m2, __shfl_xor(m2, 1));
      m2 = fmaxf(m2, __shfl_xor(m2, 2));
      m2 = fmaxf(m2, __shfl_xor(m2, 4));
      m2 = fmaxf(m2, __shfl_xor(m2, 8));
      mt[r] = m2;
      trig = trig || (m2 > m_i[r] + DEFER_THR);
    }
    if (__any(trig)) {                       // rare after the first tile
#pragma unroll
      for (int r = 0; r < 4; r++) {
        float mn = fmaxf(m_i[r], mt[r]);
        float a = exp2f(m_i[r] - mn);
        m_i[r] = mn;
        ol[r] *= a;
#pragma unroll
        for (int n = 0; n < 8; n++) o[n][r] *= a;
      }
    }
#pragma unroll
    for (int n = 0; n < 2; n++)
#pragma unroll
      for (int r = 0; r < 4; r++) {
        float p = exp2f(sv[n][r] - m_i[r]);   // bounded by 2^DEFER_THR
        Pw[(quad*4 + r) * 40 + n*16 + l15] = f2bf(p);
      }
    // ---- PV; l via ones-MFMA (same wave wrote Pw, no barrier) ----
    bfrag ph = *(const bfrag*)&Pw[l15 * 40 + quad * 8];
    ol = __builtin_amdgcn_mfma_f32_16x16x32_bf16(ph, ones, ol, 0,0,0);
#pragma unroll
    for (int n = 0; n < 8; n++) {
      bfrag vh = *(const bfrag*)&Vsh[(n * 16 + l15) * 32 + vq8];
      o[n] = __builtin_amdgcn_mfma_f32_16x16x32_bf16(ph, vh, o[n], 0,0,0);
    }
  }

  // ---- write unnormalized partial (o, m, l) for this half ----
  float* dst = half ? attn : Opart;
#pragma unroll
  for (int n = 0; n < 8; n++)
#pragma unroll
    for (int r = 0; r < 4; r++) {
      int row = q0 + quad * 4 + r;
      dst[(size_t)row * HID + (size_t)h * HD + n * 16 + l15] = o[n][r];
    }
  if (l15 == 0) {
#pragma unroll
    for (int r = 0; r < 4; r++) {
      int row = q0 + quad * 4 + r;
      size_t ix = (size_t)half * NH * T + (size_t)h * T + row;
      Mp[ix] = m_i[r];
      Lp[ix] = ol[r];
    }
  }
}

// ---- split-K combine (log2-domain m): out = (o0*2^(m0-m)+o1*2^(m1-m))/l ----
__global__ __launch_bounds__(256)
void attn_combine(const float* __restrict__ Opart, const float* __restrict__ Mp,
                  const float* __restrict__ Lp, float* attn) {
  const int row = blockIdx.x, tid = threadIdx.x;
  const int h = tid >> 3;                      // 16 floats/thread, within one head
  const float m0 = Mp[(size_t)h * T + row];
  const float m1 = Mp[(size_t)NH * T + (size_t)h * T + row];
  const float l0 = Lp[(size_t)h * T + row];
  const float l1 = Lp[(size_t)NH * T + (size_t)h * T + row];
  const float m = fmaxf(m0, m1);
  float s0 = exp2f(m0 - m), s1 = exp2f(m1 - m);
  const float inv = 1.f / (l0 * s0 + l1 * s1);
  s0 *= inv; s1 *= inv;
  const size_t base = (size_t)row * HID + (size_t)tid * 16;
  float4* dst = (float4*)(attn + base);
  const float4* p0 = (const float4*)(Opart + base);
#pragma unroll
  for (int i = 0; i < 4; i++) {
    float4 a = p0[i];
    float4 b = dst[i];
    dst[i] = make_float4(a.x * s0 + b.x * s1, a.y * s0 + b.y * s1,
                         a.z * s0 + b.z * s1, a.w * s0 + b.w * s1);
  }
}

// ---------------- dynamic quant with sum (i8 out) ----------------
__global__ __launch_bounds__(256)
void quant_kernel(const float* __restrict__ x, char* __restrict__ q2,
                  float* __restrict__ s2, float* __restrict__ sum2) {
  __shared__ float red[256];
  const int t = blockIdx.x, tid = threadIdx.x;
  const float* row = x + (size_t)t * HID;
  float4 v[4];
  float m = 0.f;
#pragma unroll
  for (int i = 0; i < 4; i++) {
    v[i] = *(const float4*)(row + tid * 16 + i * 4);
    m = fmaxf(m, fmaxf(fmaxf(fabsf(v[i].x), fabsf(v[i].y)),
                       fmaxf(fabsf(v[i].z), fabsf(v[i].w))));
  }
  red[tid] = m; __syncthreads();
  for (int off = 128; off > 0; off >>= 1) {
    if (tid < off) red[tid] = fmaxf(red[tid], red[tid + off]);
    __syncthreads();
  }
  float s = fmaxf(red[0], 1e-8f) / 127.f;
  __syncthreads();
  float ssum = 0.f;
  c16 o;
#pragma unroll
  for (int i = 0; i < 4; i++) {
    float q;
    q = fminf(127.f, fmaxf(-127.f, rintf(v[i].x / s))); ssum += q; o[i*4+0] = (char)(int)q;
    q = fminf(127.f, fmaxf(-127.f, rintf(v[i].y / s))); ssum += q; o[i*4+1] = (char)(int)q;
    q = fminf(127.f, fmaxf(-127.f, rintf(v[i].z / s))); ssum += q; o[i*4+2] = (char)(int)q;
    q = fminf(127.f, fmaxf(-127.f, rintf(v[i].w / s))); ssum += q; o[i*4+3] = (char)(int)q;
  }
  *(c16*)(q2 + (size_t)t * HID + tid * 16) = o;
  red[tid] = ssum; __syncthreads();
  for (int off = 128; off > 0; off >>= 1) {
    if (tid < off) red[tid] += red[tid + off];
    __syncthreads();
  }
  if (tid == 0) { s2[t] = s; sum2[t] = red[0]; }
}

// ---------------- launch ----------------
// Workspace layout (~110.4 MB, <= 117.5 MB proven):
//   act8+w8 are allocated ADJACENT; their 33,554,432 B exactly hold Opart
//   (T*NH*HD fp32 split-K half-0 partial), dead by the time conv_i2c(w_o) /
//   quant_kernel reuse those regions.
extern "C" void kernel_launch(void* const* d_in, const int* in_sizes, int n_in,
                              void* d_out, int out_size, void* d_ws, size_t ws_size,
                              hipStream_t stream) {
  const int*   positions   = (const int*)d_in[0];
  const int*   q_act       = (const int*)d_in[1];
  const float* act_scale   = (const float*)d_in[2];
  const int*   w_qkv_q     = (const int*)d_in[3];
  const float* w_qkv_scale = (const float*)d_in[4];
  const float* w_qkv_zero  = (const float*)d_in[5];
  const int*   w_o_q       = (const int*)d_in[6];
  const float* w_o_scale   = (const float*)d_in[7];
  const float* w_o_zero    = (const float*)d_in[8];
  float* out = (float*)d_out;

  size_t off = 0;
  auto alloc = [&](size_t bytes) -> void* {
    void* p = (char*)d_ws + off;
    off += (bytes + 255) & ~(size_t)255;
    return p;
  };
  float* qkv   = (float*)alloc((size_t)T * QKV_OUT * 4);         // 50.3 MB
  char*  act8  = (char*)alloc((size_t)T * HID);                  //  8.4 MB (a_i8 / q2 / Opart lo)
  char*  w8    = (char*)alloc((size_t)QKV_OUT * HID);            // 25.2 MB (wqkv / wo / Opart hi)
  short* Kh    = (short*)alloc((size_t)NKV * T * HD * 2);        //  8.4 MB
  short* Kl    = (short*)alloc((size_t)NKV * T * HD * 2);        //  8.4 MB
  short* Vth   = (short*)alloc((size_t)NKV * T * HD * 2);        //  8.4 MB
  float* a_sum = (float*)alloc(T * 4);
  float* s2    = (float*)alloc(T * 4);
  float* sum2  = (float*)alloc(T * 4);
  float* Mp    = (float*)alloc((size_t)2 * NH * T * 4);          //  0.5 MB
  float* Lp    = (float*)alloc((size_t)2 * NH * T * 4);          //  0.5 MB
  float* Opart = (float*)act8;   // spans act8+w8 = exactly T*NH*HD*4 bytes
  (void)ws_size;

  asum_conv<<<T, 256, 0, stream>>>(q_act, a_sum, act8);
  conv_i2c<<<(QKV_OUT * HID / 16 + 255) / 256, 256, 0, stream>>>(
      w_qkv_q, w8, QKV_OUT * HID / 16);
  gemm_i8<<<dim3(QKV_OUT / 128, T / 128), 256, 0, stream>>>(
      act8, w8, act_scale, a_sum, w_qkv_scale, w_qkv_zero, qkv, T, QKV_OUT, HID);
  split_kv<<<dim3(T / 64, NKV + NH), 256, 0, stream>>>(qkv, positions, Kh, Kl, Vth);
  attn_kernel<<<dim3(256, NKV), 256, 0, stream>>>(
      qkv, Kh, Kl, Vth, Opart, Mp, Lp, out);
  attn_combine<<<T, 256, 0, stream>>>(Opart, Mp, Lp, out);
  conv_i2c<<<(HID * HID / 16 + 255) / 256, 256, 0, stream>>>(
      w_o_q, w8, HID * HID / 16);                 // Opart dead; reuse w8
  quant_kernel<<<T, 256, 0, stream>>>(out, act8, s2, sum2);   // reuse act8
  gemm_i8<<<dim3(HID / 128, T / 128), 256, 0, stream>>>(
      act8, w8, s2, sum2, w_o_scale, w_o_zero, out, T, HID, HID);
}

// Round 6
// 557.052 us; speedup vs baseline: 1.0769x; 1.0327x over previous
//
#include <hip/hip_runtime.h>

#define T 2048
#define HID 4096
#define NH 32
#define NKV 8
#define HD 128
#define QKV_OUT ((NH + 2*NKV) * HD)   // 6144
#define SCALING 0.08838834764831843f  // 128^-0.5
#define QS2 0.12751744954f            // SCALING * log2(e): QK^T in log2 domain
#define DEFER_THR 10.0f               // defer-max threshold (log2 domain, P<=2^10)
#define ROPE_C 0.20762050593046014f   // log2(10000)/64

typedef __attribute__((ext_vector_type(8))) short bfrag;   // 8 bf16
typedef __attribute__((ext_vector_type(4))) float ffrag;   // 4 f32 acc
typedef __attribute__((ext_vector_type(4))) int  ifrag;    // 16 i8 / 4 i32 acc
typedef __attribute__((ext_vector_type(16))) char c16;

__device__ __forceinline__ short f2bf(float f) {
  unsigned u = __builtin_bit_cast(unsigned, f);
  u += 0x7fffu + ((u >> 16) & 1u);   // RNE
  return (short)(u >> 16);
}

// bf16x2 split: x ~= hi + lo, residual ~2^-17 * |x|
__device__ __forceinline__ void split2(float x, short& hi, short& lo) {
  unsigned u = __builtin_bit_cast(unsigned, x);
  unsigned uh = u + (0x7fffu + ((u >> 16) & 1u));
  hi = (short)(uh >> 16);
  float fh = __builtin_bit_cast(float, uh & 0xffff0000u);
  float r = x - fh;
  unsigned ur = __builtin_bit_cast(unsigned, r);
  ur += 0x7fffu + ((ur >> 16) & 1u);
  lo = (short)(ur >> 16);
}

// async global->LDS, 16 B per lane (LDS dest = wave-uniform base + lane*16)
__device__ __forceinline__ void gload_lds16(const void* g, void* l) {
  __builtin_amdgcn_global_load_lds(
      (const __attribute__((address_space(1))) unsigned int*)g,
      (__attribute__((address_space(3))) unsigned int*)l, 16, 0, 0);
}

// ---------------- fused a_sum + int8 pack of activations ----------------
__global__ __launch_bounds__(256)
void asum_conv(const int* __restrict__ qact, float* __restrict__ a_sum,
               char* __restrict__ a_i8) {
  __shared__ int red[256];
  const int t = blockIdx.x, tid = threadIdx.x;
  const int* row = qact + (size_t)t * HID + tid * 16;
  int s = 0;
  c16 o;
#pragma unroll
  for (int i = 0; i < 4; i++) {
    int4 v = *(const int4*)(row + i * 4);
    s += v.x + v.y + v.z + v.w;
    o[i*4+0] = (char)v.x; o[i*4+1] = (char)v.y;
    o[i*4+2] = (char)v.z; o[i*4+3] = (char)v.w;
  }
  *(c16*)(a_i8 + (size_t)t * HID + tid * 16) = o;
  red[tid] = s; __syncthreads();
  for (int off = 128; off > 0; off >>= 1) {
    if (tid < off) red[tid] += red[tid + off];
    __syncthreads();
  }
  if (tid == 0) a_sum[t] = (float)red[0];
}

// ---------------- int32 -> int8 pack (weights) ----------------
__global__ __launch_bounds__(256)
void conv_i2c(const int* __restrict__ src, char* __restrict__ dst, int n16) {
  int idx = blockIdx.x * 256 + threadIdx.x;
  if (idx >= n16) return;
  const int4* s4 = (const int4*)src + (size_t)idx * 4;
  c16 o;
#pragma unroll
  for (int j = 0; j < 4; j++) {
    int4 v = s4[j];
    o[j*4+0] = (char)v.x; o[j*4+1] = (char)v.y;
    o[j*4+2] = (char)v.z; o[j*4+3] = (char)v.w;
  }
  *(c16*)(dst + (size_t)idx * 16) = o;
}

// ---------------- W4A8 GEMM, exact i8 MFMA (pre-packed weights only) ------
__global__ __launch_bounds__(256)
void gemm_i8(const char* __restrict__ A, const char* __restrict__ W,
             const float* __restrict__ s_a, const float* __restrict__ asum,
             const float* __restrict__ s_w, const float* __restrict__ z_w,
             float* __restrict__ C, int M, int N, int K) {
  __shared__ __align__(16) char As[128 * 64];
  __shared__ __align__(16) char Bs[128 * 64];
  const int tid = threadIdx.x;
  const int lane = tid & 63;
  const int quad = lane >> 4, l15 = lane & 15;
  const int wave = tid >> 6;
  const int wm = (wave >> 1) * 64, wn = (wave & 1) * 64;
  const int bm = blockIdx.y * 128, bn = blockIdx.x * 128;
  const int sr = tid >> 2, sc = (tid & 3) * 16;

  ifrag acc[4][4];
#pragma unroll
  for (int mi = 0; mi < 4; mi++)
#pragma unroll
    for (int ni = 0; ni < 4; ni++)
      acc[mi][ni] = (ifrag){0, 0, 0, 0};

  for (int k0 = 0; k0 < K; k0 += 64) {
#pragma unroll
    for (int it = 0; it < 2; it++) {
      gload_lds16(A + (size_t)(bm + it * 64 + sr) * K + k0 + sc,
                  &As[it * 4096 + wave * 1024]);
      gload_lds16(W + (size_t)(bn + it * 64 + sr) * K + k0 + sc,
                  &Bs[it * 4096 + wave * 1024]);
    }
    __syncthreads();

    ifrag af[4], bfv[4];
#pragma unroll
    for (int mi = 0; mi < 4; mi++)
      af[mi] = *(const ifrag*)&As[(wm + mi * 16 + l15) * 64 + quad * 16];
#pragma unroll
    for (int ni = 0; ni < 4; ni++)
      bfv[ni] = *(const ifrag*)&Bs[(wn + ni * 16 + l15) * 64 + quad * 16];
#pragma unroll
    for (int mi = 0; mi < 4; mi++)
#pragma unroll
      for (int ni = 0; ni < 4; ni++)
        acc[mi][ni] = __builtin_amdgcn_mfma_i32_16x16x64_i8(
            af[mi], bfv[ni], acc[mi][ni], 0, 0, 0);
    __syncthreads();
  }

#pragma unroll
  for (int mi = 0; mi < 4; mi++) {
    int row0 = bm + wm + mi * 16 + quad * 4;
#pragma unroll
    for (int r = 0; r < 4; r++) {
      int row = row0 + r;
      float sa = s_a[row], av = asum[row];
#pragma unroll
      for (int ni = 0; ni < 4; ni++) {
        int col = bn + wn + ni * 16 + l15;
        C[(size_t)row * N + col] = (sa * s_w[col]) * ((float)acc[mi][ni][r] - z_w[col] * av);
      }
    }
  }
}

// ---- split/rope. K and V are written PRE-SWIZZLED (guide rule 21) so the
// attn kernel can stage them with linear global_load_lds and read with the
// matching XOR:
//   K row t: logical 16B-slot s (0..15) stored at u = (s&8)|((s^t)&7)
//   V dim d: logical 16B key-slot q (0..3) stored at q^((d>>1)&3)
__global__ __launch_bounds__(256)
void split_kv(float* __restrict__ qkv, const int* __restrict__ positions,
              short* __restrict__ Kh, short* __restrict__ Kl,
              short* __restrict__ Vth) {
  __shared__ __align__(16) short Vh_lds[128 * 72];
  const int y = blockIdx.y;
  const int t0 = blockIdx.x * 64;
  const int tid = threadIdx.x;

  if (y >= NKV) {                      // ---- Q: rope in place ----
    const int h = y - NKV;
#pragma unroll
    for (int it = 0; it < 4; it++) {
      int c = tid + 256 * it;
      int key = c >> 4, dc = c & 15;
      float* qr = qkv + (size_t)(t0 + key) * QKV_OUT + (size_t)h * HD;
      float4 a = *(const float4*)(qr + dc * 4);
      float4 b = *(const float4*)(qr + dc * 4 + 64);
      float av[4] = {a.x, a.y, a.z, a.w};
      float bv[4] = {b.x, b.y, b.z, b.w};
      float pos = (float)positions[t0 + key];
#pragma unroll
      for (int jj = 0; jj < 4; jj++) {
        float fr = pos * exp2f(-ROPE_C * (float)(dc * 4 + jj));
        float sn, cs; sincosf(fr, &sn, &cs);
        float x1 = av[jj], x2 = bv[jj];
        av[jj] = x1 * cs - x2 * sn;
        bv[jj] = x2 * cs + x1 * sn;
      }
      *(float4*)(qr + dc * 4)      = make_float4(av[0], av[1], av[2], av[3]);
      *(float4*)(qr + dc * 4 + 64) = make_float4(bv[0], bv[1], bv[2], bv[3]);
    }
    return;
  }

  const int kvh = y;
  // K: rope + hi/lo split, swizzled slot placement
#pragma unroll
  for (int it = 0; it < 4; it++) {
    int c = tid + 256 * it;
    int key = c >> 4, dc = c & 15;
    const int t = t0 + key;
    const float* kr = qkv + (size_t)t * QKV_OUT
                      + (size_t)NH * HD + (size_t)kvh * HD;
    float4 a = *(const float4*)(kr + dc * 4);
    float4 b = *(const float4*)(kr + dc * 4 + 64);
    float av[4] = {a.x, a.y, a.z, a.w};
    float bv[4] = {b.x, b.y, b.z, b.w};
    float pos = (float)positions[t];
    short4 ha, la, hb, lb;
    short hh, ll;
#pragma unroll
    for (int jj = 0; jj < 4; jj++) {
      float fr = pos * exp2f(-ROPE_C * (float)(dc * 4 + jj));
      float sn, cs; sincosf(fr, &sn, &cs);
      float x1 = av[jj], x2 = bv[jj];
      float r1 = x1 * cs - x2 * sn;
      float r2 = x2 * cs + x1 * sn;
      split2(r1, hh, ll); ((short*)&ha)[jj] = hh; ((short*)&la)[jj] = ll;
      split2(r2, hh, ll); ((short*)&hb)[jj] = hh; ((short*)&lb)[jj] = ll;
    }
    // logical slots: first write s=dc>>1 (half dc&1), second s=8+(dc>>1)
    const int uu = ((dc >> 1) ^ t) & 7;
    const int h4 = (dc & 1) * 4;
    size_t base = (size_t)kvh * T * HD + (size_t)t * HD;
    *(short4*)(Kh + base + uu * 8 + h4) = ha;
    *(short4*)(Kl + base + uu * 8 + h4) = la;
    *(short4*)(Kh + base + (8 + uu) * 8 + h4) = hb;
    *(short4*)(Kl + base + (8 + uu) * 8 + h4) = lb;
  }
  // V -> bf16 transposed, swizzled key-slot placement within 32-key tiles
#pragma unroll
  for (int i = 0; i < 8; i++) {
    int c = tid + 256 * i;
    int key = c >> 5, dc = c & 31;
    float4 f = *(const float4*)(qkv + (size_t)(t0 + key) * QKV_OUT
                                + (size_t)(NH + NKV) * HD + (size_t)kvh * HD + dc * 4);
    Vh_lds[(dc*4+0)*72 + key] = f2bf(f.x);
    Vh_lds[(dc*4+1)*72 + key] = f2bf(f.y);
    Vh_lds[(dc*4+2)*72 + key] = f2bf(f.z);
    Vh_lds[(dc*4+3)*72 + key] = f2bf(f.w);
  }
  __syncthreads();
#pragma unroll
  for (int i = 0; i < 2; i++) {
    int c = tid + 256 * i;
    int row = c >> 2, cc = c & 3;
    int sd = (row >> 1) & 3;
    size_t o = (size_t)kvh * HD * T + (size_t)row * T + t0 + ((cc ^ sd)) * 8;
    *(bfrag*)(Vth + o) = *(const bfrag*)&Vh_lds[row * 72 + cc * 8];
  }
#pragma unroll
  for (int i = 0; i < 2; i++) {
    int c = tid + 256 * i;
    int row = c >> 2, cc = c & 3;
    int sd = (row >> 1) & 3;
    size_t o = (size_t)kvh * HD * T + (size_t)row * T + t0 + 32 + ((cc ^ sd)) * 8;
    *(bfrag*)(Vth + o) = *(const bfrag*)&Vh_lds[row * 72 + 32 + cc * 8];
  }
}

// ---------------- MFMA flash attention ------------------------------------
// R5 post-mortem: split-K never paid (R0's 512-block grid already filled the
// 2-blocks/CU reg-band cap); R5's single-buffer loop serialized the staging
// latency R0 used to hide with a 24-VGPR reg-prefetch. This version:
//  - R0 monolithic pair grid (64x8 blocks, 2 passes, direct normalized out,
//    no combine kernel, no Opart/Mp/Lp traffic);
//  - zero-VGPR swizzled gload_lds staging (R5) but DOUBLE-BUFFERED with
//    counted waits (guide T3 2-phase): issue tile t+1's 6 loads BEFORE
//    computing tile t; vmcnt(0)+raw s_barrier AFTER compute, so loads land
//    under the MFMA/softmax phase. One barrier per iter (R0 had two).
//  - exp2-domain softmax + defer-max (R5 VALU cuts) kept.
__global__ __launch_bounds__(256)
void attn_kernel(const float* __restrict__ qkv,
                 const short* __restrict__ Kh, const short* __restrict__ Kl,
                 const short* __restrict__ Vth,
                 float* __restrict__ attn) {
  __shared__ __align__(16) short Ksh[2][32 * 128];   // 2x8KB, swizzled
  __shared__ __align__(16) short Ksl[2][32 * 128];   // 2x8KB
  __shared__ __align__(16) short Vsh[2][128 * 32];   // 2x8KB, swizzled
  __shared__ __align__(16) short Psh[4 * 16 * 40];   // 5KB, per-wave

  const int kvh = blockIdx.y;
  const int pair = blockIdx.x;                 // 0..63
  const int tid = threadIdx.x;
  const int lane = tid & 63;
  const int wv = tid >> 6;
  const int l15 = lane & 15, quad = lane >> 4;
  const int h = kvh * 4 + wv;
  short* Pw = Psh + wv * 16 * 40;

  const short* KhB = Kh + (size_t)kvh * T * HD;
  const short* KlB = Kl + (size_t)kvh * T * HD;
  const short* VhB = Vth + (size_t)kvh * HD * T;

  // staging source offsets (shorts), loop-invariant; dest is linear lane*16
  const int offK0 = (tid >> 4) * 128 + (tid & 15) * 8;          // rows 0..15
  const int offK1 = offK0 + 16 * 128;                           // rows 16..31
  const int offV0 = (tid >> 2) * T + (tid & 3) * 8;             // dims 0..63
  const int offV1 = offV0 + 64 * T;                             // dims 64..127
  const int wv1k = wv * 1024;                                   // byte chunk

  auto stage = [&](int k0, int b) {
    const short* khs = KhB + (size_t)k0 * HD;
    const short* kls = KlB + (size_t)k0 * HD;
    const short* vs  = VhB + k0;
    gload_lds16(khs + offK0, (char*)&Ksh[b][0] + wv1k);
    gload_lds16(khs + offK1, (char*)&Ksh[b][0] + 4096 + wv1k);
    gload_lds16(kls + offK0, (char*)&Ksl[b][0] + wv1k);
    gload_lds16(kls + offK1, (char*)&Ksl[b][0] + 4096 + wv1k);
    gload_lds16(vs + offV0, (char*)&Vsh[b][0] + wv1k);
    gload_lds16(vs + offV1, (char*)&Vsh[b][0] + 4096 + wv1k);
  };

  // read-side swizzle constants (lane-invariant per kc)
  const int sdv = (l15 >> 1) & 3;                 // V: q' = quad ^ sdv
  const int vq8 = (quad ^ sdv) * 8;
  int uuk[4];                                     // K: u = (s&8)|((s^l15)&7)
#pragma unroll
  for (int kc = 0; kc < 4; kc++) {
    int s = 4 * kc + quad;
    uuk[kc] = ((s & 8) | ((s ^ l15) & 7)) * 8;
  }

  bfrag ones;
#pragma unroll
  for (int j = 0; j < 8; j++) ones[j] = (short)0x3f80;

  for (int pass = 0; pass < 2; pass++) {
    const int qt = pass ? pair : 127 - pair;     // heavy first
    const int q0 = qt * 16;
    const int nk = (q0 >> 5) + 1;                // keys 0..q0+15

    // Q fragments (roped fp32), prescaled by QS2, bf16x2 split, in regs
    bfrag qh[4], ql[4];
    const float* qrow = qkv + (size_t)(q0 + l15) * QKV_OUT + (size_t)h * HD;
#pragma unroll
    for (int kc = 0; kc < 4; kc++) {
      float4 f0 = *(const float4*)(qrow + kc * 32 + quad * 8);
      float4 f1 = *(const float4*)(qrow + kc * 32 + quad * 8 + 4);
      float fv[8] = {f0.x, f0.y, f0.z, f0.w, f1.x, f1.y, f1.z, f1.w};
#pragma unroll
      for (int j = 0; j < 8; j++) {
        short hi, lo; split2(fv[j] * QS2, hi, lo);
        qh[kc][j] = hi; ql[kc][j] = lo;
      }
    }

    ffrag o[8], ol;
    ol = (ffrag){0.f, 0.f, 0.f, 0.f};
#pragma unroll
    for (int n = 0; n < 8; n++) o[n] = (ffrag){0.f, 0.f, 0.f, 0.f};
    float m_i[4] = {-1e30f, -1e30f, -1e30f, -1e30f};

    // prologue: stage tile 0, drain, sync
    stage(0, 0);
    asm volatile("s_waitcnt vmcnt(0)" ::: "memory");
    __builtin_amdgcn_s_barrier();

    int cur = 0;
    for (int kt = 0; kt < nk; kt++) {
      const int k0 = kt << 5;
      if (kt + 1 < nk) stage(k0 + 32, cur ^ 1);  // in flight during compute

      const short* ksh = &Ksh[cur][0];
      const short* ksl = &Ksl[cur][0];
      const short* vsh = &Vsh[cur][0];

      // ---- S = Q K^T (exact via hi/lo split; log2-domain prescaled) ----
      ffrag s[2];
      s[0] = (ffrag){0.f,0.f,0.f,0.f}; s[1] = (ffrag){0.f,0.f,0.f,0.f};
#pragma unroll
      for (int kc = 0; kc < 4; kc++) {
#pragma unroll
        for (int n = 0; n < 2; n++) {
          const int rb = (n * 16 + l15) * 128 + uuk[kc];
          bfrag bh = *(const bfrag*)&ksh[rb];
          bfrag bl = *(const bfrag*)&ksl[rb];
          s[n] = __builtin_amdgcn_mfma_f32_16x16x32_bf16(qh[kc], bh, s[n], 0,0,0);
          s[n] = __builtin_amdgcn_mfma_f32_16x16x32_bf16(qh[kc], bl, s[n], 0,0,0);
          s[n] = __builtin_amdgcn_mfma_f32_16x16x32_bf16(ql[kc], bh, s[n], 0,0,0);
        }
      }
      // ---- online softmax (log2 domain, defer-max) ----
      const bool lastkt = (kt == nk - 1);
      float sv[2][4];
#pragma unroll
      for (int n = 0; n < 2; n++)
#pragma unroll
        for (int r = 0; r < 4; r++) {
          float v = s[n][r];
          if (lastkt) {
            int key = k0 + n * 16 + l15;
            int row = q0 + quad * 4 + r;
            if (key > row) v = -1e30f;
          }
          sv[n][r] = v;
        }
      float mt[4];
      bool trig = false;
#pragma unroll
      for (int r = 0; r < 4; r++) {
        float m2 = fmaxf(sv[0][r], sv[1][r]);
        m2 = fmaxf(m2, __shfl_xor(m2, 1));
        m2 = fmaxf(m2, __shfl_xor(m2, 2));
        m2 = fmaxf(m2, __shfl_xor(m2, 4));
        m2 = fmaxf(m2, __shfl_xor(m2, 8));
        mt[r] = m2;
        trig = trig || (m2 > m_i[r] + DEFER_THR);
      }
      if (__any(trig)) {                       // rare after the first tile
#pragma unroll
        for (int r = 0; r < 4; r++) {
          float mn = fmaxf(m_i[r], mt[r]);
          float a = exp2f(m_i[r] - mn);
          m_i[r] = mn;
          ol[r] *= a;
#pragma unroll
          for (int n = 0; n < 8; n++) o[n][r] *= a;
        }
      }
#pragma unroll
      for (int n = 0; n < 2; n++)
#pragma unroll
        for (int r = 0; r < 4; r++) {
          float p = exp2f(sv[n][r] - m_i[r]);   // bounded by 2^DEFER_THR
          Pw[(quad*4 + r) * 40 + n*16 + l15] = f2bf(p);
        }
      // ---- PV; l via ones-MFMA (same wave wrote Pw, no barrier) ----
      bfrag ph = *(const bfrag*)&Pw[l15 * 40 + quad * 8];
      ol = __builtin_amdgcn_mfma_f32_16x16x32_bf16(ph, ones, ol, 0,0,0);
#pragma unroll
      for (int n = 0; n < 8; n++) {
        bfrag vh = *(const bfrag*)&vsh[(n * 16 + l15) * 32 + vq8];
        o[n] = __builtin_amdgcn_mfma_f32_16x16x32_bf16(ph, vh, o[n], 0,0,0);
      }

      // tile t+1's loads landed during compute; sync and flip
      asm volatile("s_waitcnt vmcnt(0)" ::: "memory");
      __builtin_amdgcn_s_barrier();
      cur ^= 1;
    }

    // ---- normalized output ----
    float inv[4];
#pragma unroll
    for (int r = 0; r < 4; r++) inv[r] = 1.f / ol[r];
#pragma unroll
    for (int n = 0; n < 8; n++)
#pragma unroll
      for (int r = 0; r < 4; r++) {
        int row = q0 + quad * 4 + r;
        attn[(size_t)row * HID + (size_t)h * HD + n * 16 + l15] = o[n][r] * inv[r];
      }
  }
}

// ---------------- dynamic quant with sum (i8 out) ----------------
__global__ __launch_bounds__(256)
void quant_kernel(const float* __restrict__ x, char* __restrict__ q2,
                  float* __restrict__ s2, float* __restrict__ sum2) {
  __shared__ float red[256];
  const int t = blockIdx.x, tid = threadIdx.x;
  const float* row = x + (size_t)t * HID;
  float4 v[4];
  float m = 0.f;
#pragma unroll
  for (int i = 0; i < 4; i++) {
    v[i] = *(const float4*)(row + tid * 16 + i * 4);
    m = fmaxf(m, fmaxf(fmaxf(fabsf(v[i].x), fabsf(v[i].y)),
                       fmaxf(fabsf(v[i].z), fabsf(v[i].w))));
  }
  red[tid] = m; __syncthreads();
  for (int off = 128; off > 0; off >>= 1) {
    if (tid < off) red[tid] = fmaxf(red[tid], red[tid + off]);
    __syncthreads();
  }
  float s = fmaxf(red[0], 1e-8f) / 127.f;
  __syncthreads();
  float ssum = 0.f;
  c16 o;
#pragma unroll
  for (int i = 0; i < 4; i++) {
    float q;
    q = fminf(127.f, fmaxf(-127.f, rintf(v[i].x / s))); ssum += q; o[i*4+0] = (char)(int)q;
    q = fminf(127.f, fmaxf(-127.f, rintf(v[i].y / s))); ssum += q; o[i*4+1] = (char)(int)q;
    q = fminf(127.f, fmaxf(-127.f, rintf(v[i].z / s))); ssum += q; o[i*4+2] = (char)(int)q;
    q = fminf(127.f, fmaxf(-127.f, rintf(v[i].w / s))); ssum += q; o[i*4+3] = (char)(int)q;
  }
  *(c16*)(q2 + (size_t)t * HID + tid * 16) = o;
  red[tid] = ssum; __syncthreads();
  for (int off = 128; off > 0; off >>= 1) {
    if (tid < off) red[tid] += red[tid + off];
    __syncthreads();
  }
  if (tid == 0) { s2[t] = s; sum2[t] = red[0]; }
}

// ---------------- launch ----------------
// Workspace layout (~109 MB): act8 (a_i8/q2) and w8 (wqkv/wo) reused across
// phases as in R0. No split-K scratch needed anymore.
extern "C" void kernel_launch(void* const* d_in, const int* in_sizes, int n_in,
                              void* d_out, int out_size, void* d_ws, size_t ws_size,
                              hipStream_t stream) {
  const int*   positions   = (const int*)d_in[0];
  const int*   q_act       = (const int*)d_in[1];
  const float* act_scale   = (const float*)d_in[2];
  const int*   w_qkv_q     = (const int*)d_in[3];
  const float* w_qkv_scale = (const float*)d_in[4];
  const float* w_qkv_zero  = (const float*)d_in[5];
  const int*   w_o_q       = (const int*)d_in[6];
  const float* w_o_scale   = (const float*)d_in[7];
  const float* w_o_zero    = (const float*)d_in[8];
  float* out = (float*)d_out;

  size_t off = 0;
  auto alloc = [&](size_t bytes) -> void* {
    void* p = (char*)d_ws + off;
    off += (bytes + 255) & ~(size_t)255;
    return p;
  };
  float* qkv   = (float*)alloc((size_t)T * QKV_OUT * 4);         // 50.3 MB
  char*  act8  = (char*)alloc((size_t)T * HID);                  //  8.4 MB (a_i8 / q2)
  char*  w8    = (char*)alloc((size_t)QKV_OUT * HID);            // 25.2 MB (wqkv / wo)
  short* Kh    = (short*)alloc((size_t)NKV * T * HD * 2);        //  8.4 MB
  short* Kl    = (short*)alloc((size_t)NKV * T * HD * 2);        //  8.4 MB
  short* Vth   = (short*)alloc((size_t)NKV * T * HD * 2);        //  8.4 MB
  float* a_sum = (float*)alloc(T * 4);
  float* s2    = (float*)alloc(T * 4);
  float* sum2  = (float*)alloc(T * 4);
  (void)ws_size;

  asum_conv<<<T, 256, 0, stream>>>(q_act, a_sum, act8);
  conv_i2c<<<(QKV_OUT * HID / 16 + 255) / 256, 256, 0, stream>>>(
      w_qkv_q, w8, QKV_OUT * HID / 16);
  gemm_i8<<<dim3(QKV_OUT / 128, T / 128), 256, 0, stream>>>(
      act8, w8, act_scale, a_sum, w_qkv_scale, w_qkv_zero, qkv, T, QKV_OUT, HID);
  split_kv<<<dim3(T / 64, NKV + NH), 256, 0, stream>>>(qkv, positions, Kh, Kl, Vth);
  attn_kernel<<<dim3(64, NKV), 256, 0, stream>>>(qkv, Kh, Kl, Vth, out);
  conv_i2c<<<(HID * HID / 16 + 255) / 256, 256, 0, stream>>>(
      w_o_q, w8, HID * HID / 16);                 // wqkv dead; reuse w8
  quant_kernel<<<T, 256, 0, stream>>>(out, act8, s2, sum2);   // a_i8 dead; reuse act8
  gemm_i8<<<dim3(HID / 128, T / 128), 256, 0, stream>>>(
      act8, w8, s2, sum2, w_o_scale, w_o_zero, out, T, HID, HID);
}

// Round 7
// 522.308 us; speedup vs baseline: 1.1486x; 1.0665x over previous
//
#include <hip/hip_runtime.h>

#define T 2048
#define HID 4096
#define NH 32
#define NKV 8
#define HD 128
#define QKV_OUT ((NH + 2*NKV) * HD)   // 6144
#define SCALING 0.08838834764831843f  // 128^-0.5
#define QS2 0.12751744954f            // SCALING * log2(e): QK^T in log2 domain
#define DEFER_THR 10.0f               // defer-max threshold (log2 domain, P<=2^10)
#define ROPE_C 0.20762050593046014f   // log2(10000)/64

typedef __attribute__((ext_vector_type(8))) short bfrag;   // 8 bf16
typedef __attribute__((ext_vector_type(4))) float ffrag;   // 4 f32 acc
typedef __attribute__((ext_vector_type(4))) int  ifrag;    // 16 i8 / 4 i32 acc
typedef __attribute__((ext_vector_type(16))) char c16;

__device__ __forceinline__ short f2bf(float f) {
  unsigned u = __builtin_bit_cast(unsigned, f);
  u += 0x7fffu + ((u >> 16) & 1u);   // RNE
  return (short)(u >> 16);
}

// bf16x2 split: x ~= hi + lo, residual ~2^-17 * |x|
__device__ __forceinline__ void split2(float x, short& hi, short& lo) {
  unsigned u = __builtin_bit_cast(unsigned, x);
  unsigned uh = u + (0x7fffu + ((u >> 16) & 1u));
  hi = (short)(uh >> 16);
  float fh = __builtin_bit_cast(float, uh & 0xffff0000u);
  float r = x - fh;
  unsigned ur = __builtin_bit_cast(unsigned, r);
  ur += 0x7fffu + ((ur >> 16) & 1u);
  lo = (short)(ur >> 16);
}

// async global->LDS, 16 B per lane (LDS dest = wave-uniform base + lane*16)
__device__ __forceinline__ void gload_lds16(const void* g, void* l) {
  __builtin_amdgcn_global_load_lds(
      (const __attribute__((address_space(1))) unsigned int*)g,
      (__attribute__((address_space(3))) unsigned int*)l, 16, 0, 0);
}

// ---------------- fused a_sum + int8 pack of activations ----------------
__global__ __launch_bounds__(256)
void asum_conv(const int* __restrict__ qact, float* __restrict__ a_sum,
               char* __restrict__ a_i8) {
  __shared__ int red[256];
  const int t = blockIdx.x, tid = threadIdx.x;
  const int* row = qact + (size_t)t * HID + tid * 16;
  int s = 0;
  c16 o;
#pragma unroll
  for (int i = 0; i < 4; i++) {
    int4 v = *(const int4*)(row + i * 4);
    s += v.x + v.y + v.z + v.w;
    o[i*4+0] = (char)v.x; o[i*4+1] = (char)v.y;
    o[i*4+2] = (char)v.z; o[i*4+3] = (char)v.w;
  }
  *(c16*)(a_i8 + (size_t)t * HID + tid * 16) = o;
  red[tid] = s; __syncthreads();
  for (int off = 128; off > 0; off >>= 1) {
    if (tid < off) red[tid] += red[tid + off];
    __syncthreads();
  }
  if (tid == 0) a_sum[t] = (float)red[0];
}

// ---------------- int32 -> int8 pack (weights) ----------------
__global__ __launch_bounds__(256)
void conv_i2c(const int* __restrict__ src, char* __restrict__ dst, int n16) {
  int idx = blockIdx.x * 256 + threadIdx.x;
  if (idx >= n16) return;
  const int4* s4 = (const int4*)src + (size_t)idx * 4;
  c16 o;
#pragma unroll
  for (int j = 0; j < 4; j++) {
    int4 v = s4[j];
    o[j*4+0] = (char)v.x; o[j*4+1] = (char)v.y;
    o[j*4+2] = (char)v.z; o[j*4+3] = (char)v.w;
  }
  *(c16*)(dst + (size_t)idx * 16) = o;
}

// ---------------- W4A8 GEMM, exact i8 MFMA (pre-packed weights only) ------
__global__ __launch_bounds__(256)
void gemm_i8(const char* __restrict__ A, const char* __restrict__ W,
             const float* __restrict__ s_a, const float* __restrict__ asum,
             const float* __restrict__ s_w, const float* __restrict__ z_w,
             float* __restrict__ C, int M, int N, int K) {
  __shared__ __align__(16) char As[128 * 64];
  __shared__ __align__(16) char Bs[128 * 64];
  const int tid = threadIdx.x;
  const int lane = tid & 63;
  const int quad = lane >> 4, l15 = lane & 15;
  const int wave = tid >> 6;
  const int wm = (wave >> 1) * 64, wn = (wave & 1) * 64;
  const int bm = blockIdx.y * 128, bn = blockIdx.x * 128;
  const int sr = tid >> 2, sc = (tid & 3) * 16;

  ifrag acc[4][4];
#pragma unroll
  for (int mi = 0; mi < 4; mi++)
#pragma unroll
    for (int ni = 0; ni < 4; ni++)
      acc[mi][ni] = (ifrag){0, 0, 0, 0};

  for (int k0 = 0; k0 < K; k0 += 64) {
#pragma unroll
    for (int it = 0; it < 2; it++) {
      gload_lds16(A + (size_t)(bm + it * 64 + sr) * K + k0 + sc,
                  &As[it * 4096 + wave * 1024]);
      gload_lds16(W + (size_t)(bn + it * 64 + sr) * K + k0 + sc,
                  &Bs[it * 4096 + wave * 1024]);
    }
    __syncthreads();

    ifrag af[4], bfv[4];
#pragma unroll
    for (int mi = 0; mi < 4; mi++)
      af[mi] = *(const ifrag*)&As[(wm + mi * 16 + l15) * 64 + quad * 16];
#pragma unroll
    for (int ni = 0; ni < 4; ni++)
      bfv[ni] = *(const ifrag*)&Bs[(wn + ni * 16 + l15) * 64 + quad * 16];
#pragma unroll
    for (int mi = 0; mi < 4; mi++)
#pragma unroll
      for (int ni = 0; ni < 4; ni++)
        acc[mi][ni] = __builtin_amdgcn_mfma_i32_16x16x64_i8(
            af[mi], bfv[ni], acc[mi][ni], 0, 0, 0);
    __syncthreads();
  }

#pragma unroll
  for (int mi = 0; mi < 4; mi++) {
    int row0 = bm + wm + mi * 16 + quad * 4;
#pragma unroll
    for (int r = 0; r < 4; r++) {
      int row = row0 + r;
      float sa = s_a[row], av = asum[row];
#pragma unroll
      for (int ni = 0; ni < 4; ni++) {
        int col = bn + wn + ni * 16 + l15;
        C[(size_t)row * N + col] = (sa * s_w[col]) * ((float)acc[mi][ni][r] - z_w[col] * av);
      }
    }
  }
}

// ---- split/rope. K and V are written PRE-SWIZZLED (guide rule 21) so the
// attn kernel can stage them with linear global_load_lds and read with the
// matching XOR:
//   K row t: logical 16B-slot s (0..15) stored at u = (s&8)|((s^t)&7)
//   V dim d: logical 16B key-slot q (0..3) stored at q^((d>>1)&3)
__global__ __launch_bounds__(256)
void split_kv(float* __restrict__ qkv, const int* __restrict__ positions,
              short* __restrict__ Kh, short* __restrict__ Kl,
              short* __restrict__ Vth) {
  __shared__ __align__(16) short Vh_lds[128 * 72];
  const int y = blockIdx.y;
  const int t0 = blockIdx.x * 64;
  const int tid = threadIdx.x;

  if (y >= NKV) {                      // ---- Q: rope in place ----
    const int h = y - NKV;
#pragma unroll
    for (int it = 0; it < 4; it++) {
      int c = tid + 256 * it;
      int key = c >> 4, dc = c & 15;
      float* qr = qkv + (size_t)(t0 + key) * QKV_OUT + (size_t)h * HD;
      float4 a = *(const float4*)(qr + dc * 4);
      float4 b = *(const float4*)(qr + dc * 4 + 64);
      float av[4] = {a.x, a.y, a.z, a.w};
      float bv[4] = {b.x, b.y, b.z, b.w};
      float pos = (float)positions[t0 + key];
#pragma unroll
      for (int jj = 0; jj < 4; jj++) {
        float fr = pos * exp2f(-ROPE_C * (float)(dc * 4 + jj));
        float sn, cs; sincosf(fr, &sn, &cs);
        float x1 = av[jj], x2 = bv[jj];
        av[jj] = x1 * cs - x2 * sn;
        bv[jj] = x2 * cs + x1 * sn;
      }
      *(float4*)(qr + dc * 4)      = make_float4(av[0], av[1], av[2], av[3]);
      *(float4*)(qr + dc * 4 + 64) = make_float4(bv[0], bv[1], bv[2], bv[3]);
    }
    return;
  }

  const int kvh = y;
  // K: rope + hi/lo split, swizzled slot placement
#pragma unroll
  for (int it = 0; it < 4; it++) {
    int c = tid + 256 * it;
    int key = c >> 4, dc = c & 15;
    const int t = t0 + key;
    const float* kr = qkv + (size_t)t * QKV_OUT
                      + (size_t)NH * HD + (size_t)kvh * HD;
    float4 a = *(const float4*)(kr + dc * 4);
    float4 b = *(const float4*)(kr + dc * 4 + 64);
    float av[4] = {a.x, a.y, a.z, a.w};
    float bv[4] = {b.x, b.y, b.z, b.w};
    float pos = (float)positions[t];
    short4 ha, la, hb, lb;
    short hh, ll;
#pragma unroll
    for (int jj = 0; jj < 4; jj++) {
      float fr = pos * exp2f(-ROPE_C * (float)(dc * 4 + jj));
      float sn, cs; sincosf(fr, &sn, &cs);
      float x1 = av[jj], x2 = bv[jj];
      float r1 = x1 * cs - x2 * sn;
      float r2 = x2 * cs + x1 * sn;
      split2(r1, hh, ll); ((short*)&ha)[jj] = hh; ((short*)&la)[jj] = ll;
      split2(r2, hh, ll); ((short*)&hb)[jj] = hh; ((short*)&lb)[jj] = ll;
    }
    // logical slots: first write s=dc>>1 (half dc&1), second s=8+(dc>>1)
    const int uu = ((dc >> 1) ^ t) & 7;
    const int h4 = (dc & 1) * 4;
    size_t base = (size_t)kvh * T * HD + (size_t)t * HD;
    *(short4*)(Kh + base + uu * 8 + h4) = ha;
    *(short4*)(Kl + base + uu * 8 + h4) = la;
    *(short4*)(Kh + base + (8 + uu) * 8 + h4) = hb;
    *(short4*)(Kl + base + (8 + uu) * 8 + h4) = lb;
  }
  // V -> bf16 transposed, swizzled key-slot placement within 32-key tiles
#pragma unroll
  for (int i = 0; i < 8; i++) {
    int c = tid + 256 * i;
    int key = c >> 5, dc = c & 31;
    float4 f = *(const float4*)(qkv + (size_t)(t0 + key) * QKV_OUT
                                + (size_t)(NH + NKV) * HD + (size_t)kvh * HD + dc * 4);
    Vh_lds[(dc*4+0)*72 + key] = f2bf(f.x);
    Vh_lds[(dc*4+1)*72 + key] = f2bf(f.y);
    Vh_lds[(dc*4+2)*72 + key] = f2bf(f.z);
    Vh_lds[(dc*4+3)*72 + key] = f2bf(f.w);
  }
  __syncthreads();
#pragma unroll
  for (int i = 0; i < 2; i++) {
    int c = tid + 256 * i;
    int row = c >> 2, cc = c & 3;
    int sd = (row >> 1) & 3;
    size_t o = (size_t)kvh * HD * T + (size_t)row * T + t0 + ((cc ^ sd)) * 8;
    *(bfrag*)(Vth + o) = *(const bfrag*)&Vh_lds[row * 72 + cc * 8];
  }
#pragma unroll
  for (int i = 0; i < 2; i++) {
    int c = tid + 256 * i;
    int row = c >> 2, cc = c & 3;
    int sd = (row >> 1) & 3;
    size_t o = (size_t)kvh * HD * T + (size_t)row * T + t0 + 32 + ((cc ^ sd)) * 8;
    *(bfrag*)(Vth + o) = *(const bfrag*)&Vh_lds[row * 72 + 32 + cc * 8];
  }
}

// ---------------- MFMA flash attention ------------------------------------
// R6 post-mortem: (a) FETCH 144MB vs ~60MB ideal -- dim3(64,8) scattered each
// kvh's 64 blocks across all XCDs, so every XCD streamed all 8 kvh K/V sets
// through its 4MB L2. NKV==NXCD==8: a 1D grid with kvh = bid&7 pins each kvh
// to one XCD (round-robin dispatch, m09) -> K/V L2-resident (3.1MB/XCD).
// (b) the 16 ds_bpermute max-reduce ran EVERY ktile just to check the
// defer-max trigger. rowmax > m+THR <=> any lane-local max > m+THR, so the
// common path is now 4 fmax + 1 ballot; the 4-shuffle reduce only runs on
// trigger (rare). Identical math.
__global__ __launch_bounds__(256)
void attn_kernel(const float* __restrict__ qkv,
                 const short* __restrict__ Kh, const short* __restrict__ Kl,
                 const short* __restrict__ Vth,
                 float* __restrict__ attn) {
  __shared__ __align__(16) short Ksh[2][32 * 128];   // 2x8KB, swizzled
  __shared__ __align__(16) short Ksl[2][32 * 128];   // 2x8KB
  __shared__ __align__(16) short Vsh[2][128 * 32];   // 2x8KB, swizzled
  __shared__ __align__(16) short Psh[4 * 16 * 40];   // 5KB, per-wave

  const int kvh = blockIdx.x & 7;              // == XCD id (round-robin)
  const int pair = blockIdx.x >> 3;            // 0..63
  const int tid = threadIdx.x;
  const int lane = tid & 63;
  const int wv = tid >> 6;
  const int l15 = lane & 15, quad = lane >> 4;
  const int h = kvh * 4 + wv;
  short* Pw = Psh + wv * 16 * 40;

  const short* KhB = Kh + (size_t)kvh * T * HD;
  const short* KlB = Kl + (size_t)kvh * T * HD;
  const short* VhB = Vth + (size_t)kvh * HD * T;

  // staging source offsets (shorts), loop-invariant; dest is linear lane*16
  const int offK0 = (tid >> 4) * 128 + (tid & 15) * 8;          // rows 0..15
  const int offK1 = offK0 + 16 * 128;                           // rows 16..31
  const int offV0 = (tid >> 2) * T + (tid & 3) * 8;             // dims 0..63
  const int offV1 = offV0 + 64 * T;                             // dims 64..127
  const int wv1k = wv * 1024;                                   // byte chunk

  auto stage = [&](int k0, int b) {
    const short* khs = KhB + (size_t)k0 * HD;
    const short* kls = KlB + (size_t)k0 * HD;
    const short* vs  = VhB + k0;
    gload_lds16(khs + offK0, (char*)&Ksh[b][0] + wv1k);
    gload_lds16(khs + offK1, (char*)&Ksh[b][0] + 4096 + wv1k);
    gload_lds16(kls + offK0, (char*)&Ksl[b][0] + wv1k);
    gload_lds16(kls + offK1, (char*)&Ksl[b][0] + 4096 + wv1k);
    gload_lds16(vs + offV0, (char*)&Vsh[b][0] + wv1k);
    gload_lds16(vs + offV1, (char*)&Vsh[b][0] + 4096 + wv1k);
  };

  // read-side swizzle constants (lane-invariant per kc)
  const int sdv = (l15 >> 1) & 3;                 // V: q' = quad ^ sdv
  const int vq8 = (quad ^ sdv) * 8;
  int uuk[4];                                     // K: u = (s&8)|((s^l15)&7)
#pragma unroll
  for (int kc = 0; kc < 4; kc++) {
    int s = 4 * kc + quad;
    uuk[kc] = ((s & 8) | ((s ^ l15) & 7)) * 8;
  }

  bfrag ones;
#pragma unroll
  for (int j = 0; j < 8; j++) ones[j] = (short)0x3f80;

  for (int pass = 0; pass < 2; pass++) {
    const int qt = pass ? pair : 127 - pair;     // heavy first
    const int q0 = qt * 16;
    const int nk = (q0 >> 5) + 1;                // keys 0..q0+15

    // Q fragments (roped fp32), prescaled by QS2, bf16x2 split, in regs
    bfrag qh[4], ql[4];
    const float* qrow = qkv + (size_t)(q0 + l15) * QKV_OUT + (size_t)h * HD;
#pragma unroll
    for (int kc = 0; kc < 4; kc++) {
      float4 f0 = *(const float4*)(qrow + kc * 32 + quad * 8);
      float4 f1 = *(const float4*)(qrow + kc * 32 + quad * 8 + 4);
      float fv[8] = {f0.x, f0.y, f0.z, f0.w, f1.x, f1.y, f1.z, f1.w};
#pragma unroll
      for (int j = 0; j < 8; j++) {
        short hi, lo; split2(fv[j] * QS2, hi, lo);
        qh[kc][j] = hi; ql[kc][j] = lo;
      }
    }

    ffrag o[8], ol;
    ol = (ffrag){0.f, 0.f, 0.f, 0.f};
#pragma unroll
    for (int n = 0; n < 8; n++) o[n] = (ffrag){0.f, 0.f, 0.f, 0.f};
    float m_i[4] = {-1e30f, -1e30f, -1e30f, -1e30f};

    // prologue: stage tile 0, drain, sync
    stage(0, 0);
    asm volatile("s_waitcnt vmcnt(0)" ::: "memory");
    __builtin_amdgcn_s_barrier();

    int cur = 0;
    for (int kt = 0; kt < nk; kt++) {
      const int k0 = kt << 5;
      if (kt + 1 < nk) stage(k0 + 32, cur ^ 1);  // in flight during compute

      const short* ksh = &Ksh[cur][0];
      const short* ksl = &Ksl[cur][0];
      const short* vsh = &Vsh[cur][0];

      // ---- S = Q K^T (exact via hi/lo split; log2-domain prescaled) ----
      ffrag s[2];
      s[0] = (ffrag){0.f,0.f,0.f,0.f}; s[1] = (ffrag){0.f,0.f,0.f,0.f};
#pragma unroll
      for (int kc = 0; kc < 4; kc++) {
#pragma unroll
        for (int n = 0; n < 2; n++) {
          const int rb = (n * 16 + l15) * 128 + uuk[kc];
          bfrag bh = *(const bfrag*)&ksh[rb];
          bfrag bl = *(const bfrag*)&ksl[rb];
          s[n] = __builtin_amdgcn_mfma_f32_16x16x32_bf16(qh[kc], bh, s[n], 0,0,0);
          s[n] = __builtin_amdgcn_mfma_f32_16x16x32_bf16(qh[kc], bl, s[n], 0,0,0);
          s[n] = __builtin_amdgcn_mfma_f32_16x16x32_bf16(ql[kc], bh, s[n], 0,0,0);
        }
      }
      // ---- online softmax (log2 domain; lane-local defer check) ----
      const bool lastkt = (kt == nk - 1);
      float sv[2][4];
#pragma unroll
      for (int n = 0; n < 2; n++)
#pragma unroll
        for (int r = 0; r < 4; r++) {
          float v = s[n][r];
          if (lastkt) {
            int key = k0 + n * 16 + l15;
            int row = q0 + quad * 4 + r;
            if (key > row) v = -1e30f;
          }
          sv[n][r] = v;
        }
      // lane-local max per row; trigger iff any lane exceeds m_i+THR
      float lm[4];
      bool trig = false;
#pragma unroll
      for (int r = 0; r < 4; r++) {
        lm[r] = fmaxf(sv[0][r], sv[1][r]);
        trig = trig || (lm[r] > m_i[r] + DEFER_THR);
      }
      if (__any(trig)) {                       // rare: full reduce + rescale
#pragma unroll
        for (int r = 0; r < 4; r++) {
          float m2 = lm[r];
          m2 = fmaxf(m2, __shfl_xor(m2, 1));
          m2 = fmaxf(m2, __shfl_xor(m2, 2));
          m2 = fmaxf(m2, __shfl_xor(m2, 4));
          m2 = fmaxf(m2, __shfl_xor(m2, 8));
          float mn = fmaxf(m_i[r], m2);
          float a = exp2f(m_i[r] - mn);
          m_i[r] = mn;
          ol[r] *= a;
#pragma unroll
          for (int n = 0; n < 8; n++) o[n][r] *= a;
        }
      }
#pragma unroll
      for (int n = 0; n < 2; n++)
#pragma unroll
        for (int r = 0; r < 4; r++) {
          float p = exp2f(sv[n][r] - m_i[r]);   // bounded by 2^DEFER_THR
          Pw[(quad*4 + r) * 40 + n*16 + l15] = f2bf(p);
        }
      // ---- PV; l via ones-MFMA (same wave wrote Pw, no barrier) ----
      bfrag ph = *(const bfrag*)&Pw[l15 * 40 + quad * 8];
      ol = __builtin_amdgcn_mfma_f32_16x16x32_bf16(ph, ones, ol, 0,0,0);
#pragma unroll
      for (int n = 0; n < 8; n++) {
        bfrag vh = *(const bfrag*)&vsh[(n * 16 + l15) * 32 + vq8];
        o[n] = __builtin_amdgcn_mfma_f32_16x16x32_bf16(ph, vh, o[n], 0,0,0);
      }

      // tile t+1's loads landed during compute; sync and flip
      asm volatile("s_waitcnt vmcnt(0)" ::: "memory");
      __builtin_amdgcn_s_barrier();
      cur ^= 1;
    }

    // ---- normalized output ----
    float inv[4];
#pragma unroll
    for (int r = 0; r < 4; r++) inv[r] = 1.f / ol[r];
#pragma unroll
    for (int n = 0; n < 8; n++)
#pragma unroll
      for (int r = 0; r < 4; r++) {
        int row = q0 + quad * 4 + r;
        attn[(size_t)row * HID + (size_t)h * HD + n * 16 + l15] = o[n][r] * inv[r];
      }
  }
}

// ---------------- dynamic quant with sum (i8 out) ----------------
__global__ __launch_bounds__(256)
void quant_kernel(const float* __restrict__ x, char* __restrict__ q2,
                  float* __restrict__ s2, float* __restrict__ sum2) {
  __shared__ float red[256];
  const int t = blockIdx.x, tid = threadIdx.x;
  const float* row = x + (size_t)t * HID;
  float4 v[4];
  float m = 0.f;
#pragma unroll
  for (int i = 0; i < 4; i++) {
    v[i] = *(const float4*)(row + tid * 16 + i * 4);
    m = fmaxf(m, fmaxf(fmaxf(fabsf(v[i].x), fabsf(v[i].y)),
                       fmaxf(fabsf(v[i].z), fabsf(v[i].w))));
  }
  red[tid] = m; __syncthreads();
  for (int off = 128; off > 0; off >>= 1) {
    if (tid < off) red[tid] = fmaxf(red[tid], red[tid + off]);
    __syncthreads();
  }
  float s = fmaxf(red[0], 1e-8f) / 127.f;
  __syncthreads();
  float ssum = 0.f;
  c16 o;
#pragma unroll
  for (int i = 0; i < 4; i++) {
    float q;
    q = fminf(127.f, fmaxf(-127.f, rintf(v[i].x / s))); ssum += q; o[i*4+0] = (char)(int)q;
    q = fminf(127.f, fmaxf(-127.f, rintf(v[i].y / s))); ssum += q; o[i*4+1] = (char)(int)q;
    q = fminf(127.f, fmaxf(-127.f, rintf(v[i].z / s))); ssum += q; o[i*4+2] = (char)(int)q;
    q = fminf(127.f, fmaxf(-127.f, rintf(v[i].w / s))); ssum += q; o[i*4+3] = (char)(int)q;
  }
  *(c16*)(q2 + (size_t)t * HID + tid * 16) = o;
  red[tid] = ssum; __syncthreads();
  for (int off = 128; off > 0; off >>= 1) {
    if (tid < off) red[tid] += red[tid + off];
    __syncthreads();
  }
  if (tid == 0) { s2[t] = s; sum2[t] = red[0]; }
}

// ---------------- launch ----------------
// Workspace layout (~109 MB): act8 (a_i8/q2) and w8 (wqkv/wo) reused across
// phases as in R0.
extern "C" void kernel_launch(void* const* d_in, const int* in_sizes, int n_in,
                              void* d_out, int out_size, void* d_ws, size_t ws_size,
                              hipStream_t stream) {
  const int*   positions   = (const int*)d_in[0];
  const int*   q_act       = (const int*)d_in[1];
  const float* act_scale   = (const float*)d_in[2];
  const int*   w_qkv_q     = (const int*)d_in[3];
  const float* w_qkv_scale = (const float*)d_in[4];
  const float* w_qkv_zero  = (const float*)d_in[5];
  const int*   w_o_q       = (const int*)d_in[6];
  const float* w_o_scale   = (const float*)d_in[7];
  const float* w_o_zero    = (const float*)d_in[8];
  float* out = (float*)d_out;

  size_t off = 0;
  auto alloc = [&](size_t bytes) -> void* {
    void* p = (char*)d_ws + off;
    off += (bytes + 255) & ~(size_t)255;
    return p;
  };
  float* qkv   = (float*)alloc((size_t)T * QKV_OUT * 4);         // 50.3 MB
  char*  act8  = (char*)alloc((size_t)T * HID);                  //  8.4 MB (a_i8 / q2)
  char*  w8    = (char*)alloc((size_t)QKV_OUT * HID);            // 25.2 MB (wqkv / wo)
  short* Kh    = (short*)alloc((size_t)NKV * T * HD * 2);        //  8.4 MB
  short* Kl    = (short*)alloc((size_t)NKV * T * HD * 2);        //  8.4 MB
  short* Vth   = (short*)alloc((size_t)NKV * T * HD * 2);        //  8.4 MB
  float* a_sum = (float*)alloc(T * 4);
  float* s2    = (float*)alloc(T * 4);
  float* sum2  = (float*)alloc(T * 4);
  (void)ws_size;

  asum_conv<<<T, 256, 0, stream>>>(q_act, a_sum, act8);
  conv_i2c<<<(QKV_OUT * HID / 16 + 255) / 256, 256, 0, stream>>>(
      w_qkv_q, w8, QKV_OUT * HID / 16);
  gemm_i8<<<dim3(QKV_OUT / 128, T / 128), 256, 0, stream>>>(
      act8, w8, act_scale, a_sum, w_qkv_scale, w_qkv_zero, qkv, T, QKV_OUT, HID);
  split_kv<<<dim3(T / 64, NKV + NH), 256, 0, stream>>>(qkv, positions, Kh, Kl, Vth);
  attn_kernel<<<dim3(512), 256, 0, stream>>>(qkv, Kh, Kl, Vth, out);
  conv_i2c<<<(HID * HID / 16 + 255) / 256, 256, 0, stream>>>(
      w_o_q, w8, HID * HID / 16);                 // wqkv dead; reuse w8
  quant_kernel<<<T, 256, 0, stream>>>(out, act8, s2, sum2);   // a_i8 dead; reuse act8
  gemm_i8<<<dim3(HID / 128, T / 128), 256, 0, stream>>>(
      act8, w8, s2, sum2, w_o_scale, w_o_zero, out, T, HID, HID);
}

// Round 8
// 489.430 us; speedup vs baseline: 1.2257x; 1.0672x over previous
//
#include <hip/hip_runtime.h>

#define T 2048
#define HID 4096
#define NH 32
#define NKV 8
#define HD 128
#define QKV_OUT ((NH + 2*NKV) * HD)   // 6144
#define SCALING 0.08838834764831843f  // 128^-0.5
#define QS2 0.12751744954f            // SCALING * log2(e): QK^T in log2 domain
#define DEFER_THR 10.0f               // defer-max threshold (log2 domain, P<=2^10)
#define ROPE_C 0.20762050593046014f   // log2(10000)/64

typedef __attribute__((ext_vector_type(8))) short bfrag;   // 8 bf16
typedef __attribute__((ext_vector_type(4))) float ffrag;   // 4 f32 acc
typedef __attribute__((ext_vector_type(4))) int  ifrag;    // 16 i8 / 4 i32 acc
typedef __attribute__((ext_vector_type(16))) char c16;

__device__ __forceinline__ short f2bf(float f) {
  unsigned u = __builtin_bit_cast(unsigned, f);
  u += 0x7fffu + ((u >> 16) & 1u);   // RNE
  return (short)(u >> 16);
}

// bf16x2 split: x ~= hi + lo, residual ~2^-17 * |x|
__device__ __forceinline__ void split2(float x, short& hi, short& lo) {
  unsigned u = __builtin_bit_cast(unsigned, x);
  unsigned uh = u + (0x7fffu + ((u >> 16) & 1u));
  hi = (short)(uh >> 16);
  float fh = __builtin_bit_cast(float, uh & 0xffff0000u);
  float r = x - fh;
  unsigned ur = __builtin_bit_cast(unsigned, r);
  ur += 0x7fffu + ((ur >> 16) & 1u);
  lo = (short)(ur >> 16);
}

// async global->LDS, 16 B per lane (LDS dest = wave-uniform base + lane*16)
__device__ __forceinline__ void gload_lds16(const void* g, void* l) {
  __builtin_amdgcn_global_load_lds(
      (const __attribute__((address_space(1))) unsigned int*)g,
      (__attribute__((address_space(3))) unsigned int*)l, 16, 0, 0);
}

// ---------------- rope sincos table: tab[p][j] = (cos, sin) ---------------
// Bit-identical fr computation to the old in-kernel path.
__global__ __launch_bounds__(256)
void rope_table(float2* __restrict__ tab) {
  int idx = blockIdx.x * 256 + threadIdx.x;   // grid 512 -> T*64 entries
  int p = idx >> 6, j = idx & 63;
  float fr = (float)p * exp2f(-ROPE_C * (float)j);
  float sn, cs; sincosf(fr, &sn, &cs);
  tab[idx] = make_float2(cs, sn);
}

// ---- i8 swizzle convention (rule 21): within each 128B window of a row,
// the 16B chunk with logical slot s (0..7) is STORED at slot s ^ (row & 7).
// gemm stages rows linearly via global_load_lds and reads with the same XOR
// -> conflict-free ds_read_b128 (2-way max). All i8 writers apply it.

// ---------------- fused a_sum + int8 pack of activations ----------------
__global__ __launch_bounds__(256)
void asum_conv(const int* __restrict__ qact, float* __restrict__ a_sum,
               char* __restrict__ a_i8) {
  __shared__ int red[256];
  const int t = blockIdx.x, tid = threadIdx.x;
  const int* row = qact + (size_t)t * HID + tid * 16;
  int s = 0;
  c16 o;
#pragma unroll
  for (int i = 0; i < 4; i++) {
    int4 v = *(const int4*)(row + i * 4);
    s += v.x + v.y + v.z + v.w;
    o[i*4+0] = (char)v.x; o[i*4+1] = (char)v.y;
    o[i*4+2] = (char)v.z; o[i*4+3] = (char)v.w;
  }
  const int chunk = (tid & ~7) | ((tid & 7) ^ (t & 7));   // swizzled slot
  *(c16*)(a_i8 + (size_t)t * HID + chunk * 16) = o;
  red[tid] = s; __syncthreads();
  for (int off = 128; off > 0; off >>= 1) {
    if (tid < off) red[tid] += red[tid + off];
    __syncthreads();
  }
  if (tid == 0) a_sum[t] = (float)red[0];
}

// ---------------- int32 -> int8 pack (weights), swizzled ------------------
// Rows have HID/16 = 256 chunks; row = idx>>8.
__global__ __launch_bounds__(256)
void conv_i2c(const int* __restrict__ src, char* __restrict__ dst, int n16) {
  int idx = blockIdx.x * 256 + threadIdx.x;
  if (idx >= n16) return;
  const int4* s4 = (const int4*)src + (size_t)idx * 4;
  c16 o;
#pragma unroll
  for (int j = 0; j < 4; j++) {
    int4 v = s4[j];
    o[j*4+0] = (char)v.x; o[j*4+1] = (char)v.y;
    o[j*4+2] = (char)v.z; o[j*4+3] = (char)v.w;
  }
  const int idxp = (idx & ~7) | ((idx & 7) ^ ((idx >> 8) & 7));
  *(c16*)(dst + (size_t)idxp * 16) = o;
}

// ---------------- W4A8 GEMM, exact i8 MFMA --------------------------------
// R7 post-mortem: GEMMs now ~170us of the pipeline (103+69 GOP at the m97-
// structure ~1 POPS ceiling). i8 lets BK=128 fit in 32KB LDS (m132's bf16
// failure was the 64KB occupancy cliff) -> half the barrier drains. ds_reads
// use the rule-21 swizzle (sources pre-swizzled) -> 2-way conflicts (free).
__global__ __launch_bounds__(256)
void gemm_i8(const char* __restrict__ A, const char* __restrict__ W,
             const float* __restrict__ s_a, const float* __restrict__ asum,
             const float* __restrict__ s_w, const float* __restrict__ z_w,
             float* __restrict__ C, int M, int N, int K) {
  __shared__ __align__(16) char As[128 * 128];   // 16KB, swizzled content
  __shared__ __align__(16) char Bs[128 * 128];   // 16KB
  const int tid = threadIdx.x;
  const int lane = tid & 63;
  const int quad = lane >> 4, l15 = lane & 15;
  const int wave = tid >> 6;
  const int wm = (wave >> 1) * 64, wn = (wave & 1) * 64;
  const int bm = blockIdx.y * 128, bn = blockIdx.x * 128;
  const int sr = tid >> 3, sc = (tid & 7) * 16;   // staging: 32 rows/call

  ifrag acc[4][4];
#pragma unroll
  for (int mi = 0; mi < 4; mi++)
#pragma unroll
    for (int ni = 0; ni < 4; ni++)
      acc[mi][ni] = (ifrag){0, 0, 0, 0};

  // swizzled byte col for k-sub ks: slot (ks*4+quad) ^ (l15&7)
  const int scol0 = ((quad)     ^ (l15 & 7)) * 16;
  const int scol1 = ((4 + quad) ^ (l15 & 7)) * 16;

  for (int k0 = 0; k0 < K; k0 += 128) {
#pragma unroll
    for (int j = 0; j < 4; j++) {
      gload_lds16(A + (size_t)(bm + j * 32 + sr) * K + k0 + sc,
                  &As[j * 4096 + tid * 16]);
      gload_lds16(W + (size_t)(bn + j * 32 + sr) * K + k0 + sc,
                  &Bs[j * 4096 + tid * 16]);
    }
    __syncthreads();

#pragma unroll
    for (int ks = 0; ks < 2; ks++) {
      const int scol = ks ? scol1 : scol0;
      ifrag af[4], bfv[4];
#pragma unroll
      for (int mi = 0; mi < 4; mi++)
        af[mi] = *(const ifrag*)&As[(wm + mi * 16 + l15) * 128 + scol];
#pragma unroll
      for (int ni = 0; ni < 4; ni++)
        bfv[ni] = *(const ifrag*)&Bs[(wn + ni * 16 + l15) * 128 + scol];
#pragma unroll
      for (int mi = 0; mi < 4; mi++)
#pragma unroll
        for (int ni = 0; ni < 4; ni++)
          acc[mi][ni] = __builtin_amdgcn_mfma_i32_16x16x64_i8(
              af[mi], bfv[ni], acc[mi][ni], 0, 0, 0);
    }
    __syncthreads();
  }

#pragma unroll
  for (int mi = 0; mi < 4; mi++) {
    int row0 = bm + wm + mi * 16 + quad * 4;
#pragma unroll
    for (int r = 0; r < 4; r++) {
      int row = row0 + r;
      float sa = s_a[row], av = asum[row];
#pragma unroll
      for (int ni = 0; ni < 4; ni++) {
        int col = bn + wn + ni * 16 + l15;
        C[(size_t)row * N + col] = (sa * s_w[col]) * ((float)acc[mi][ni][r] - z_w[col] * av);
      }
    }
  }
}

// ---- split/rope. K and V are written PRE-SWIZZLED (guide rule 21) so the
// attn kernel can stage them with linear global_load_lds and read with the
// matching XOR. Rope uses the precomputed sincos table.
__global__ __launch_bounds__(256)
void split_kv(float* __restrict__ qkv, const int* __restrict__ positions,
              const float2* __restrict__ tab,
              short* __restrict__ Kh, short* __restrict__ Kl,
              short* __restrict__ Vth) {
  __shared__ __align__(16) short Vh_lds[128 * 72];
  const int y = blockIdx.y;
  const int t0 = blockIdx.x * 64;
  const int tid = threadIdx.x;

  if (y >= NKV) {                      // ---- Q: rope in place ----
    const int h = y - NKV;
#pragma unroll
    for (int it = 0; it < 4; it++) {
      int c = tid + 256 * it;
      int key = c >> 4, dc = c & 15;
      float* qr = qkv + (size_t)(t0 + key) * QKV_OUT + (size_t)h * HD;
      float4 a = *(const float4*)(qr + dc * 4);
      float4 b = *(const float4*)(qr + dc * 4 + 64);
      float av[4] = {a.x, a.y, a.z, a.w};
      float bv[4] = {b.x, b.y, b.z, b.w};
      const float2* tr = tab + (size_t)positions[t0 + key] * 64 + dc * 4;
#pragma unroll
      for (int jj = 0; jj < 4; jj++) {
        float cs = tr[jj].x, sn = tr[jj].y;
        float x1 = av[jj], x2 = bv[jj];
        av[jj] = x1 * cs - x2 * sn;
        bv[jj] = x2 * cs + x1 * sn;
      }
      *(float4*)(qr + dc * 4)      = make_float4(av[0], av[1], av[2], av[3]);
      *(float4*)(qr + dc * 4 + 64) = make_float4(bv[0], bv[1], bv[2], bv[3]);
    }
    return;
  }

  const int kvh = y;
  // K: rope + hi/lo split, swizzled slot placement
#pragma unroll
  for (int it = 0; it < 4; it++) {
    int c = tid + 256 * it;
    int key = c >> 4, dc = c & 15;
    const int t = t0 + key;
    const float* kr = qkv + (size_t)t * QKV_OUT
                      + (size_t)NH * HD + (size_t)kvh * HD;
    float4 a = *(const float4*)(kr + dc * 4);
    float4 b = *(const float4*)(kr + dc * 4 + 64);
    float av[4] = {a.x, a.y, a.z, a.w};
    float bv[4] = {b.x, b.y, b.z, b.w};
    const float2* tr = tab + (size_t)positions[t] * 64 + dc * 4;
    short4 ha, la, hb, lb;
    short hh, ll;
#pragma unroll
    for (int jj = 0; jj < 4; jj++) {
      float cs = tr[jj].x, sn = tr[jj].y;
      float x1 = av[jj], x2 = bv[jj];
      float r1 = x1 * cs - x2 * sn;
      float r2 = x2 * cs + x1 * sn;
      split2(r1, hh, ll); ((short*)&ha)[jj] = hh; ((short*)&la)[jj] = ll;
      split2(r2, hh, ll); ((short*)&hb)[jj] = hh; ((short*)&lb)[jj] = ll;
    }
    // logical slots: first write s=dc>>1 (half dc&1), second s=8+(dc>>1)
    const int uu = ((dc >> 1) ^ t) & 7;
    const int h4 = (dc & 1) * 4;
    size_t base = (size_t)kvh * T * HD + (size_t)t * HD;
    *(short4*)(Kh + base + uu * 8 + h4) = ha;
    *(short4*)(Kl + base + uu * 8 + h4) = la;
    *(short4*)(Kh + base + (8 + uu) * 8 + h4) = hb;
    *(short4*)(Kl + base + (8 + uu) * 8 + h4) = lb;
  }
  // V -> bf16 transposed, swizzled key-slot placement within 32-key tiles
#pragma unroll
  for (int i = 0; i < 8; i++) {
    int c = tid + 256 * i;
    int key = c >> 5, dc = c & 31;
    float4 f = *(const float4*)(qkv + (size_t)(t0 + key) * QKV_OUT
                                + (size_t)(NH + NKV) * HD + (size_t)kvh * HD + dc * 4);
    Vh_lds[(dc*4+0)*72 + key] = f2bf(f.x);
    Vh_lds[(dc*4+1)*72 + key] = f2bf(f.y);
    Vh_lds[(dc*4+2)*72 + key] = f2bf(f.z);
    Vh_lds[(dc*4+3)*72 + key] = f2bf(f.w);
  }
  __syncthreads();
#pragma unroll
  for (int i = 0; i < 2; i++) {
    int c = tid + 256 * i;
    int row = c >> 2, cc = c & 3;
    int sd = (row >> 1) & 3;
    size_t o = (size_t)kvh * HD * T + (size_t)row * T + t0 + ((cc ^ sd)) * 8;
    *(bfrag*)(Vth + o) = *(const bfrag*)&Vh_lds[row * 72 + cc * 8];
  }
#pragma unroll
  for (int i = 0; i < 2; i++) {
    int c = tid + 256 * i;
    int row = c >> 2, cc = c & 3;
    int sd = (row >> 1) & 3;
    size_t o = (size_t)kvh * HD * T + (size_t)row * T + t0 + 32 + ((cc ^ sd)) * 8;
    *(bfrag*)(Vth + o) = *(const bfrag*)&Vh_lds[row * 72 + 32 + cc * 8];
  }
}

// ---------------- MFMA flash attention (R7 state, verified) ---------------
// 1D grid, kvh = bid&7 pins each kvh to one XCD -> K/V L2-resident
// (FETCH 144->24MB, R7). Lane-local defer-max check; full reduce only on
// trigger. Double-buffered zero-VGPR gload_lds staging.
__global__ __launch_bounds__(256)
void attn_kernel(const float* __restrict__ qkv,
                 const short* __restrict__ Kh, const short* __restrict__ Kl,
                 const short* __restrict__ Vth,
                 float* __restrict__ attn) {
  __shared__ __align__(16) short Ksh[2][32 * 128];   // 2x8KB, swizzled
  __shared__ __align__(16) short Ksl[2][32 * 128];   // 2x8KB
  __shared__ __align__(16) short Vsh[2][128 * 32];   // 2x8KB, swizzled
  __shared__ __align__(16) short Psh[4 * 16 * 40];   // 5KB, per-wave

  const int kvh = blockIdx.x & 7;              // == XCD id (round-robin)
  const int pair = blockIdx.x >> 3;            // 0..63
  const int tid = threadIdx.x;
  const int lane = tid & 63;
  const int wv = tid >> 6;
  const int l15 = lane & 15, quad = lane >> 4;
  const int h = kvh * 4 + wv;
  short* Pw = Psh + wv * 16 * 40;

  const short* KhB = Kh + (size_t)kvh * T * HD;
  const short* KlB = Kl + (size_t)kvh * T * HD;
  const short* VhB = Vth + (size_t)kvh * HD * T;

  // staging source offsets (shorts), loop-invariant; dest is linear lane*16
  const int offK0 = (tid >> 4) * 128 + (tid & 15) * 8;          // rows 0..15
  const int offK1 = offK0 + 16 * 128;                           // rows 16..31
  const int offV0 = (tid >> 2) * T + (tid & 3) * 8;             // dims 0..63
  const int offV1 = offV0 + 64 * T;                             // dims 64..127
  const int wv1k = wv * 1024;                                   // byte chunk

  auto stage = [&](int k0, int b) {
    const short* khs = KhB + (size_t)k0 * HD;
    const short* kls = KlB + (size_t)k0 * HD;
    const short* vs  = VhB + k0;
    gload_lds16(khs + offK0, (char*)&Ksh[b][0] + wv1k);
    gload_lds16(khs + offK1, (char*)&Ksh[b][0] + 4096 + wv1k);
    gload_lds16(kls + offK0, (char*)&Ksl[b][0] + wv1k);
    gload_lds16(kls + offK1, (char*)&Ksl[b][0] + 4096 + wv1k);
    gload_lds16(vs + offV0, (char*)&Vsh[b][0] + wv1k);
    gload_lds16(vs + offV1, (char*)&Vsh[b][0] + 4096 + wv1k);
  };

  // read-side swizzle constants (lane-invariant per kc)
  const int sdv = (l15 >> 1) & 3;                 // V: q' = quad ^ sdv
  const int vq8 = (quad ^ sdv) * 8;
  int uuk[4];                                     // K: u = (s&8)|((s^l15)&7)
#pragma unroll
  for (int kc = 0; kc < 4; kc++) {
    int s = 4 * kc + quad;
    uuk[kc] = ((s & 8) | ((s ^ l15) & 7)) * 8;
  }

  bfrag ones;
#pragma unroll
  for (int j = 0; j < 8; j++) ones[j] = (short)0x3f80;

  for (int pass = 0; pass < 2; pass++) {
    const int qt = pass ? pair : 127 - pair;     // heavy first
    const int q0 = qt * 16;
    const int nk = (q0 >> 5) + 1;                // keys 0..q0+15

    // Q fragments (roped fp32), prescaled by QS2, bf16x2 split, in regs
    bfrag qh[4], ql[4];
    const float* qrow = qkv + (size_t)(q0 + l15) * QKV_OUT + (size_t)h * HD;
#pragma unroll
    for (int kc = 0; kc < 4; kc++) {
      float4 f0 = *(const float4*)(qrow + kc * 32 + quad * 8);
      float4 f1 = *(const float4*)(qrow + kc * 32 + quad * 8 + 4);
      float fv[8] = {f0.x, f0.y, f0.z, f0.w, f1.x, f1.y, f1.z, f1.w};
#pragma unroll
      for (int j = 0; j < 8; j++) {
        short hi, lo; split2(fv[j] * QS2, hi, lo);
        qh[kc][j] = hi; ql[kc][j] = lo;
      }
    }

    ffrag o[8], ol;
    ol = (ffrag){0.f, 0.f, 0.f, 0.f};
#pragma unroll
    for (int n = 0; n < 8; n++) o[n] = (ffrag){0.f, 0.f, 0.f, 0.f};
    float m_i[4] = {-1e30f, -1e30f, -1e30f, -1e30f};

    // prologue: stage tile 0, drain, sync
    stage(0, 0);
    asm volatile("s_waitcnt vmcnt(0)" ::: "memory");
    __builtin_amdgcn_s_barrier();

    int cur = 0;
    for (int kt = 0; kt < nk; kt++) {
      const int k0 = kt << 5;
      if (kt + 1 < nk) stage(k0 + 32, cur ^ 1);  // in flight during compute

      const short* ksh = &Ksh[cur][0];
      const short* ksl = &Ksl[cur][0];
      const short* vsh = &Vsh[cur][0];

      // ---- S = Q K^T (exact via hi/lo split; log2-domain prescaled) ----
      ffrag s[2];
      s[0] = (ffrag){0.f,0.f,0.f,0.f}; s[1] = (ffrag){0.f,0.f,0.f,0.f};
#pragma unroll
      for (int kc = 0; kc < 4; kc++) {
#pragma unroll
        for (int n = 0; n < 2; n++) {
          const int rb = (n * 16 + l15) * 128 + uuk[kc];
          bfrag bh = *(const bfrag*)&ksh[rb];
          bfrag bl = *(const bfrag*)&ksl[rb];
          s[n] = __builtin_amdgcn_mfma_f32_16x16x32_bf16(qh[kc], bh, s[n], 0,0,0);
          s[n] = __builtin_amdgcn_mfma_f32_16x16x32_bf16(qh[kc], bl, s[n], 0,0,0);
          s[n] = __builtin_amdgcn_mfma_f32_16x16x32_bf16(ql[kc], bh, s[n], 0,0,0);
        }
      }
      // ---- online softmax (log2 domain; lane-local defer check) ----
      const bool lastkt = (kt == nk - 1);
      float sv[2][4];
#pragma unroll
      for (int n = 0; n < 2; n++)
#pragma unroll
        for (int r = 0; r < 4; r++) {
          float v = s[n][r];
          if (lastkt) {
            int key = k0 + n * 16 + l15;
            int row = q0 + quad * 4 + r;
            if (key > row) v = -1e30f;
          }
          sv[n][r] = v;
        }
      // lane-local max per row; trigger iff any lane exceeds m_i+THR
      float lm[4];
      bool trig = false;
#pragma unroll
      for (int r = 0; r < 4; r++) {
        lm[r] = fmaxf(sv[0][r], sv[1][r]);
        trig = trig || (lm[r] > m_i[r] + DEFER_THR);
      }
      if (__any(trig)) {                       // rare: full reduce + rescale
#pragma unroll
        for (int r = 0; r < 4; r++) {
          float m2 = lm[r];
          m2 = fmaxf(m2, __shfl_xor(m2, 1));
          m2 = fmaxf(m2, __shfl_xor(m2, 2));
          m2 = fmaxf(m2, __shfl_xor(m2, 4));
          m2 = fmaxf(m2, __shfl_xor(m2, 8));
          float mn = fmaxf(m_i[r], m2);
          float a = exp2f(m_i[r] - mn);
          m_i[r] = mn;
          ol[r] *= a;
#pragma unroll
          for (int n = 0; n < 8; n++) o[n][r] *= a;
        }
      }
#pragma unroll
      for (int n = 0; n < 2; n++)
#pragma unroll
        for (int r = 0; r < 4; r++) {
          float p = exp2f(sv[n][r] - m_i[r]);   // bounded by 2^DEFER_THR
          Pw[(quad*4 + r) * 40 + n*16 + l15] = f2bf(p);
        }
      // ---- PV; l via ones-MFMA (same wave wrote Pw, no barrier) ----
      bfrag ph = *(const bfrag*)&Pw[l15 * 40 + quad * 8];
      ol = __builtin_amdgcn_mfma_f32_16x16x32_bf16(ph, ones, ol, 0,0,0);
#pragma unroll
      for (int n = 0; n < 8; n++) {
        bfrag vh = *(const bfrag*)&vsh[(n * 16 + l15) * 32 + vq8];
        o[n] = __builtin_amdgcn_mfma_f32_16x16x32_bf16(ph, vh, o[n], 0,0,0);
      }

      // tile t+1's loads landed during compute; sync and flip
      asm volatile("s_waitcnt vmcnt(0)" ::: "memory");
      __builtin_amdgcn_s_barrier();
      cur ^= 1;
    }

    // ---- normalized output ----
    float inv[4];
#pragma unroll
    for (int r = 0; r < 4; r++) inv[r] = 1.f / ol[r];
#pragma unroll
    for (int n = 0; n < 8; n++)
#pragma unroll
      for (int r = 0; r < 4; r++) {
        int row = q0 + quad * 4 + r;
        attn[(size_t)row * HID + (size_t)h * HD + n * 16 + l15] = o[n][r] * inv[r];
      }
  }
}

// ---------------- dynamic quant with sum (i8 out, swizzled) ---------------
__global__ __launch_bounds__(256)
void quant_kernel(const float* __restrict__ x, char* __restrict__ q2,
                  float* __restrict__ s2, float* __restrict__ sum2) {
  __shared__ float red[256];
  const int t = blockIdx.x, tid = threadIdx.x;
  const float* row = x + (size_t)t * HID;
  float4 v[4];
  float m = 0.f;
#pragma unroll
  for (int i = 0; i < 4; i++) {
    v[i] = *(const float4*)(row + tid * 16 + i * 4);
    m = fmaxf(m, fmaxf(fmaxf(fabsf(v[i].x), fabsf(v[i].y)),
                       fmaxf(fabsf(v[i].z), fabsf(v[i].w))));
  }
  red[tid] = m; __syncthreads();
  for (int off = 128; off > 0; off >>= 1) {
    if (tid < off) red[tid] = fmaxf(red[tid], red[tid + off]);
    __syncthreads();
  }
  float s = fmaxf(red[0], 1e-8f) / 127.f;
  __syncthreads();
  float ssum = 0.f;
  c16 o;
#pragma unroll
  for (int i = 0; i < 4; i++) {
    float q;
    q = fminf(127.f, fmaxf(-127.f, rintf(v[i].x / s))); ssum += q; o[i*4+0] = (char)(int)q;
    q = fminf(127.f, fmaxf(-127.f, rintf(v[i].y / s))); ssum += q; o[i*4+1] = (char)(int)q;
    q = fminf(127.f, fmaxf(-127.f, rintf(v[i].z / s))); ssum += q; o[i*4+2] = (char)(int)q;
    q = fminf(127.f, fmaxf(-127.f, rintf(v[i].w / s))); ssum += q; o[i*4+3] = (char)(int)q;
  }
  const int chunk = (tid & ~7) | ((tid & 7) ^ (t & 7));   // swizzled slot
  *(c16*)(q2 + (size_t)t * HID + chunk * 16) = o;
  red[tid] = ssum; __syncthreads();
  for (int off = 128; off > 0; off >>= 1) {
    if (tid < off) red[tid] += red[tid + off];
    __syncthreads();
  }
  if (tid == 0) { s2[t] = s; sum2[t] = red[0]; }
}

// ---------------- launch ----------------
// Workspace layout (~110 MB): act8 (a_i8/q2) and w8 (wqkv/wo) reused across
// phases as in R0; +1MB rope table.
extern "C" void kernel_launch(void* const* d_in, const int* in_sizes, int n_in,
                              void* d_out, int out_size, void* d_ws, size_t ws_size,
                              hipStream_t stream) {
  const int*   positions   = (const int*)d_in[0];
  const int*   q_act       = (const int*)d_in[1];
  const float* act_scale   = (const float*)d_in[2];
  const int*   w_qkv_q     = (const int*)d_in[3];
  const float* w_qkv_scale = (const float*)d_in[4];
  const float* w_qkv_zero  = (const float*)d_in[5];
  const int*   w_o_q       = (const int*)d_in[6];
  const float* w_o_scale   = (const float*)d_in[7];
  const float* w_o_zero    = (const float*)d_in[8];
  float* out = (float*)d_out;

  size_t off = 0;
  auto alloc = [&](size_t bytes) -> void* {
    void* p = (char*)d_ws + off;
    off += (bytes + 255) & ~(size_t)255;
    return p;
  };
  float* qkv   = (float*)alloc((size_t)T * QKV_OUT * 4);         // 50.3 MB
  char*  act8  = (char*)alloc((size_t)T * HID);                  //  8.4 MB (a_i8 / q2)
  char*  w8    = (char*)alloc((size_t)QKV_OUT * HID);            // 25.2 MB (wqkv / wo)
  short* Kh    = (short*)alloc((size_t)NKV * T * HD * 2);        //  8.4 MB
  short* Kl    = (short*)alloc((size_t)NKV * T * HD * 2);        //  8.4 MB
  short* Vth   = (short*)alloc((size_t)NKV * T * HD * 2);        //  8.4 MB
  float* a_sum = (float*)alloc(T * 4);
  float* s2    = (float*)alloc(T * 4);
  float* sum2  = (float*)alloc(T * 4);
  float2* tab  = (float2*)alloc((size_t)T * 64 * 8);             //  1.0 MB
  (void)ws_size;

  rope_table<<<T * 64 / 256, 256, 0, stream>>>(tab);
  asum_conv<<<T, 256, 0, stream>>>(q_act, a_sum, act8);
  conv_i2c<<<(QKV_OUT * HID / 16 + 255) / 256, 256, 0, stream>>>(
      w_qkv_q, w8, QKV_OUT * HID / 16);
  gemm_i8<<<dim3(QKV_OUT / 128, T / 128), 256, 0, stream>>>(
      act8, w8, act_scale, a_sum, w_qkv_scale, w_qkv_zero, qkv, T, QKV_OUT, HID);
  split_kv<<<dim3(T / 64, NKV + NH), 256, 0, stream>>>(
      qkv, positions, tab, Kh, Kl, Vth);
  attn_kernel<<<dim3(512), 256, 0, stream>>>(qkv, Kh, Kl, Vth, out);
  conv_i2c<<<(HID * HID / 16 + 255) / 256, 256, 0, stream>>>(
      w_o_q, w8, HID * HID / 16);                 // wqkv dead; reuse w8
  quant_kernel<<<T, 256, 0, stream>>>(out, act8, s2, sum2);   // a_i8 dead; reuse act8
  gemm_i8<<<dim3(HID / 128, T / 128), 256, 0, stream>>>(
      act8, w8, s2, sum2, w_o_scale, w_o_zero, out, T, HID, HID);
}

// Round 9
// 478.083 us; speedup vs baseline: 1.2548x; 1.0237x over previous
//
#include <hip/hip_runtime.h>

#define T 2048
#define HID 4096
#define NH 32
#define NKV 8
#define HD 128
#define QKV_OUT ((NH + 2*NKV) * HD)   // 6144
#define SCALING 0.08838834764831843f  // 128^-0.5
#define QS2 0.12751744954f            // SCALING * log2(e): QK^T in log2 domain
#define DEFER_THR 10.0f               // defer-max threshold (log2 domain, P<=2^10)
#define ROPE_C 0.20762050593046014f   // log2(10000)/64

typedef __attribute__((ext_vector_type(8))) short bfrag;   // 8 bf16
typedef __attribute__((ext_vector_type(4))) float ffrag;   // 4 f32 acc
typedef __attribute__((ext_vector_type(4))) int  ifrag;    // 16 i8 / 4 i32 acc
typedef __attribute__((ext_vector_type(16))) char c16;

__device__ __forceinline__ short f2bf(float f) {
  unsigned u = __builtin_bit_cast(unsigned, f);
  u += 0x7fffu + ((u >> 16) & 1u);   // RNE
  return (short)(u >> 16);
}

// bf16x2 split: x ~= hi + lo, residual ~2^-17 * |x|
__device__ __forceinline__ void split2(float x, short& hi, short& lo) {
  unsigned u = __builtin_bit_cast(unsigned, x);
  unsigned uh = u + (0x7fffu + ((u >> 16) & 1u));
  hi = (short)(uh >> 16);
  float fh = __builtin_bit_cast(float, uh & 0xffff0000u);
  float r = x - fh;
  unsigned ur = __builtin_bit_cast(unsigned, r);
  ur += 0x7fffu + ((ur >> 16) & 1u);
  lo = (short)(ur >> 16);
}

// async global->LDS, 16 B per lane (LDS dest = wave-uniform base + lane*16)
__device__ __forceinline__ void gload_lds16(const void* g, void* l) {
  __builtin_amdgcn_global_load_lds(
      (const __attribute__((address_space(1))) unsigned int*)g,
      (__attribute__((address_space(3))) unsigned int*)l, 16, 0, 0);
}

// ---------------- rope sincos table: tab[p][j] = (cos, sin) ---------------
// Bit-identical fr computation to the old in-kernel path.
__global__ __launch_bounds__(256)
void rope_table(float2* __restrict__ tab) {
  int idx = blockIdx.x * 256 + threadIdx.x;   // grid 512 -> T*64 entries
  int p = idx >> 6, j = idx & 63;
  float fr = (float)p * exp2f(-ROPE_C * (float)j);
  float sn, cs; sincosf(fr, &sn, &cs);
  tab[idx] = make_float2(cs, sn);
}

// ---- i8 swizzle convention (rule 21): within each 128B window of a row,
// the 16B chunk with logical slot s (0..7) is STORED at slot s ^ (row & 7).
// gemm stages rows linearly via global_load_lds and reads with the same XOR
// -> conflict-free ds_read_b128 (2-way max). All i8 writers apply it.

// ---------------- fused a_sum + int8 pack of activations ----------------
__global__ __launch_bounds__(256)
void asum_conv(const int* __restrict__ qact, float* __restrict__ a_sum,
               char* __restrict__ a_i8) {
  __shared__ int red[256];
  const int t = blockIdx.x, tid = threadIdx.x;
  const int* row = qact + (size_t)t * HID + tid * 16;
  int s = 0;
  c16 o;
#pragma unroll
  for (int i = 0; i < 4; i++) {
    int4 v = *(const int4*)(row + i * 4);
    s += v.x + v.y + v.z + v.w;
    o[i*4+0] = (char)v.x; o[i*4+1] = (char)v.y;
    o[i*4+2] = (char)v.z; o[i*4+3] = (char)v.w;
  }
  const int chunk = (tid & ~7) | ((tid & 7) ^ (t & 7));   // swizzled slot
  *(c16*)(a_i8 + (size_t)t * HID + chunk * 16) = o;
  red[tid] = s; __syncthreads();
  for (int off = 128; off > 0; off >>= 1) {
    if (tid < off) red[tid] += red[tid + off];
    __syncthreads();
  }
  if (tid == 0) a_sum[t] = (float)red[0];
}

// ---------------- int32 -> int8 pack (weights), swizzled ------------------
// Rows have HID/16 = 256 chunks; row = idx>>8.
__global__ __launch_bounds__(256)
void conv_i2c(const int* __restrict__ src, char* __restrict__ dst, int n16) {
  int idx = blockIdx.x * 256 + threadIdx.x;
  if (idx >= n16) return;
  const int4* s4 = (const int4*)src + (size_t)idx * 4;
  c16 o;
#pragma unroll
  for (int j = 0; j < 4; j++) {
    int4 v = s4[j];
    o[j*4+0] = (char)v.x; o[j*4+1] = (char)v.y;
    o[j*4+2] = (char)v.z; o[j*4+3] = (char)v.w;
  }
  const int idxp = (idx & ~7) | ((idx & 7) ^ ((idx >> 8) & 7));
  *(c16*)(dst + (size_t)idxp * 16) = o;
}

// ---------------- W4A8 GEMM, exact i8 MFMA --------------------------------
// R8 post-mortem: GEMMs ~220-260us combined; the 2-barrier single-buffer
// loop serializes ~400-900cy of staging latency into each of 32 K-iters --
// the exact defect R6 fixed in attn (171->131us). Same fix here: LDS double
// buffer (2x32KB), issue tile k+1's loads BEFORE computing tile k,
// vmcnt(0)+one raw barrier AFTER compute. Rule-21 swizzled reads kept.
__global__ __launch_bounds__(256)
void gemm_i8(const char* __restrict__ A, const char* __restrict__ W,
             const float* __restrict__ s_a, const float* __restrict__ asum,
             const float* __restrict__ s_w, const float* __restrict__ z_w,
             float* __restrict__ C, int M, int N, int K) {
  __shared__ __align__(16) char As[2][128 * 128];   // 2x16KB, swizzled content
  __shared__ __align__(16) char Bs[2][128 * 128];   // 2x16KB
  const int tid = threadIdx.x;
  const int lane = tid & 63;
  const int quad = lane >> 4, l15 = lane & 15;
  const int wave = tid >> 6;
  const int wm = (wave >> 1) * 64, wn = (wave & 1) * 64;
  const int bm = blockIdx.y * 128, bn = blockIdx.x * 128;
  const int sr = tid >> 3, sc = (tid & 7) * 16;   // staging: 32 rows/call

  ifrag acc[4][4];
#pragma unroll
  for (int mi = 0; mi < 4; mi++)
#pragma unroll
    for (int ni = 0; ni < 4; ni++)
      acc[mi][ni] = (ifrag){0, 0, 0, 0};

  auto stage = [&](int k0, int b) {
#pragma unroll
    for (int j = 0; j < 4; j++) {
      gload_lds16(A + (size_t)(bm + j * 32 + sr) * K + k0 + sc,
                  &As[b][j * 4096 + tid * 16]);
      gload_lds16(W + (size_t)(bn + j * 32 + sr) * K + k0 + sc,
                  &Bs[b][j * 4096 + tid * 16]);
    }
  };

  // swizzled byte col for k-sub ks: slot (ks*4+quad) ^ (l15&7)
  const int scol0 = ((quad)     ^ (l15 & 7)) * 16;
  const int scol1 = ((4 + quad) ^ (l15 & 7)) * 16;

  // prologue: stage tile 0, drain, sync
  stage(0, 0);
  asm volatile("s_waitcnt vmcnt(0)" ::: "memory");
  __builtin_amdgcn_s_barrier();

  int cur = 0;
  for (int k0 = 0; k0 < K; k0 += 128) {
    if (k0 + 128 < K) stage(k0 + 128, cur ^ 1);   // in flight during compute

#pragma unroll
    for (int ks = 0; ks < 2; ks++) {
      const int scol = ks ? scol1 : scol0;
      ifrag af[4], bfv[4];
#pragma unroll
      for (int mi = 0; mi < 4; mi++)
        af[mi] = *(const ifrag*)&As[cur][(wm + mi * 16 + l15) * 128 + scol];
#pragma unroll
      for (int ni = 0; ni < 4; ni++)
        bfv[ni] = *(const ifrag*)&Bs[cur][(wn + ni * 16 + l15) * 128 + scol];
#pragma unroll
      for (int mi = 0; mi < 4; mi++)
#pragma unroll
        for (int ni = 0; ni < 4; ni++)
          acc[mi][ni] = __builtin_amdgcn_mfma_i32_16x16x64_i8(
              af[mi], bfv[ni], acc[mi][ni], 0, 0, 0);
    }

    // next tile's loads landed during compute; sync and flip
    asm volatile("s_waitcnt vmcnt(0)" ::: "memory");
    __builtin_amdgcn_s_barrier();
    cur ^= 1;
  }

#pragma unroll
  for (int mi = 0; mi < 4; mi++) {
    int row0 = bm + wm + mi * 16 + quad * 4;
#pragma unroll
    for (int r = 0; r < 4; r++) {
      int row = row0 + r;
      float sa = s_a[row], av = asum[row];
#pragma unroll
      for (int ni = 0; ni < 4; ni++) {
        int col = bn + wn + ni * 16 + l15;
        C[(size_t)row * N + col] = (sa * s_w[col]) * ((float)acc[mi][ni][r] - z_w[col] * av);
      }
    }
  }
}

// ---- split/rope. K and V are written PRE-SWIZZLED (guide rule 21) so the
// attn kernel can stage them with linear global_load_lds and read with the
// matching XOR. Rope uses the precomputed sincos table.
__global__ __launch_bounds__(256)
void split_kv(float* __restrict__ qkv, const int* __restrict__ positions,
              const float2* __restrict__ tab,
              short* __restrict__ Kh, short* __restrict__ Kl,
              short* __restrict__ Vth) {
  __shared__ __align__(16) short Vh_lds[128 * 72];
  const int y = blockIdx.y;
  const int t0 = blockIdx.x * 64;
  const int tid = threadIdx.x;

  if (y >= NKV) {                      // ---- Q: rope in place ----
    const int h = y - NKV;
#pragma unroll
    for (int it = 0; it < 4; it++) {
      int c = tid + 256 * it;
      int key = c >> 4, dc = c & 15;
      float* qr = qkv + (size_t)(t0 + key) * QKV_OUT + (size_t)h * HD;
      float4 a = *(const float4*)(qr + dc * 4);
      float4 b = *(const float4*)(qr + dc * 4 + 64);
      float av[4] = {a.x, a.y, a.z, a.w};
      float bv[4] = {b.x, b.y, b.z, b.w};
      const float2* tr = tab + (size_t)positions[t0 + key] * 64 + dc * 4;
#pragma unroll
      for (int jj = 0; jj < 4; jj++) {
        float cs = tr[jj].x, sn = tr[jj].y;
        float x1 = av[jj], x2 = bv[jj];
        av[jj] = x1 * cs - x2 * sn;
        bv[jj] = x2 * cs + x1 * sn;
      }
      *(float4*)(qr + dc * 4)      = make_float4(av[0], av[1], av[2], av[3]);
      *(float4*)(qr + dc * 4 + 64) = make_float4(bv[0], bv[1], bv[2], bv[3]);
    }
    return;
  }

  const int kvh = y;
  // K: rope + hi/lo split, swizzled slot placement
#pragma unroll
  for (int it = 0; it < 4; it++) {
    int c = tid + 256 * it;
    int key = c >> 4, dc = c & 15;
    const int t = t0 + key;
    const float* kr = qkv + (size_t)t * QKV_OUT
                      + (size_t)NH * HD + (size_t)kvh * HD;
    float4 a = *(const float4*)(kr + dc * 4);
    float4 b = *(const float4*)(kr + dc * 4 + 64);
    float av[4] = {a.x, a.y, a.z, a.w};
    float bv[4] = {b.x, b.y, b.z, b.w};
    const float2* tr = tab + (size_t)positions[t] * 64 + dc * 4;
    short4 ha, la, hb, lb;
    short hh, ll;
#pragma unroll
    for (int jj = 0; jj < 4; jj++) {
      float cs = tr[jj].x, sn = tr[jj].y;
      float x1 = av[jj], x2 = bv[jj];
      float r1 = x1 * cs - x2 * sn;
      float r2 = x2 * cs + x1 * sn;
      split2(r1, hh, ll); ((short*)&ha)[jj] = hh; ((short*)&la)[jj] = ll;
      split2(r2, hh, ll); ((short*)&hb)[jj] = hh; ((short*)&lb)[jj] = ll;
    }
    // logical slots: first write s=dc>>1 (half dc&1), second s=8+(dc>>1)
    const int uu = ((dc >> 1) ^ t) & 7;
    const int h4 = (dc & 1) * 4;
    size_t base = (size_t)kvh * T * HD + (size_t)t * HD;
    *(short4*)(Kh + base + uu * 8 + h4) = ha;
    *(short4*)(Kl + base + uu * 8 + h4) = la;
    *(short4*)(Kh + base + (8 + uu) * 8 + h4) = hb;
    *(short4*)(Kl + base + (8 + uu) * 8 + h4) = lb;
  }
  // V -> bf16 transposed, swizzled key-slot placement within 32-key tiles
#pragma unroll
  for (int i = 0; i < 8; i++) {
    int c = tid + 256 * i;
    int key = c >> 5, dc = c & 31;
    float4 f = *(const float4*)(qkv + (size_t)(t0 + key) * QKV_OUT
                                + (size_t)(NH + NKV) * HD + (size_t)kvh * HD + dc * 4);
    Vh_lds[(dc*4+0)*72 + key] = f2bf(f.x);
    Vh_lds[(dc*4+1)*72 + key] = f2bf(f.y);
    Vh_lds[(dc*4+2)*72 + key] = f2bf(f.z);
    Vh_lds[(dc*4+3)*72 + key] = f2bf(f.w);
  }
  __syncthreads();
#pragma unroll
  for (int i = 0; i < 2; i++) {
    int c = tid + 256 * i;
    int row = c >> 2, cc = c & 3;
    int sd = (row >> 1) & 3;
    size_t o = (size_t)kvh * HD * T + (size_t)row * T + t0 + ((cc ^ sd)) * 8;
    *(bfrag*)(Vth + o) = *(const bfrag*)&Vh_lds[row * 72 + cc * 8];
  }
#pragma unroll
  for (int i = 0; i < 2; i++) {
    int c = tid + 256 * i;
    int row = c >> 2, cc = c & 3;
    int sd = (row >> 1) & 3;
    size_t o = (size_t)kvh * HD * T + (size_t)row * T + t0 + 32 + ((cc ^ sd)) * 8;
    *(bfrag*)(Vth + o) = *(const bfrag*)&Vh_lds[row * 72 + 32 + cc * 8];
  }
}

// ---------------- MFMA flash attention (R7 state, verified) ---------------
// 1D grid, kvh = bid&7 pins each kvh to one XCD -> K/V L2-resident
// (FETCH 144->24MB, R7). Lane-local defer-max check; full reduce only on
// trigger. Double-buffered zero-VGPR gload_lds staging.
__global__ __launch_bounds__(256)
void attn_kernel(const float* __restrict__ qkv,
                 const short* __restrict__ Kh, const short* __restrict__ Kl,
                 const short* __restrict__ Vth,
                 float* __restrict__ attn) {
  __shared__ __align__(16) short Ksh[2][32 * 128];   // 2x8KB, swizzled
  __shared__ __align__(16) short Ksl[2][32 * 128];   // 2x8KB
  __shared__ __align__(16) short Vsh[2][128 * 32];   // 2x8KB, swizzled
  __shared__ __align__(16) short Psh[4 * 16 * 40];   // 5KB, per-wave

  const int kvh = blockIdx.x & 7;              // == XCD id (round-robin)
  const int pair = blockIdx.x >> 3;            // 0..63
  const int tid = threadIdx.x;
  const int lane = tid & 63;
  const int wv = tid >> 6;
  const int l15 = lane & 15, quad = lane >> 4;
  const int h = kvh * 4 + wv;
  short* Pw = Psh + wv * 16 * 40;

  const short* KhB = Kh + (size_t)kvh * T * HD;
  const short* KlB = Kl + (size_t)kvh * T * HD;
  const short* VhB = Vth + (size_t)kvh * HD * T;

  // staging source offsets (shorts), loop-invariant; dest is linear lane*16
  const int offK0 = (tid >> 4) * 128 + (tid & 15) * 8;          // rows 0..15
  const int offK1 = offK0 + 16 * 128;                           // rows 16..31
  const int offV0 = (tid >> 2) * T + (tid & 3) * 8;             // dims 0..63
  const int offV1 = offV0 + 64 * T;                             // dims 64..127
  const int wv1k = wv * 1024;                                   // byte chunk

  auto stage = [&](int k0, int b) {
    const short* khs = KhB + (size_t)k0 * HD;
    const short* kls = KlB + (size_t)k0 * HD;
    const short* vs  = VhB + k0;
    gload_lds16(khs + offK0, (char*)&Ksh[b][0] + wv1k);
    gload_lds16(khs + offK1, (char*)&Ksh[b][0] + 4096 + wv1k);
    gload_lds16(kls + offK0, (char*)&Ksl[b][0] + wv1k);
    gload_lds16(kls + offK1, (char*)&Ksl[b][0] + 4096 + wv1k);
    gload_lds16(vs + offV0, (char*)&Vsh[b][0] + wv1k);
    gload_lds16(vs + offV1, (char*)&Vsh[b][0] + 4096 + wv1k);
  };

  // read-side swizzle constants (lane-invariant per kc)
  const int sdv = (l15 >> 1) & 3;                 // V: q' = quad ^ sdv
  const int vq8 = (quad ^ sdv) * 8;
  int uuk[4];                                     // K: u = (s&8)|((s^l15)&7)
#pragma unroll
  for (int kc = 0; kc < 4; kc++) {
    int s = 4 * kc + quad;
    uuk[kc] = ((s & 8) | ((s ^ l15) & 7)) * 8;
  }

  bfrag ones;
#pragma unroll
  for (int j = 0; j < 8; j++) ones[j] = (short)0x3f80;

  for (int pass = 0; pass < 2; pass++) {
    const int qt = pass ? pair : 127 - pair;     // heavy first
    const int q0 = qt * 16;
    const int nk = (q0 >> 5) + 1;                // keys 0..q0+15

    // Q fragments (roped fp32), prescaled by QS2, bf16x2 split, in regs
    bfrag qh[4], ql[4];
    const float* qrow = qkv + (size_t)(q0 + l15) * QKV_OUT + (size_t)h * HD;
#pragma unroll
    for (int kc = 0; kc < 4; kc++) {
      float4 f0 = *(const float4*)(qrow + kc * 32 + quad * 8);
      float4 f1 = *(const float4*)(qrow + kc * 32 + quad * 8 + 4);
      float fv[8] = {f0.x, f0.y, f0.z, f0.w, f1.x, f1.y, f1.z, f1.w};
#pragma unroll
      for (int j = 0; j < 8; j++) {
        short hi, lo; split2(fv[j] * QS2, hi, lo);
        qh[kc][j] = hi; ql[kc][j] = lo;
      }
    }

    ffrag o[8], ol;
    ol = (ffrag){0.f, 0.f, 0.f, 0.f};
#pragma unroll
    for (int n = 0; n < 8; n++) o[n] = (ffrag){0.f, 0.f, 0.f, 0.f};
    float m_i[4] = {-1e30f, -1e30f, -1e30f, -1e30f};

    // prologue: stage tile 0, drain, sync
    stage(0, 0);
    asm volatile("s_waitcnt vmcnt(0)" ::: "memory");
    __builtin_amdgcn_s_barrier();

    int cur = 0;
    for (int kt = 0; kt < nk; kt++) {
      const int k0 = kt << 5;
      if (kt + 1 < nk) stage(k0 + 32, cur ^ 1);  // in flight during compute

      const short* ksh = &Ksh[cur][0];
      const short* ksl = &Ksl[cur][0];
      const short* vsh = &Vsh[cur][0];

      // ---- S = Q K^T (exact via hi/lo split; log2-domain prescaled) ----
      ffrag s[2];
      s[0] = (ffrag){0.f,0.f,0.f,0.f}; s[1] = (ffrag){0.f,0.f,0.f,0.f};
#pragma unroll
      for (int kc = 0; kc < 4; kc++) {
#pragma unroll
        for (int n = 0; n < 2; n++) {
          const int rb = (n * 16 + l15) * 128 + uuk[kc];
          bfrag bh = *(const bfrag*)&ksh[rb];
          bfrag bl = *(const bfrag*)&ksl[rb];
          s[n] = __builtin_amdgcn_mfma_f32_16x16x32_bf16(qh[kc], bh, s[n], 0,0,0);
          s[n] = __builtin_amdgcn_mfma_f32_16x16x32_bf16(qh[kc], bl, s[n], 0,0,0);
          s[n] = __builtin_amdgcn_mfma_f32_16x16x32_bf16(ql[kc], bh, s[n], 0,0,0);
        }
      }
      // ---- online softmax (log2 domain; lane-local defer check) ----
      const bool lastkt = (kt == nk - 1);
      float sv[2][4];
#pragma unroll
      for (int n = 0; n < 2; n++)
#pragma unroll
        for (int r = 0; r < 4; r++) {
          float v = s[n][r];
          if (lastkt) {
            int key = k0 + n * 16 + l15;
            int row = q0 + quad * 4 + r;
            if (key > row) v = -1e30f;
          }
          sv[n][r] = v;
        }
      // lane-local max per row; trigger iff any lane exceeds m_i+THR
      float lm[4];
      bool trig = false;
#pragma unroll
      for (int r = 0; r < 4; r++) {
        lm[r] = fmaxf(sv[0][r], sv[1][r]);
        trig = trig || (lm[r] > m_i[r] + DEFER_THR);
      }
      if (__any(trig)) {                       // rare: full reduce + rescale
#pragma unroll
        for (int r = 0; r < 4; r++) {
          float m2 = lm[r];
          m2 = fmaxf(m2, __shfl_xor(m2, 1));
          m2 = fmaxf(m2, __shfl_xor(m2, 2));
          m2 = fmaxf(m2, __shfl_xor(m2, 4));
          m2 = fmaxf(m2, __shfl_xor(m2, 8));
          float mn = fmaxf(m_i[r], m2);
          float a = exp2f(m_i[r] - mn);
          m_i[r] = mn;
          ol[r] *= a;
#pragma unroll
          for (int n = 0; n < 8; n++) o[n][r] *= a;
        }
      }
#pragma unroll
      for (int n = 0; n < 2; n++)
#pragma unroll
        for (int r = 0; r < 4; r++) {
          float p = exp2f(sv[n][r] - m_i[r]);   // bounded by 2^DEFER_THR
          Pw[(quad*4 + r) * 40 + n*16 + l15] = f2bf(p);
        }
      // ---- PV; l via ones-MFMA (same wave wrote Pw, no barrier) ----
      bfrag ph = *(const bfrag*)&Pw[l15 * 40 + quad * 8];
      ol = __builtin_amdgcn_mfma_f32_16x16x32_bf16(ph, ones, ol, 0,0,0);
#pragma unroll
      for (int n = 0; n < 8; n++) {
        bfrag vh = *(const bfrag*)&vsh[(n * 16 + l15) * 32 + vq8];
        o[n] = __builtin_amdgcn_mfma_f32_16x16x32_bf16(ph, vh, o[n], 0,0,0);
      }

      // tile t+1's loads landed during compute; sync and flip
      asm volatile("s_waitcnt vmcnt(0)" ::: "memory");
      __builtin_amdgcn_s_barrier();
      cur ^= 1;
    }

    // ---- normalized output ----
    float inv[4];
#pragma unroll
    for (int r = 0; r < 4; r++) inv[r] = 1.f / ol[r];
#pragma unroll
    for (int n = 0; n < 8; n++)
#pragma unroll
      for (int r = 0; r < 4; r++) {
        int row = q0 + quad * 4 + r;
        attn[(size_t)row * HID + (size_t)h * HD + n * 16 + l15] = o[n][r] * inv[r];
      }
  }
}

// ---------------- dynamic quant with sum (i8 out, swizzled) ---------------
__global__ __launch_bounds__(256)
void quant_kernel(const float* __restrict__ x, char* __restrict__ q2,
                  float* __restrict__ s2, float* __restrict__ sum2) {
  __shared__ float red[256];
  const int t = blockIdx.x, tid = threadIdx.x;
  const float* row = x + (size_t)t * HID;
  float4 v[4];
  float m = 0.f;
#pragma unroll
  for (int i = 0; i < 4; i++) {
    v[i] = *(const float4*)(row + tid * 16 + i * 4);
    m = fmaxf(m, fmaxf(fmaxf(fabsf(v[i].x), fabsf(v[i].y)),
                       fmaxf(fabsf(v[i].z), fabsf(v[i].w))));
  }
  red[tid] = m; __syncthreads();
  for (int off = 128; off > 0; off >>= 1) {
    if (tid < off) red[tid] = fmaxf(red[tid], red[tid + off]);
    __syncthreads();
  }
  float s = fmaxf(red[0], 1e-8f) / 127.f;
  __syncthreads();
  float ssum = 0.f;
  c16 o;
#pragma unroll
  for (int i = 0; i < 4; i++) {
    float q;
    q = fminf(127.f, fmaxf(-127.f, rintf(v[i].x / s))); ssum += q; o[i*4+0] = (char)(int)q;
    q = fminf(127.f, fmaxf(-127.f, rintf(v[i].y / s))); ssum += q; o[i*4+1] = (char)(int)q;
    q = fminf(127.f, fmaxf(-127.f, rintf(v[i].z / s))); ssum += q; o[i*4+2] = (char)(int)q;
    q = fminf(127.f, fmaxf(-127.f, rintf(v[i].w / s))); ssum += q; o[i*4+3] = (char)(int)q;
  }
  const int chunk = (tid & ~7) | ((tid & 7) ^ (t & 7));   // swizzled slot
  *(c16*)(q2 + (size_t)t * HID + chunk * 16) = o;
  red[tid] = ssum; __syncthreads();
  for (int off = 128; off > 0; off >>= 1) {
    if (tid < off) red[tid] += red[tid + off];
    __syncthreads();
  }
  if (tid == 0) { s2[t] = s; sum2[t] = red[0]; }
}

// ---------------- launch ----------------
// Workspace layout (~110 MB): act8 (a_i8/q2) and w8 (wqkv/wo) reused across
// phases as in R0; +1MB rope table.
extern "C" void kernel_launch(void* const* d_in, const int* in_sizes, int n_in,
                              void* d_out, int out_size, void* d_ws, size_t ws_size,
                              hipStream_t stream) {
  const int*   positions   = (const int*)d_in[0];
  const int*   q_act       = (const int*)d_in[1];
  const float* act_scale   = (const float*)d_in[2];
  const int*   w_qkv_q     = (const int*)d_in[3];
  const float* w_qkv_scale = (const float*)d_in[4];
  const float* w_qkv_zero  = (const float*)d_in[5];
  const int*   w_o_q       = (const int*)d_in[6];
  const float* w_o_scale   = (const float*)d_in[7];
  const float* w_o_zero    = (const float*)d_in[8];
  float* out = (float*)d_out;

  size_t off = 0;
  auto alloc = [&](size_t bytes) -> void* {
    void* p = (char*)d_ws + off;
    off += (bytes + 255) & ~(size_t)255;
    return p;
  };
  float* qkv   = (float*)alloc((size_t)T * QKV_OUT * 4);         // 50.3 MB
  char*  act8  = (char*)alloc((size_t)T * HID);                  //  8.4 MB (a_i8 / q2)
  char*  w8    = (char*)alloc((size_t)QKV_OUT * HID);            // 25.2 MB (wqkv / wo)
  short* Kh    = (short*)alloc((size_t)NKV * T * HD * 2);        //  8.4 MB
  short* Kl    = (short*)alloc((size_t)NKV * T * HD * 2);        //  8.4 MB
  short* Vth   = (short*)alloc((size_t)NKV * T * HD * 2);        //  8.4 MB
  float* a_sum = (float*)alloc(T * 4);
  float* s2    = (float*)alloc(T * 4);
  float* sum2  = (float*)alloc(T * 4);
  float2* tab  = (float2*)alloc((size_t)T * 64 * 8);             //  1.0 MB
  (void)ws_size;

  rope_table<<<T * 64 / 256, 256, 0, stream>>>(tab);
  asum_conv<<<T, 256, 0, stream>>>(q_act, a_sum, act8);
  conv_i2c<<<(QKV_OUT * HID / 16 + 255) / 256, 256, 0, stream>>>(
      w_qkv_q, w8, QKV_OUT * HID / 16);
  gemm_i8<<<dim3(QKV_OUT / 128, T / 128), 256, 0, stream>>>(
      act8, w8, act_scale, a_sum, w_qkv_scale, w_qkv_zero, qkv, T, QKV_OUT, HID);
  split_kv<<<dim3(T / 64, NKV + NH), 256, 0, stream>>>(
      qkv, positions, tab, Kh, Kl, Vth);
  attn_kernel<<<dim3(512), 256, 0, stream>>>(qkv, Kh, Kl, Vth, out);
  conv_i2c<<<(HID * HID / 16 + 255) / 256, 256, 0, stream>>>(
      w_o_q, w8, HID * HID / 16);                 // wqkv dead; reuse w8
  quant_kernel<<<T, 256, 0, stream>>>(out, act8, s2, sum2);   // a_i8 dead; reuse act8
  gemm_i8<<<dim3(HID / 128, T / 128), 256, 0, stream>>>(
      act8, w8, s2, sum2, w_o_scale, w_o_zero, out, T, HID, HID);
}

// Round 10
// 467.019 us; speedup vs baseline: 1.2845x; 1.0237x over previous
//
#include <hip/hip_runtime.h>

#define T 2048
#define HID 4096
#define NH 32
#define NKV 8
#define HD 128
#define QKV_OUT ((NH + 2*NKV) * HD)   // 6144
#define SCALING 0.08838834764831843f  // 128^-0.5
#define QS2 0.12751744954f            // SCALING * log2(e): QK^T in log2 domain
#define DEFER_THR 10.0f               // defer-max threshold (log2 domain, P<=2^10)
#define ROPE_C 0.20762050593046014f   // log2(10000)/64

typedef __attribute__((ext_vector_type(8))) short bfrag;   // 8 bf16
typedef __attribute__((ext_vector_type(4))) float ffrag;   // 4 f32 acc
typedef __attribute__((ext_vector_type(4))) int  ifrag;    // 16 i8 / 4 i32 acc
typedef __attribute__((ext_vector_type(16))) char c16;

__device__ __forceinline__ short f2bf(float f) {
  unsigned u = __builtin_bit_cast(unsigned, f);
  u += 0x7fffu + ((u >> 16) & 1u);   // RNE
  return (short)(u >> 16);
}

// bf16x2 split: x ~= hi + lo, residual ~2^-17 * |x|
__device__ __forceinline__ void split2(float x, short& hi, short& lo) {
  unsigned u = __builtin_bit_cast(unsigned, x);
  unsigned uh = u + (0x7fffu + ((u >> 16) & 1u));
  hi = (short)(uh >> 16);
  float fh = __builtin_bit_cast(float, uh & 0xffff0000u);
  float r = x - fh;
  unsigned ur = __builtin_bit_cast(unsigned, r);
  ur += 0x7fffu + ((ur >> 16) & 1u);
  lo = (short)(ur >> 16);
}

// async global->LDS, 16 B per lane (LDS dest = wave-uniform base + lane*16)
__device__ __forceinline__ void gload_lds16(const void* g, void* l) {
  __builtin_amdgcn_global_load_lds(
      (const __attribute__((address_space(1))) unsigned int*)g,
      (__attribute__((address_space(3))) unsigned int*)l, 16, 0, 0);
}

// ---- i8 swizzle convention (rule 21): within each 128B window of a row,
// the 16B chunk with logical slot s (0..7) is STORED at slot s ^ (row & 7).
// gemm stages rows linearly via global_load_lds and reads with the same XOR
// -> conflict-free ds_read_b128 (2-way max). All i8 writers apply it.

// ------- fused a_sum + int8 pack of activations + rope table fill ---------
// Blocks < 512 additionally fill one rope-table entry per thread
// (tab[p][j] = (cos, sin) of p * 2^(-ROPE_C*j); bit-identical to the old
// rope_table kernel). Saves one launch.
__global__ __launch_bounds__(256)
void asum_conv(const int* __restrict__ qact, float* __restrict__ a_sum,
               char* __restrict__ a_i8, float2* __restrict__ tab) {
  __shared__ int red[256];
  const int t = blockIdx.x, tid = threadIdx.x;
  if (t < 512) {
    int idx = t * 256 + tid;          // T*64 = 131072 entries = 512 blocks
    int p = idx >> 6, j = idx & 63;
    float fr = (float)p * exp2f(-ROPE_C * (float)j);
    float sn, cs; sincosf(fr, &sn, &cs);
    tab[idx] = make_float2(cs, sn);
  }
  const int* row = qact + (size_t)t * HID + tid * 16;
  int s = 0;
  c16 o;
#pragma unroll
  for (int i = 0; i < 4; i++) {
    int4 v = *(const int4*)(row + i * 4);
    s += v.x + v.y + v.z + v.w;
    o[i*4+0] = (char)v.x; o[i*4+1] = (char)v.y;
    o[i*4+2] = (char)v.z; o[i*4+3] = (char)v.w;
  }
  const int chunk = (tid & ~7) | ((tid & 7) ^ (t & 7));   // swizzled slot
  *(c16*)(a_i8 + (size_t)t * HID + chunk * 16) = o;
  red[tid] = s; __syncthreads();
  for (int off = 128; off > 0; off >>= 1) {
    if (tid < off) red[tid] += red[tid + off];
    __syncthreads();
  }
  if (tid == 0) a_sum[t] = (float)red[0];
}

// ---------------- int32 -> int8 pack (weights), swizzled ------------------
// Rows have HID/16 = 256 chunks; row = idx>>8.
__global__ __launch_bounds__(256)
void conv_i2c(const int* __restrict__ src, char* __restrict__ dst, int n16) {
  int idx = blockIdx.x * 256 + threadIdx.x;
  if (idx >= n16) return;
  const int4* s4 = (const int4*)src + (size_t)idx * 4;
  c16 o;
#pragma unroll
  for (int j = 0; j < 4; j++) {
    int4 v = s4[j];
    o[j*4+0] = (char)v.x; o[j*4+1] = (char)v.y;
    o[j*4+2] = (char)v.z; o[j*4+3] = (char)v.w;
  }
  const int idxp = (idx & ~7) | ((idx & 7) ^ ((idx >> 8) & 7));
  *(c16*)(dst + (size_t)idxp * 16) = o;
}

// ---------------- W4A8 GEMM, exact i8 MFMA (R9 state) ---------------------
__global__ __launch_bounds__(256)
void gemm_i8(const char* __restrict__ A, const char* __restrict__ W,
             const float* __restrict__ s_a, const float* __restrict__ asum,
             const float* __restrict__ s_w, const float* __restrict__ z_w,
             float* __restrict__ C, int M, int N, int K) {
  __shared__ __align__(16) char As[2][128 * 128];   // 2x16KB, swizzled content
  __shared__ __align__(16) char Bs[2][128 * 128];   // 2x16KB
  const int tid = threadIdx.x;
  const int lane = tid & 63;
  const int quad = lane >> 4, l15 = lane & 15;
  const int wave = tid >> 6;
  const int wm = (wave >> 1) * 64, wn = (wave & 1) * 64;
  const int bm = blockIdx.y * 128, bn = blockIdx.x * 128;
  const int sr = tid >> 3, sc = (tid & 7) * 16;   // staging: 32 rows/call

  ifrag acc[4][4];
#pragma unroll
  for (int mi = 0; mi < 4; mi++)
#pragma unroll
    for (int ni = 0; ni < 4; ni++)
      acc[mi][ni] = (ifrag){0, 0, 0, 0};

  auto stage = [&](int k0, int b) {
#pragma unroll
    for (int j = 0; j < 4; j++) {
      gload_lds16(A + (size_t)(bm + j * 32 + sr) * K + k0 + sc,
                  &As[b][j * 4096 + tid * 16]);
      gload_lds16(W + (size_t)(bn + j * 32 + sr) * K + k0 + sc,
                  &Bs[b][j * 4096 + tid * 16]);
    }
  };

  // swizzled byte col for k-sub ks: slot (ks*4+quad) ^ (l15&7)
  const int scol0 = ((quad)     ^ (l15 & 7)) * 16;
  const int scol1 = ((4 + quad) ^ (l15 & 7)) * 16;

  // prologue: stage tile 0, drain, sync
  stage(0, 0);
  asm volatile("s_waitcnt vmcnt(0)" ::: "memory");
  __builtin_amdgcn_s_barrier();

  int cur = 0;
  for (int k0 = 0; k0 < K; k0 += 128) {
    if (k0 + 128 < K) stage(k0 + 128, cur ^ 1);   // in flight during compute

#pragma unroll
    for (int ks = 0; ks < 2; ks++) {
      const int scol = ks ? scol1 : scol0;
      ifrag af[4], bfv[4];
#pragma unroll
      for (int mi = 0; mi < 4; mi++)
        af[mi] = *(const ifrag*)&As[cur][(wm + mi * 16 + l15) * 128 + scol];
#pragma unroll
      for (int ni = 0; ni < 4; ni++)
        bfv[ni] = *(const ifrag*)&Bs[cur][(wn + ni * 16 + l15) * 128 + scol];
#pragma unroll
      for (int mi = 0; mi < 4; mi++)
#pragma unroll
        for (int ni = 0; ni < 4; ni++)
          acc[mi][ni] = __builtin_amdgcn_mfma_i32_16x16x64_i8(
              af[mi], bfv[ni], acc[mi][ni], 0, 0, 0);
    }

    // next tile's loads landed during compute; sync and flip
    asm volatile("s_waitcnt vmcnt(0)" ::: "memory");
    __builtin_amdgcn_s_barrier();
    cur ^= 1;
  }

#pragma unroll
  for (int mi = 0; mi < 4; mi++) {
    int row0 = bm + wm + mi * 16 + quad * 4;
#pragma unroll
    for (int r = 0; r < 4; r++) {
      int row = row0 + r;
      float sa = s_a[row], av = asum[row];
#pragma unroll
      for (int ni = 0; ni < 4; ni++) {
        int col = bn + wn + ni * 16 + l15;
        C[(size_t)row * N + col] = (sa * s_w[col]) * ((float)acc[mi][ni][r] - z_w[col] * av);
      }
    }
  }
}

// ---- split/rope: K/V ONLY now (Q rope moved into attn prologue -- each Q
// row-head is consumed by exactly one attn block, so the separate 67MB
// read+write Q pass was pure waste). K and V written PRE-SWIZZLED (rule 21):
//   K row t: logical 16B-slot s (0..15) stored at u = (s&8)|((s^t)&7)
//   V dim d: logical 16B key-slot q (0..3) stored at q^((d>>1)&3)
__global__ __launch_bounds__(256)
void split_kv(const float* __restrict__ qkv, const int* __restrict__ positions,
              const float2* __restrict__ tab,
              short* __restrict__ Kh, short* __restrict__ Kl,
              short* __restrict__ Vth) {
  __shared__ __align__(16) short Vh_lds[128 * 72];
  const int kvh = blockIdx.y;
  const int t0 = blockIdx.x * 64;
  const int tid = threadIdx.x;

  // K: rope + hi/lo split, swizzled slot placement
#pragma unroll
  for (int it = 0; it < 4; it++) {
    int c = tid + 256 * it;
    int key = c >> 4, dc = c & 15;
    const int t = t0 + key;
    const float* kr = qkv + (size_t)t * QKV_OUT
                      + (size_t)NH * HD + (size_t)kvh * HD;
    float4 a = *(const float4*)(kr + dc * 4);
    float4 b = *(const float4*)(kr + dc * 4 + 64);
    float av[4] = {a.x, a.y, a.z, a.w};
    float bv[4] = {b.x, b.y, b.z, b.w};
    const float2* tr = tab + (size_t)positions[t] * 64 + dc * 4;
    short4 ha, la, hb, lb;
    short hh, ll;
#pragma unroll
    for (int jj = 0; jj < 4; jj++) {
      float cs = tr[jj].x, sn = tr[jj].y;
      float x1 = av[jj], x2 = bv[jj];
      float r1 = x1 * cs - x2 * sn;
      float r2 = x2 * cs + x1 * sn;
      split2(r1, hh, ll); ((short*)&ha)[jj] = hh; ((short*)&la)[jj] = ll;
      split2(r2, hh, ll); ((short*)&hb)[jj] = hh; ((short*)&lb)[jj] = ll;
    }
    // logical slots: first write s=dc>>1 (half dc&1), second s=8+(dc>>1)
    const int uu = ((dc >> 1) ^ t) & 7;
    const int h4 = (dc & 1) * 4;
    size_t base = (size_t)kvh * T * HD + (size_t)t * HD;
    *(short4*)(Kh + base + uu * 8 + h4) = ha;
    *(short4*)(Kl + base + uu * 8 + h4) = la;
    *(short4*)(Kh + base + (8 + uu) * 8 + h4) = hb;
    *(short4*)(Kl + base + (8 + uu) * 8 + h4) = lb;
  }
  // V -> bf16 transposed, swizzled key-slot placement within 32-key tiles
#pragma unroll
  for (int i = 0; i < 8; i++) {
    int c = tid + 256 * i;
    int key = c >> 5, dc = c & 31;
    float4 f = *(const float4*)(qkv + (size_t)(t0 + key) * QKV_OUT
                                + (size_t)(NH + NKV) * HD + (size_t)kvh * HD + dc * 4);
    Vh_lds[(dc*4+0)*72 + key] = f2bf(f.x);
    Vh_lds[(dc*4+1)*72 + key] = f2bf(f.y);
    Vh_lds[(dc*4+2)*72 + key] = f2bf(f.z);
    Vh_lds[(dc*4+3)*72 + key] = f2bf(f.w);
  }
  __syncthreads();
#pragma unroll
  for (int i = 0; i < 2; i++) {
    int c = tid + 256 * i;
    int row = c >> 2, cc = c & 3;
    int sd = (row >> 1) & 3;
    size_t o = (size_t)kvh * HD * T + (size_t)row * T + t0 + ((cc ^ sd)) * 8;
    *(bfrag*)(Vth + o) = *(const bfrag*)&Vh_lds[row * 72 + cc * 8];
  }
#pragma unroll
  for (int i = 0; i < 2; i++) {
    int c = tid + 256 * i;
    int row = c >> 2, cc = c & 3;
    int sd = (row >> 1) & 3;
    size_t o = (size_t)kvh * HD * T + (size_t)row * T + t0 + 32 + ((cc ^ sd)) * 8;
    *(bfrag*)(Vth + o) = *(const bfrag*)&Vh_lds[row * 72 + 32 + cc * 8];
  }
}

// ---------------- MFMA flash attention ------------------------------------
// R7 structure (kvh = bid&7 XCD pinning, dbuf gload_lds staging, lane-local
// defer check) + R10: (a) Q rope applied in-register at Q-load (pairs d and
// d+64 live at kc and kc+2 of the SAME thread; identical fp32 arithmetic to
// the old split_kv Q pass -> bit-identical results); (b) last ktile peeled
// so the main loop carries no causal-mask code.
__global__ __launch_bounds__(256)
void attn_kernel(const float* __restrict__ qkv, const int* __restrict__ positions,
                 const float2* __restrict__ tab,
                 const short* __restrict__ Kh, const short* __restrict__ Kl,
                 const short* __restrict__ Vth,
                 float* __restrict__ attn) {
  __shared__ __align__(16) short Ksh[2][32 * 128];   // 2x8KB, swizzled
  __shared__ __align__(16) short Ksl[2][32 * 128];   // 2x8KB
  __shared__ __align__(16) short Vsh[2][128 * 32];   // 2x8KB, swizzled
  __shared__ __align__(16) short Psh[4 * 16 * 40];   // 5KB, per-wave

  const int kvh = blockIdx.x & 7;              // == XCD id (round-robin)
  const int pair = blockIdx.x >> 3;            // 0..63
  const int tid = threadIdx.x;
  const int lane = tid & 63;
  const int wv = tid >> 6;
  const int l15 = lane & 15, quad = lane >> 4;
  const int h = kvh * 4 + wv;
  short* Pw = Psh + wv * 16 * 40;

  const short* KhB = Kh + (size_t)kvh * T * HD;
  const short* KlB = Kl + (size_t)kvh * T * HD;
  const short* VhB = Vth + (size_t)kvh * HD * T;

  // staging source offsets (shorts), loop-invariant; dest is linear lane*16
  const int offK0 = (tid >> 4) * 128 + (tid & 15) * 8;          // rows 0..15
  const int offK1 = offK0 + 16 * 128;                           // rows 16..31
  const int offV0 = (tid >> 2) * T + (tid & 3) * 8;             // dims 0..63
  const int offV1 = offV0 + 64 * T;                             // dims 64..127
  const int wv1k = wv * 1024;                                   // byte chunk

  auto stage = [&](int k0, int b) {
    const short* khs = KhB + (size_t)k0 * HD;
    const short* kls = KlB + (size_t)k0 * HD;
    const short* vs  = VhB + k0;
    gload_lds16(khs + offK0, (char*)&Ksh[b][0] + wv1k);
    gload_lds16(khs + offK1, (char*)&Ksh[b][0] + 4096 + wv1k);
    gload_lds16(kls + offK0, (char*)&Ksl[b][0] + wv1k);
    gload_lds16(kls + offK1, (char*)&Ksl[b][0] + 4096 + wv1k);
    gload_lds16(vs + offV0, (char*)&Vsh[b][0] + wv1k);
    gload_lds16(vs + offV1, (char*)&Vsh[b][0] + 4096 + wv1k);
  };

  // read-side swizzle constants (lane-invariant per kc)
  const int sdv = (l15 >> 1) & 3;                 // V: q' = quad ^ sdv
  const int vq8 = (quad ^ sdv) * 8;
  int uuk[4];                                     // K: u = (s&8)|((s^l15)&7)
#pragma unroll
  for (int kc = 0; kc < 4; kc++) {
    int s = 4 * kc + quad;
    uuk[kc] = ((s & 8) | ((s ^ l15) & 7)) * 8;
  }

  bfrag ones;
#pragma unroll
  for (int j = 0; j < 8; j++) ones[j] = (short)0x3f80;

  for (int pass = 0; pass < 2; pass++) {
    const int qt = pass ? pair : 127 - pair;     // heavy first
    const int q0 = qt * 16;
    const int nk = (q0 >> 5) + 1;                // keys 0..q0+15

    // ---- Q load + in-register rope + QS2 prescale + bf16x2 split ----
    bfrag qh[4], ql[4];
    {
      const float* qrow = qkv + (size_t)(q0 + l15) * QKV_OUT + (size_t)h * HD;
      float fvv[4][8];
#pragma unroll
      for (int kc = 0; kc < 4; kc++) {
        float4 f0 = *(const float4*)(qrow + kc * 32 + quad * 8);
        float4 f1 = *(const float4*)(qrow + kc * 32 + quad * 8 + 4);
        fvv[kc][0] = f0.x; fvv[kc][1] = f0.y; fvv[kc][2] = f0.z; fvv[kc][3] = f0.w;
        fvv[kc][4] = f1.x; fvv[kc][5] = f1.y; fvv[kc][6] = f1.z; fvv[kc][7] = f1.w;
      }
      const float2* trw = tab + (size_t)positions[q0 + l15] * 64;
#pragma unroll
      for (int kc = 0; kc < 2; kc++) {
#pragma unroll
        for (int j = 0; j < 8; j++) {
          int d = kc * 32 + quad * 8 + j;        // < 64
          float2 cssn = trw[d];
          float x1 = fvv[kc][j], x2 = fvv[kc + 2][j];
          fvv[kc][j]     = x1 * cssn.x - x2 * cssn.y;
          fvv[kc + 2][j] = x2 * cssn.x + x1 * cssn.y;
        }
      }
#pragma unroll
      for (int kc = 0; kc < 4; kc++)
#pragma unroll
        for (int j = 0; j < 8; j++) {
          short hi, lo; split2(fvv[kc][j] * QS2, hi, lo);
          qh[kc][j] = hi; ql[kc][j] = lo;
        }
    }

    ffrag o[8], ol;
    ol = (ffrag){0.f, 0.f, 0.f, 0.f};
#pragma unroll
    for (int n = 0; n < 8; n++) o[n] = (ffrag){0.f, 0.f, 0.f, 0.f};
    float m_i[4] = {-1e30f, -1e30f, -1e30f, -1e30f};

    // one ktile's full compute; maskq folds at inline sites
    auto compute_tile = [&](int k0, int b, bool maskq) {
      const short* ksh = &Ksh[b][0];
      const short* ksl = &Ksl[b][0];
      const short* vsh = &Vsh[b][0];
      ffrag s[2];
      s[0] = (ffrag){0.f,0.f,0.f,0.f}; s[1] = (ffrag){0.f,0.f,0.f,0.f};
#pragma unroll
      for (int kc = 0; kc < 4; kc++) {
#pragma unroll
        for (int n = 0; n < 2; n++) {
          const int rb = (n * 16 + l15) * 128 + uuk[kc];
          bfrag bh = *(const bfrag*)&ksh[rb];
          bfrag bl = *(const bfrag*)&ksl[rb];
          s[n] = __builtin_amdgcn_mfma_f32_16x16x32_bf16(qh[kc], bh, s[n], 0,0,0);
          s[n] = __builtin_amdgcn_mfma_f32_16x16x32_bf16(qh[kc], bl, s[n], 0,0,0);
          s[n] = __builtin_amdgcn_mfma_f32_16x16x32_bf16(ql[kc], bh, s[n], 0,0,0);
        }
      }
      float sv[2][4];
#pragma unroll
      for (int n = 0; n < 2; n++)
#pragma unroll
        for (int r = 0; r < 4; r++) {
          float v = s[n][r];
          if (maskq) {
            int key = k0 + n * 16 + l15;
            int row = q0 + quad * 4 + r;
            if (key > row) v = -1e30f;
          }
          sv[n][r] = v;
        }
      // lane-local max per row; trigger iff any lane exceeds m_i+THR
      float lm[4];
      bool trig = false;
#pragma unroll
      for (int r = 0; r < 4; r++) {
        lm[r] = fmaxf(sv[0][r], sv[1][r]);
        trig = trig || (lm[r] > m_i[r] + DEFER_THR);
      }
      if (__any(trig)) {                       // rare: full reduce + rescale
#pragma unroll
        for (int r = 0; r < 4; r++) {
          float m2 = lm[r];
          m2 = fmaxf(m2, __shfl_xor(m2, 1));
          m2 = fmaxf(m2, __shfl_xor(m2, 2));
          m2 = fmaxf(m2, __shfl_xor(m2, 4));
          m2 = fmaxf(m2, __shfl_xor(m2, 8));
          float mn = fmaxf(m_i[r], m2);
          float a = exp2f(m_i[r] - mn);
          m_i[r] = mn;
          ol[r] *= a;
#pragma unroll
          for (int n = 0; n < 8; n++) o[n][r] *= a;
        }
      }
#pragma unroll
      for (int n = 0; n < 2; n++)
#pragma unroll
        for (int r = 0; r < 4; r++) {
          float p = exp2f(sv[n][r] - m_i[r]);   // bounded by 2^DEFER_THR
          Pw[(quad*4 + r) * 40 + n*16 + l15] = f2bf(p);
        }
      // ---- PV; l via ones-MFMA (same wave wrote Pw, no barrier) ----
      bfrag ph = *(const bfrag*)&Pw[l15 * 40 + quad * 8];
      ol = __builtin_amdgcn_mfma_f32_16x16x32_bf16(ph, ones, ol, 0,0,0);
#pragma unroll
      for (int n = 0; n < 8; n++) {
        bfrag vh = *(const bfrag*)&vsh[(n * 16 + l15) * 32 + vq8];
        o[n] = __builtin_amdgcn_mfma_f32_16x16x32_bf16(ph, vh, o[n], 0,0,0);
      }
    };

    // prologue: stage tile 0, drain, sync
    stage(0, 0);
    asm volatile("s_waitcnt vmcnt(0)" ::: "memory");
    __builtin_amdgcn_s_barrier();

    int cur = 0;
    for (int kt = 0; kt < nk - 1; kt++) {        // mask-free main loop
      const int k0 = kt << 5;
      stage(k0 + 32, cur ^ 1);                   // in flight during compute
      compute_tile(k0, cur, false);
      asm volatile("s_waitcnt vmcnt(0)" ::: "memory");
      __builtin_amdgcn_s_barrier();
      cur ^= 1;
    }
    // peeled last ktile (causal mask lives only here)
    compute_tile((nk - 1) << 5, cur, true);
    __builtin_amdgcn_s_barrier();                // LDS safe before next pass

    // ---- normalized output ----
    float inv[4];
#pragma unroll
    for (int r = 0; r < 4; r++) inv[r] = 1.f / ol[r];
#pragma unroll
    for (int n = 0; n < 8; n++)
#pragma unroll
      for (int r = 0; r < 4; r++) {
        int row = q0 + quad * 4 + r;
        attn[(size_t)row * HID + (size_t)h * HD + n * 16 + l15] = o[n][r] * inv[r];
      }
  }
}

// ---------------- dynamic quant with sum (i8 out, swizzled) ---------------
__global__ __launch_bounds__(256)
void quant_kernel(const float* __restrict__ x, char* __restrict__ q2,
                  float* __restrict__ s2, float* __restrict__ sum2) {
  __shared__ float red[256];
  const int t = blockIdx.x, tid = threadIdx.x;
  const float* row = x + (size_t)t * HID;
  float4 v[4];
  float m = 0.f;
#pragma unroll
  for (int i = 0; i < 4; i++) {
    v[i] = *(const float4*)(row + tid * 16 + i * 4);
    m = fmaxf(m, fmaxf(fmaxf(fabsf(v[i].x), fabsf(v[i].y)),
                       fmaxf(fabsf(v[i].z), fabsf(v[i].w))));
  }
  red[tid] = m; __syncthreads();
  for (int off = 128; off > 0; off >>= 1) {
    if (tid < off) red[tid] = fmaxf(red[tid], red[tid + off]);
    __syncthreads();
  }
  float s = fmaxf(red[0], 1e-8f) / 127.f;
  __syncthreads();
  float ssum = 0.f;
  c16 o;
#pragma unroll
  for (int i = 0; i < 4; i++) {
    float q;
    q = fminf(127.f, fmaxf(-127.f, rintf(v[i].x / s))); ssum += q; o[i*4+0] = (char)(int)q;
    q = fminf(127.f, fmaxf(-127.f, rintf(v[i].y / s))); ssum += q; o[i*4+1] = (char)(int)q;
    q = fminf(127.f, fmaxf(-127.f, rintf(v[i].z / s))); ssum += q; o[i*4+2] = (char)(int)q;
    q = fminf(127.f, fmaxf(-127.f, rintf(v[i].w / s))); ssum += q; o[i*4+3] = (char)(int)q;
  }
  const int chunk = (tid & ~7) | ((tid & 7) ^ (t & 7));   // swizzled slot
  *(c16*)(q2 + (size_t)t * HID + chunk * 16) = o;
  red[tid] = ssum; __syncthreads();
  for (int off = 128; off > 0; off >>= 1) {
    if (tid < off) red[tid] += red[tid + off];
    __syncthreads();
  }
  if (tid == 0) { s2[t] = s; sum2[t] = red[0]; }
}

// ---------------- launch ----------------
// Workspace layout (~110 MB): act8 (a_i8/q2) and w8 (wqkv/wo) reused across
// phases; +1MB rope table (filled by asum_conv's first 512 blocks).
extern "C" void kernel_launch(void* const* d_in, const int* in_sizes, int n_in,
                              void* d_out, int out_size, void* d_ws, size_t ws_size,
                              hipStream_t stream) {
  const int*   positions   = (const int*)d_in[0];
  const int*   q_act       = (const int*)d_in[1];
  const float* act_scale   = (const float*)d_in[2];
  const int*   w_qkv_q     = (const int*)d_in[3];
  const float* w_qkv_scale = (const float*)d_in[4];
  const float* w_qkv_zero  = (const float*)d_in[5];
  const int*   w_o_q       = (const int*)d_in[6];
  const float* w_o_scale   = (const float*)d_in[7];
  const float* w_o_zero    = (const float*)d_in[8];
  float* out = (float*)d_out;

  size_t off = 0;
  auto alloc = [&](size_t bytes) -> void* {
    void* p = (char*)d_ws + off;
    off += (bytes + 255) & ~(size_t)255;
    return p;
  };
  float* qkv   = (float*)alloc((size_t)T * QKV_OUT * 4);         // 50.3 MB
  char*  act8  = (char*)alloc((size_t)T * HID);                  //  8.4 MB (a_i8 / q2)
  char*  w8    = (char*)alloc((size_t)QKV_OUT * HID);            // 25.2 MB (wqkv / wo)
  short* Kh    = (short*)alloc((size_t)NKV * T * HD * 2);        //  8.4 MB
  short* Kl    = (short*)alloc((size_t)NKV * T * HD * 2);        //  8.4 MB
  short* Vth   = (short*)alloc((size_t)NKV * T * HD * 2);        //  8.4 MB
  float* a_sum = (float*)alloc(T * 4);
  float* s2    = (float*)alloc(T * 4);
  float* sum2  = (float*)alloc(T * 4);
  float2* tab  = (float2*)alloc((size_t)T * 64 * 8);             //  1.0 MB
  (void)ws_size;

  asum_conv<<<T, 256, 0, stream>>>(q_act, a_sum, act8, tab);
  conv_i2c<<<(QKV_OUT * HID / 16 + 255) / 256, 256, 0, stream>>>(
      w_qkv_q, w8, QKV_OUT * HID / 16);
  gemm_i8<<<dim3(QKV_OUT / 128, T / 128), 256, 0, stream>>>(
      act8, w8, act_scale, a_sum, w_qkv_scale, w_qkv_zero, qkv, T, QKV_OUT, HID);
  split_kv<<<dim3(T / 64, NKV), 256, 0, stream>>>(
      qkv, positions, tab, Kh, Kl, Vth);
  attn_kernel<<<dim3(512), 256, 0, stream>>>(
      qkv, positions, tab, Kh, Kl, Vth, out);
  conv_i2c<<<(HID * HID / 16 + 255) / 256, 256, 0, stream>>>(
      w_o_q, w8, HID * HID / 16);                 // wqkv dead; reuse w8
  quant_kernel<<<T, 256, 0, stream>>>(out, act8, s2, sum2);   // a_i8 dead; reuse act8
  gemm_i8<<<dim3(HID / 128, T / 128), 256, 0, stream>>>(
      act8, w8, s2, sum2, w_o_scale, w_o_zero, out, T, HID, HID);
}

// Round 11
// 463.740 us; speedup vs baseline: 1.2936x; 1.0071x over previous
//
#include <hip/hip_runtime.h>

#define T 2048
#define HID 4096
#define NH 32
#define NKV 8
#define HD 128
#define QKV_OUT ((NH + 2*NKV) * HD)   // 6144
#define SCALING 0.08838834764831843f  // 128^-0.5
#define QS2 0.12751744954f            // SCALING * log2(e): QK^T in log2 domain
#define DEFER_THR 10.0f               // defer-max threshold (log2 domain, P<=2^10)
#define ROPE_C 0.20762050593046014f   // log2(10000)/64

typedef __attribute__((ext_vector_type(8))) short bfrag;   // 8 bf16
typedef __attribute__((ext_vector_type(4))) float ffrag;   // 4 f32 acc
typedef __attribute__((ext_vector_type(4))) int  ifrag;    // 16 i8 / 4 i32 acc
typedef __attribute__((ext_vector_type(16))) char c16;

__device__ __forceinline__ short f2bf(float f) {
  unsigned u = __builtin_bit_cast(unsigned, f);
  u += 0x7fffu + ((u >> 16) & 1u);   // RNE
  return (short)(u >> 16);
}

// bf16x2 split: x ~= hi + lo, residual ~2^-17 * |x|
__device__ __forceinline__ void split2(float x, short& hi, short& lo) {
  unsigned u = __builtin_bit_cast(unsigned, x);
  unsigned uh = u + (0x7fffu + ((u >> 16) & 1u));
  hi = (short)(uh >> 16);
  float fh = __builtin_bit_cast(float, uh & 0xffff0000u);
  float r = x - fh;
  unsigned ur = __builtin_bit_cast(unsigned, r);
  ur += 0x7fffu + ((ur >> 16) & 1u);
  lo = (short)(ur >> 16);
}

// async global->LDS, 16 B per lane (LDS dest = wave-uniform base + lane*16)
__device__ __forceinline__ void gload_lds16(const void* g, void* l) {
  __builtin_amdgcn_global_load_lds(
      (const __attribute__((address_space(1))) unsigned int*)g,
      (__attribute__((address_space(3))) unsigned int*)l, 16, 0, 0);
}

// ---- i8 swizzle convention (rule 21): within each 128B window of a row,
// the 16B chunk with logical slot s (0..7) is STORED at slot s ^ (row & 7).
// gemm stages rows linearly via global_load_lds and reads with the same XOR
// -> conflict-free ds_read_b128 (2-way max). All i8 writers apply it.

// ---- fused prep A: blocks [0,T): a_sum + act pack (+rope table for <512);
//      blocks [T, T+6144): w_qkv int32->int8 pack. One launch, fuller GPU.
__global__ __launch_bounds__(256)
void prep_a(const int* __restrict__ qact, float* __restrict__ a_sum,
            char* __restrict__ a_i8, float2* __restrict__ tab,
            const int* __restrict__ wsrc, char* __restrict__ wdst) {
  __shared__ int red[256];
  const int bid = blockIdx.x, tid = threadIdx.x;

  if (bid >= T) {                     // ---- w_qkv conv path ----
    int idx = (bid - T) * 256 + tid;  // n16 = QKV_OUT*HID/16 = 6144 blocks
    const int4* s4 = (const int4*)wsrc + (size_t)idx * 4;
    c16 o;
#pragma unroll
    for (int j = 0; j < 4; j++) {
      int4 v = s4[j];
      o[j*4+0] = (char)v.x; o[j*4+1] = (char)v.y;
      o[j*4+2] = (char)v.z; o[j*4+3] = (char)v.w;
    }
    const int idxp = (idx & ~7) | ((idx & 7) ^ ((idx >> 8) & 7));
    *(c16*)(wdst + (size_t)idxp * 16) = o;
    return;
  }

  const int t = bid;
  if (t < 512) {                      // rope table: T*64 entries
    int idx = t * 256 + tid;
    int p = idx >> 6, j = idx & 63;
    float fr = (float)p * exp2f(-ROPE_C * (float)j);
    float sn, cs; sincosf(fr, &sn, &cs);
    tab[idx] = make_float2(cs, sn);
  }
  const int* row = qact + (size_t)t * HID + tid * 16;
  int s = 0;
  c16 o;
#pragma unroll
  for (int i = 0; i < 4; i++) {
    int4 v = *(const int4*)(row + i * 4);
    s += v.x + v.y + v.z + v.w;
    o[i*4+0] = (char)v.x; o[i*4+1] = (char)v.y;
    o[i*4+2] = (char)v.z; o[i*4+3] = (char)v.w;
  }
  const int chunk = (tid & ~7) | ((tid & 7) ^ (t & 7));   // swizzled slot
  *(c16*)(a_i8 + (size_t)t * HID + chunk * 16) = o;
  red[tid] = s; __syncthreads();
  for (int off = 128; off > 0; off >>= 1) {
    if (tid < off) red[tid] += red[tid + off];
    __syncthreads();
  }
  if (tid == 0) a_sum[t] = (float)red[0];
}

// ---------------- W4A8 GEMM, exact i8 MFMA (R9 state) ---------------------
__global__ __launch_bounds__(256)
void gemm_i8(const char* __restrict__ A, const char* __restrict__ W,
             const float* __restrict__ s_a, const float* __restrict__ asum,
             const float* __restrict__ s_w, const float* __restrict__ z_w,
             float* __restrict__ C, int M, int N, int K) {
  __shared__ __align__(16) char As[2][128 * 128];   // 2x16KB, swizzled content
  __shared__ __align__(16) char Bs[2][128 * 128];   // 2x16KB
  const int tid = threadIdx.x;
  const int lane = tid & 63;
  const int quad = lane >> 4, l15 = lane & 15;
  const int wave = tid >> 6;
  const int wm = (wave >> 1) * 64, wn = (wave & 1) * 64;
  const int bm = blockIdx.y * 128, bn = blockIdx.x * 128;
  const int sr = tid >> 3, sc = (tid & 7) * 16;   // staging: 32 rows/call

  ifrag acc[4][4];
#pragma unroll
  for (int mi = 0; mi < 4; mi++)
#pragma unroll
    for (int ni = 0; ni < 4; ni++)
      acc[mi][ni] = (ifrag){0, 0, 0, 0};

  auto stage = [&](int k0, int b) {
#pragma unroll
    for (int j = 0; j < 4; j++) {
      gload_lds16(A + (size_t)(bm + j * 32 + sr) * K + k0 + sc,
                  &As[b][j * 4096 + tid * 16]);
      gload_lds16(W + (size_t)(bn + j * 32 + sr) * K + k0 + sc,
                  &Bs[b][j * 4096 + tid * 16]);
    }
  };

  // swizzled byte col for k-sub ks: slot (ks*4+quad) ^ (l15&7)
  const int scol0 = ((quad)     ^ (l15 & 7)) * 16;
  const int scol1 = ((4 + quad) ^ (l15 & 7)) * 16;

  // prologue: stage tile 0, drain, sync
  stage(0, 0);
  asm volatile("s_waitcnt vmcnt(0)" ::: "memory");
  __builtin_amdgcn_s_barrier();

  int cur = 0;
  for (int k0 = 0; k0 < K; k0 += 128) {
    if (k0 + 128 < K) stage(k0 + 128, cur ^ 1);   // in flight during compute

#pragma unroll
    for (int ks = 0; ks < 2; ks++) {
      const int scol = ks ? scol1 : scol0;
      ifrag af[4], bfv[4];
#pragma unroll
      for (int mi = 0; mi < 4; mi++)
        af[mi] = *(const ifrag*)&As[cur][(wm + mi * 16 + l15) * 128 + scol];
#pragma unroll
      for (int ni = 0; ni < 4; ni++)
        bfv[ni] = *(const ifrag*)&Bs[cur][(wn + ni * 16 + l15) * 128 + scol];
#pragma unroll
      for (int mi = 0; mi < 4; mi++)
#pragma unroll
        for (int ni = 0; ni < 4; ni++)
          acc[mi][ni] = __builtin_amdgcn_mfma_i32_16x16x64_i8(
              af[mi], bfv[ni], acc[mi][ni], 0, 0, 0);
    }

    // next tile's loads landed during compute; sync and flip
    asm volatile("s_waitcnt vmcnt(0)" ::: "memory");
    __builtin_amdgcn_s_barrier();
    cur ^= 1;
  }

#pragma unroll
  for (int mi = 0; mi < 4; mi++) {
    int row0 = bm + wm + mi * 16 + quad * 4;
#pragma unroll
    for (int r = 0; r < 4; r++) {
      int row = row0 + r;
      float sa = s_a[row], av = asum[row];
#pragma unroll
      for (int ni = 0; ni < 4; ni++) {
        int col = bn + wn + ni * 16 + l15;
        C[(size_t)row * N + col] = (sa * s_w[col]) * ((float)acc[mi][ni][r] - z_w[col] * av);
      }
    }
  }
}

// ---- fused prep B: blocks [0,256): split K/V (rope+split+swizzle);
//      blocks [256, 256+4096): w_o int32->int8 pack. split_kv's 256-block
//      grid left the GPU idle; w8 is dead after the QKV GEMM, so the w_o
//      conv can ride along here.
__global__ __launch_bounds__(256)
void kv_prep(const float* __restrict__ qkv, const int* __restrict__ positions,
             const float2* __restrict__ tab,
             short* __restrict__ Kh, short* __restrict__ Kl,
             short* __restrict__ Vth,
             const int* __restrict__ wsrc, char* __restrict__ wdst) {
  __shared__ __align__(16) short Vh_lds[128 * 72];
  const int bid = blockIdx.x, tid = threadIdx.x;

  if (bid >= 256) {                   // ---- w_o conv path ----
    int idx = (bid - 256) * 256 + tid;  // n16 = HID*HID/16 = 4096 blocks
    const int4* s4 = (const int4*)wsrc + (size_t)idx * 4;
    c16 o;
#pragma unroll
    for (int j = 0; j < 4; j++) {
      int4 v = s4[j];
      o[j*4+0] = (char)v.x; o[j*4+1] = (char)v.y;
      o[j*4+2] = (char)v.z; o[j*4+3] = (char)v.w;
    }
    const int idxp = (idx & ~7) | ((idx & 7) ^ ((idx >> 8) & 7));
    *(c16*)(wdst + (size_t)idxp * 16) = o;
    return;
  }

  const int kvh = bid & 7;
  const int t0 = (bid >> 3) * 64;

  // K: rope + hi/lo split, swizzled slot placement
#pragma unroll
  for (int it = 0; it < 4; it++) {
    int c = tid + 256 * it;
    int key = c >> 4, dc = c & 15;
    const int t = t0 + key;
    const float* kr = qkv + (size_t)t * QKV_OUT
                      + (size_t)NH * HD + (size_t)kvh * HD;
    float4 a = *(const float4*)(kr + dc * 4);
    float4 b = *(const float4*)(kr + dc * 4 + 64);
    float av[4] = {a.x, a.y, a.z, a.w};
    float bv[4] = {b.x, b.y, b.z, b.w};
    const float2* tr = tab + (size_t)positions[t] * 64 + dc * 4;
    short4 ha, la, hb, lb;
    short hh, ll;
#pragma unroll
    for (int jj = 0; jj < 4; jj++) {
      float cs = tr[jj].x, sn = tr[jj].y;
      float x1 = av[jj], x2 = bv[jj];
      float r1 = x1 * cs - x2 * sn;
      float r2 = x2 * cs + x1 * sn;
      split2(r1, hh, ll); ((short*)&ha)[jj] = hh; ((short*)&la)[jj] = ll;
      split2(r2, hh, ll); ((short*)&hb)[jj] = hh; ((short*)&lb)[jj] = ll;
    }
    // logical slots: first write s=dc>>1 (half dc&1), second s=8+(dc>>1)
    const int uu = ((dc >> 1) ^ t) & 7;
    const int h4 = (dc & 1) * 4;
    size_t base = (size_t)kvh * T * HD + (size_t)t * HD;
    *(short4*)(Kh + base + uu * 8 + h4) = ha;
    *(short4*)(Kl + base + uu * 8 + h4) = la;
    *(short4*)(Kh + base + (8 + uu) * 8 + h4) = hb;
    *(short4*)(Kl + base + (8 + uu) * 8 + h4) = lb;
  }
  // V -> bf16 transposed, swizzled key-slot placement within 32-key tiles
#pragma unroll
  for (int i = 0; i < 8; i++) {
    int c = tid + 256 * i;
    int key = c >> 5, dc = c & 31;
    float4 f = *(const float4*)(qkv + (size_t)(t0 + key) * QKV_OUT
                                + (size_t)(NH + NKV) * HD + (size_t)kvh * HD + dc * 4);
    Vh_lds[(dc*4+0)*72 + key] = f2bf(f.x);
    Vh_lds[(dc*4+1)*72 + key] = f2bf(f.y);
    Vh_lds[(dc*4+2)*72 + key] = f2bf(f.z);
    Vh_lds[(dc*4+3)*72 + key] = f2bf(f.w);
  }
  __syncthreads();
#pragma unroll
  for (int i = 0; i < 2; i++) {
    int c = tid + 256 * i;
    int row = c >> 2, cc = c & 3;
    int sd = (row >> 1) & 3;
    size_t o = (size_t)kvh * HD * T + (size_t)row * T + t0 + ((cc ^ sd)) * 8;
    *(bfrag*)(Vth + o) = *(const bfrag*)&Vh_lds[row * 72 + cc * 8];
  }
#pragma unroll
  for (int i = 0; i < 2; i++) {
    int c = tid + 256 * i;
    int row = c >> 2, cc = c & 3;
    int sd = (row >> 1) & 3;
    size_t o = (size_t)kvh * HD * T + (size_t)row * T + t0 + 32 + ((cc ^ sd)) * 8;
    *(bfrag*)(Vth + o) = *(const bfrag*)&Vh_lds[row * 72 + 32 + cc * 8];
  }
}

// ---------------- MFMA flash attention ------------------------------------
// R10 post-mortem: VGPR=92 (unified total) allows 5 waves/SIMD and LDS
// 54272x3 <= 160KB allows 3 blocks/CU -- occupancy was GRID-limited
// (512 blocks = 2/CU). R11: ONE qtile per block -> 1024 blocks, longest
// first (qt descending), kvh = bid&7 keeps XCD pinning. 768 resident at
// 3/CU; tail is the shortest blocks. Per-row math bit-identical.
__global__ __launch_bounds__(256)
void attn_kernel(const float* __restrict__ qkv, const int* __restrict__ positions,
                 const float2* __restrict__ tab,
                 const short* __restrict__ Kh, const short* __restrict__ Kl,
                 const short* __restrict__ Vth,
                 float* __restrict__ attn) {
  __shared__ __align__(16) short Ksh[2][32 * 128];   // 2x8KB, swizzled
  __shared__ __align__(16) short Ksl[2][32 * 128];   // 2x8KB
  __shared__ __align__(16) short Vsh[2][128 * 32];   // 2x8KB, swizzled
  __shared__ __align__(16) short Psh[4 * 16 * 40];   // 5KB, per-wave

  const int kvh = blockIdx.x & 7;              // == XCD id (round-robin)
  const int qt  = 127 - (int)(blockIdx.x >> 3);  // longest blocks first
  const int tid = threadIdx.x;
  const int lane = tid & 63;
  const int wv = tid >> 6;
  const int l15 = lane & 15, quad = lane >> 4;
  const int h = kvh * 4 + wv;
  short* Pw = Psh + wv * 16 * 40;

  const short* KhB = Kh + (size_t)kvh * T * HD;
  const short* KlB = Kl + (size_t)kvh * T * HD;
  const short* VhB = Vth + (size_t)kvh * HD * T;

  // staging source offsets (shorts), loop-invariant; dest is linear lane*16
  const int offK0 = (tid >> 4) * 128 + (tid & 15) * 8;          // rows 0..15
  const int offK1 = offK0 + 16 * 128;                           // rows 16..31
  const int offV0 = (tid >> 2) * T + (tid & 3) * 8;             // dims 0..63
  const int offV1 = offV0 + 64 * T;                             // dims 64..127
  const int wv1k = wv * 1024;                                   // byte chunk

  auto stage = [&](int k0, int b) {
    const short* khs = KhB + (size_t)k0 * HD;
    const short* kls = KlB + (size_t)k0 * HD;
    const short* vs  = VhB + k0;
    gload_lds16(khs + offK0, (char*)&Ksh[b][0] + wv1k);
    gload_lds16(khs + offK1, (char*)&Ksh[b][0] + 4096 + wv1k);
    gload_lds16(kls + offK0, (char*)&Ksl[b][0] + wv1k);
    gload_lds16(kls + offK1, (char*)&Ksl[b][0] + 4096 + wv1k);
    gload_lds16(vs + offV0, (char*)&Vsh[b][0] + wv1k);
    gload_lds16(vs + offV1, (char*)&Vsh[b][0] + 4096 + wv1k);
  };

  // read-side swizzle constants (lane-invariant per kc)
  const int sdv = (l15 >> 1) & 3;                 // V: q' = quad ^ sdv
  const int vq8 = (quad ^ sdv) * 8;
  int uuk[4];                                     // K: u = (s&8)|((s^l15)&7)
#pragma unroll
  for (int kc = 0; kc < 4; kc++) {
    int s = 4 * kc + quad;
    uuk[kc] = ((s & 8) | ((s ^ l15) & 7)) * 8;
  }

  bfrag ones;
#pragma unroll
  for (int j = 0; j < 8; j++) ones[j] = (short)0x3f80;

  const int q0 = qt * 16;
  const int nk = (q0 >> 5) + 1;                // keys 0..q0+15

  // ---- Q load + in-register rope + QS2 prescale + bf16x2 split ----
  bfrag qh[4], ql[4];
  {
    const float* qrow = qkv + (size_t)(q0 + l15) * QKV_OUT + (size_t)h * HD;
    float fvv[4][8];
#pragma unroll
    for (int kc = 0; kc < 4; kc++) {
      float4 f0 = *(const float4*)(qrow + kc * 32 + quad * 8);
      float4 f1 = *(const float4*)(qrow + kc * 32 + quad * 8 + 4);
      fvv[kc][0] = f0.x; fvv[kc][1] = f0.y; fvv[kc][2] = f0.z; fvv[kc][3] = f0.w;
      fvv[kc][4] = f1.x; fvv[kc][5] = f1.y; fvv[kc][6] = f1.z; fvv[kc][7] = f1.w;
    }
    const float2* trw = tab + (size_t)positions[q0 + l15] * 64;
#pragma unroll
    for (int kc = 0; kc < 2; kc++) {
#pragma unroll
      for (int j = 0; j < 8; j++) {
        int d = kc * 32 + quad * 8 + j;        // < 64
        float2 cssn = trw[d];
        float x1 = fvv[kc][j], x2 = fvv[kc + 2][j];
        fvv[kc][j]     = x1 * cssn.x - x2 * cssn.y;
        fvv[kc + 2][j] = x2 * cssn.x + x1 * cssn.y;
      }
    }
#pragma unroll
    for (int kc = 0; kc < 4; kc++)
#pragma unroll
      for (int j = 0; j < 8; j++) {
        short hi, lo; split2(fvv[kc][j] * QS2, hi, lo);
        qh[kc][j] = hi; ql[kc][j] = lo;
      }
  }

  ffrag o[8], ol;
  ol = (ffrag){0.f, 0.f, 0.f, 0.f};
#pragma unroll
  for (int n = 0; n < 8; n++) o[n] = (ffrag){0.f, 0.f, 0.f, 0.f};
  float m_i[4] = {-1e30f, -1e30f, -1e30f, -1e30f};

  // one ktile's full compute; maskq folds at inline sites
  auto compute_tile = [&](int k0, int b, bool maskq) {
    const short* ksh = &Ksh[b][0];
    const short* ksl = &Ksl[b][0];
    const short* vsh = &Vsh[b][0];
    ffrag s[2];
    s[0] = (ffrag){0.f,0.f,0.f,0.f}; s[1] = (ffrag){0.f,0.f,0.f,0.f};
#pragma unroll
    for (int kc = 0; kc < 4; kc++) {
#pragma unroll
      for (int n = 0; n < 2; n++) {
        const int rb = (n * 16 + l15) * 128 + uuk[kc];
        bfrag bh = *(const bfrag*)&ksh[rb];
        bfrag bl = *(const bfrag*)&ksl[rb];
        s[n] = __builtin_amdgcn_mfma_f32_16x16x32_bf16(qh[kc], bh, s[n], 0,0,0);
        s[n] = __builtin_amdgcn_mfma_f32_16x16x32_bf16(qh[kc], bl, s[n], 0,0,0);
        s[n] = __builtin_amdgcn_mfma_f32_16x16x32_bf16(ql[kc], bh, s[n], 0,0,0);
      }
    }
    float sv[2][4];
#pragma unroll
    for (int n = 0; n < 2; n++)
#pragma unroll
      for (int r = 0; r < 4; r++) {
        float v = s[n][r];
        if (maskq) {
          int key = k0 + n * 16 + l15;
          int row = q0 + quad * 4 + r;
          if (key > row) v = -1e30f;
        }
        sv[n][r] = v;
      }
    // lane-local max per row; trigger iff any lane exceeds m_i+THR
    float lm[4];
    bool trig = false;
#pragma unroll
    for (int r = 0; r < 4; r++) {
      lm[r] = fmaxf(sv[0][r], sv[1][r]);
      trig = trig || (lm[r] > m_i[r] + DEFER_THR);
    }
    if (__any(trig)) {                       // rare: full reduce + rescale
#pragma unroll
      for (int r = 0; r < 4; r++) {
        float m2 = lm[r];
        m2 = fmaxf(m2, __shfl_xor(m2, 1));
        m2 = fmaxf(m2, __shfl_xor(m2, 2));
        m2 = fmaxf(m2, __shfl_xor(m2, 4));
        m2 = fmaxf(m2, __shfl_xor(m2, 8));
        float mn = fmaxf(m_i[r], m2);
        float a = exp2f(m_i[r] - mn);
        m_i[r] = mn;
        ol[r] *= a;
#pragma unroll
        for (int n = 0; n < 8; n++) o[n][r] *= a;
      }
    }
#pragma unroll
    for (int n = 0; n < 2; n++)
#pragma unroll
      for (int r = 0; r < 4; r++) {
        float p = exp2f(sv[n][r] - m_i[r]);   // bounded by 2^DEFER_THR
        Pw[(quad*4 + r) * 40 + n*16 + l15] = f2bf(p);
      }
    // ---- PV; l via ones-MFMA (same wave wrote Pw, no barrier) ----
    bfrag ph = *(const bfrag*)&Pw[l15 * 40 + quad * 8];
    ol = __builtin_amdgcn_mfma_f32_16x16x32_bf16(ph, ones, ol, 0,0,0);
#pragma unroll
    for (int n = 0; n < 8; n++) {
      bfrag vh = *(const bfrag*)&vsh[(n * 16 + l15) * 32 + vq8];
      o[n] = __builtin_amdgcn_mfma_f32_16x16x32_bf16(ph, vh, o[n], 0,0,0);
    }
  };

  // prologue: stage tile 0, drain, sync
  stage(0, 0);
  asm volatile("s_waitcnt vmcnt(0)" ::: "memory");
  __builtin_amdgcn_s_barrier();

  int cur = 0;
  for (int kt = 0; kt < nk - 1; kt++) {        // mask-free main loop
    const int k0 = kt << 5;
    stage(k0 + 32, cur ^ 1);                   // in flight during compute
    compute_tile(k0, cur, false);
    asm volatile("s_waitcnt vmcnt(0)" ::: "memory");
    __builtin_amdgcn_s_barrier();
    cur ^= 1;
  }
  // peeled last ktile (causal mask lives only here)
  compute_tile((nk - 1) << 5, cur, true);

  // ---- normalized output ----
  float inv[4];
#pragma unroll
  for (int r = 0; r < 4; r++) inv[r] = 1.f / ol[r];
#pragma unroll
  for (int n = 0; n < 8; n++)
#pragma unroll
    for (int r = 0; r < 4; r++) {
      int row = q0 + quad * 4 + r;
      attn[(size_t)row * HID + (size_t)h * HD + n * 16 + l15] = o[n][r] * inv[r];
    }
}

// ---------------- dynamic quant with sum (i8 out, swizzled) ---------------
__global__ __launch_bounds__(256)
void quant_kernel(const float* __restrict__ x, char* __restrict__ q2,
                  float* __restrict__ s2, float* __restrict__ sum2) {
  __shared__ float red[256];
  const int t = blockIdx.x, tid = threadIdx.x;
  const float* row = x + (size_t)t * HID;
  float4 v[4];
  float m = 0.f;
#pragma unroll
  for (int i = 0; i < 4; i++) {
    v[i] = *(const float4*)(row + tid * 16 + i * 4);
    m = fmaxf(m, fmaxf(fmaxf(fabsf(v[i].x), fabsf(v[i].y)),
                       fmaxf(fabsf(v[i].z), fabsf(v[i].w))));
  }
  red[tid] = m; __syncthreads();
  for (int off = 128; off > 0; off >>= 1) {
    if (tid < off) red[tid] = fmaxf(red[tid], red[tid + off]);
    __syncthreads();
  }
  float s = fmaxf(red[0], 1e-8f) / 127.f;
  __syncthreads();
  float ssum = 0.f;
  c16 o;
#pragma unroll
  for (int i = 0; i < 4; i++) {
    float q;
    q = fminf(127.f, fmaxf(-127.f, rintf(v[i].x / s))); ssum += q; o[i*4+0] = (char)(int)q;
    q = fminf(127.f, fmaxf(-127.f, rintf(v[i].y / s))); ssum += q; o[i*4+1] = (char)(int)q;
    q = fminf(127.f, fmaxf(-127.f, rintf(v[i].z / s))); ssum += q; o[i*4+2] = (char)(int)q;
    q = fminf(127.f, fmaxf(-127.f, rintf(v[i].w / s))); ssum += q; o[i*4+3] = (char)(int)q;
  }
  const int chunk = (tid & ~7) | ((tid & 7) ^ (t & 7));   // swizzled slot
  *(c16*)(q2 + (size_t)t * HID + chunk * 16) = o;
  red[tid] = ssum; __syncthreads();
  for (int off = 128; off > 0; off >>= 1) {
    if (tid < off) red[tid] += red[tid + off];
    __syncthreads();
  }
  if (tid == 0) { s2[t] = s; sum2[t] = red[0]; }
}

// ---------------- launch ----------------
// Workspace layout (~110 MB): act8 (a_i8/q2) and w8 (wqkv/wo) reused across
// phases; +1MB rope table. 6 launches (was 8): conv passes ride along with
// asum_conv and split_kv dispatches.
extern "C" void kernel_launch(void* const* d_in, const int* in_sizes, int n_in,
                              void* d_out, int out_size, void* d_ws, size_t ws_size,
                              hipStream_t stream) {
  const int*   positions   = (const int*)d_in[0];
  const int*   q_act       = (const int*)d_in[1];
  const float* act_scale   = (const float*)d_in[2];
  const int*   w_qkv_q     = (const int*)d_in[3];
  const float* w_qkv_scale = (const float*)d_in[4];
  const float* w_qkv_zero  = (const float*)d_in[5];
  const int*   w_o_q       = (const int*)d_in[6];
  const float* w_o_scale   = (const float*)d_in[7];
  const float* w_o_zero    = (const float*)d_in[8];
  float* out = (float*)d_out;

  size_t off = 0;
  auto alloc = [&](size_t bytes) -> void* {
    void* p = (char*)d_ws + off;
    off += (bytes + 255) & ~(size_t)255;
    return p;
  };
  float* qkv   = (float*)alloc((size_t)T * QKV_OUT * 4);         // 50.3 MB
  char*  act8  = (char*)alloc((size_t)T * HID);                  //  8.4 MB (a_i8 / q2)
  char*  w8    = (char*)alloc((size_t)QKV_OUT * HID);            // 25.2 MB (wqkv / wo)
  short* Kh    = (short*)alloc((size_t)NKV * T * HD * 2);        //  8.4 MB
  short* Kl    = (short*)alloc((size_t)NKV * T * HD * 2);        //  8.4 MB
  short* Vth   = (short*)alloc((size_t)NKV * T * HD * 2);        //  8.4 MB
  float* a_sum = (float*)alloc(T * 4);
  float* s2    = (float*)alloc(T * 4);
  float* sum2  = (float*)alloc(T * 4);
  float2* tab  = (float2*)alloc((size_t)T * 64 * 8);             //  1.0 MB
  (void)ws_size;

  prep_a<<<T + QKV_OUT * HID / 16 / 256, 256, 0, stream>>>(
      q_act, a_sum, act8, tab, w_qkv_q, w8);
  gemm_i8<<<dim3(QKV_OUT / 128, T / 128), 256, 0, stream>>>(
      act8, w8, act_scale, a_sum, w_qkv_scale, w_qkv_zero, qkv, T, QKV_OUT, HID);
  kv_prep<<<256 + HID * HID / 16 / 256, 256, 0, stream>>>(
      qkv, positions, tab, Kh, Kl, Vth, w_o_q, w8);   // wqkv dead; reuse w8
  attn_kernel<<<dim3(1024), 256, 0, stream>>>(
      qkv, positions, tab, Kh, Kl, Vth, out);
  quant_kernel<<<T, 256, 0, stream>>>(out, act8, s2, sum2);   // a_i8 dead; reuse act8
  gemm_i8<<<dim3(HID / 128, T / 128), 256, 0, stream>>>(
      act8, w8, s2, sum2, w_o_scale, w_o_zero, out, T, HID, HID);
}